// Round 11
// baseline (228.863 us; speedup 1.0000x reference)
//
#include <hip/hip_runtime.h>
#include <math.h>

#define BIGF 3.0e38f

// ===========================================================================
// Spatial-hash KNN (K=3), 16 lanes per query.
// Selection must replicate the np reference's fp32 expansion distance:
//   sx  = (x*x + y*y) + z*z            (sequential, individually rounded)
//   dot = (p0 + p1) + p2, p_k = q_k*s_k
//   d2  = (sy + sx) - 2*dot
// evaluated with fp contract(off) — hipcc's default -ffp-contract=fast
// selects different neighbors (verified rounds 3-6). DO NOT TOUCH.
// Tie-break: lexicographic (d, idx) == stable top_k smallest-index-first;
// independent of scatter order and cell enumeration order.
// ===========================================================================

__device__ __forceinline__ int cell_clamp(float v, int G) {
  int c = (int)(v * (float)G);
  return min(G - 1, max(0, c));
}

// lex (d, idx) top-3 insert, branchless
__device__ __forceinline__ void ins3(float d, int id,
                                     float& d0, float& d1, float& d2,
                                     int& i0, int& i1, int& i2) {
  bool l0 = (d < d0) || (d == d0 && id < i0);
  bool l1 = (d < d1) || (d == d1 && id < i1);
  bool l2 = (d < d2) || (d == d2 && id < i2);
  float nd0 = l0 ? d  : d0;  int ni0 = l0 ? id : i0;
  float nd1 = l0 ? d0 : (l1 ? d  : d1);
  int   ni1 = l0 ? i0 : (l1 ? id : i1);
  float nd2 = l1 ? d1 : (l2 ? d  : d2);
  int   ni2 = l1 ? i1 : (l2 ? id : i2);
  d0 = nd0; d1 = nd1; d2 = nd2; i0 = ni0; i1 = ni1; i2 = ni2;
}

// ---- zero the count arrays ------------------------------------------------
__global__ __launch_bounds__(256) void zero_kernel(int* __restrict__ p, int n) {
  int i = blockIdx.x * 256 + threadIdx.x;
  if (i < n) p[i] = 0;
}

// ---- count: 3 point sets in one dispatch (blocks 0-63 / 64-79 / 80-95) ----
__global__ __launch_bounds__(256) void cell_count3_kernel(
    const float* __restrict__ p1, int n1, int g1, int* __restrict__ c1,
    const float* __restrict__ p2, int n2, int g2, int* __restrict__ c2,
    const float* __restrict__ p3, int n3, int g3, int* __restrict__ c3)
{
  int b = blockIdx.x;
  const float* p; int n, G; int* cnt; int i;
  if (b < 64)      { p = p1; n = n1; G = g1; cnt = c1; i = b * 256 + threadIdx.x; }
  else if (b < 80) { p = p2; n = n2; G = g2; cnt = c2; i = (b - 64) * 256 + threadIdx.x; }
  else             { p = p3; n = n3; G = g3; cnt = c3; i = (b - 80) * 256 + threadIdx.x; }
  if (i >= n) return;
  int cx = cell_clamp(p[3 * i],     G);
  int cy = cell_clamp(p[3 * i + 1], G);
  int cz = cell_clamp(p[3 * i + 2], G);
  atomicAdd(&cnt[(cz * G + cy) * G + cx], 1);
}

// ---- exclusive prefix over 3 grids; M need not divide 256 -----------------
__global__ __launch_bounds__(256) void prefix3_kernel(
    const int* __restrict__ c1, int* __restrict__ o1, int* __restrict__ u1, int m1,
    const int* __restrict__ c2, int* __restrict__ o2, int* __restrict__ u2, int m2,
    const int* __restrict__ c3, int* __restrict__ o3, int* __restrict__ u3, int m3)
{
  const int* cnt; int* offs; int* cur; int M;
  if (blockIdx.x == 0)      { cnt = c1; offs = o1; cur = u1; M = m1; }
  else if (blockIdx.x == 1) { cnt = c2; offs = o2; cur = u2; M = m2; }
  else                      { cnt = c3; offs = o3; cur = u3; M = m3; }
  __shared__ int ps[256];
  const int tid = threadIdx.x;
  const int per = (M + 255) >> 8;
  const int base = tid * per;
  int s = 0;
  for (int j = 0; j < per; ++j) if (base + j < M) s += cnt[base + j];
  ps[tid] = s;
  __syncthreads();
  for (int off = 1; off < 256; off <<= 1) {
    int v = (tid >= off) ? ps[tid - off] : 0;
    __syncthreads();
    ps[tid] += v;
    __syncthreads();
  }
  int run = (tid > 0) ? ps[tid - 1] : 0;
  for (int j = 0; j < per; ++j) {
    if (base + j < M) {
      offs[base + j] = run; cur[base + j] = run;
      run += cnt[base + j];
    }
  }
  if (tid == 255) offs[M] = run;
}

// ---- scatter: sorted float4(x,y,z,sx) + original index -------------------
__global__ __launch_bounds__(256) void scatter3_kernel(
    const float* __restrict__ p1, int n1, int g1, int* __restrict__ u1, float4* __restrict__ s1, int* __restrict__ x1,
    const float* __restrict__ p2, int n2, int g2, int* __restrict__ u2, float4* __restrict__ s2, int* __restrict__ x2,
    const float* __restrict__ p3, int n3, int g3, int* __restrict__ u3, float4* __restrict__ s3, int* __restrict__ x3)
{
  #pragma clang fp contract(off)
  int b = blockIdx.x;
  const float* p; int n, G; int* cur; float4* spts; int* sidx; int i;
  if (b < 64)      { p = p1; n = n1; G = g1; cur = u1; spts = s1; sidx = x1; i = b * 256 + threadIdx.x; }
  else if (b < 80) { p = p2; n = n2; G = g2; cur = u2; spts = s2; sidx = x2; i = (b - 64) * 256 + threadIdx.x; }
  else             { p = p3; n = n3; G = g3; cur = u3; spts = s3; sidx = x3; i = (b - 80) * 256 + threadIdx.x; }
  if (i >= n) return;
  float x = p[3 * i], y = p[3 * i + 1], z = p[3 * i + 2];
  int cx = cell_clamp(x, G), cy = cell_clamp(y, G), cz = cell_clamp(z, G);
  int c = (cz * G + cy) * G + cx;
  int pos = atomicAdd(&cur[c], 1);
  float sx = (x * x + y * y) + z * z;   // sequential, no contraction
  spts[pos] = make_float4(x, y, z, sx);
  sidx[pos] = i;
}

// ---- query: 16 lanes per query, expanding Chebyshev shells ----------------
__global__ __launch_bounds__(256) void knn_wave_kernel(
    const float* __restrict__ qpos, int Nq, int G,
    const int* __restrict__ offs,
    const float4* __restrict__ spts,
    const int* __restrict__ sidx,
    int mode,
    const float* __restrict__ base3,
    const float* __restrict__ feat3,
    float* __restrict__ w_out, int* __restrict__ i_out,
    float* __restrict__ out3)
{
  #pragma clang fp contract(off)
  const int sl = threadIdx.x & 15;
  const int q = blockIdx.x * 16 + (threadIdx.x >> 4);
  if (q >= Nq) return;

  const float qx = qpos[3 * q], qy = qpos[3 * q + 1], qz = qpos[3 * q + 2];
  const float sy = (qx * qx + qy * qy) + qz * qz;  // sequential, no contraction
  const float cs = 1.0f / (float)G;
  const int cx = cell_clamp(qx, G), cy = cell_clamp(qy, G), cz = cell_clamp(qz, G);

  float d0 = BIGF, d1 = BIGF, d2v = BIGF;
  int i0 = -1, i1 = -1, i2 = -1;
  float e0 = BIGF, e1 = BIGF, e2 = BIGF;
  int j0 = -1, j1 = -1, j2 = -1;
  bool done = false;

  for (int R = 1; R <= G; ++R) {
    if (!done) {
      const int W = 2 * R + 1;
      const int ncells = W * W * W;
      for (int m = sl; m < ncells; m += 16) {
        int a = m % W;
        int t = m / W;
        int b = t % W;
        int c = t / W;
        int dx = a - R, dy = b - R, dz = c - R;
        int adx = dx < 0 ? -dx : dx, ady = dy < 0 ? -dy : dy, adz = dz < 0 ? -dz : dz;
        int cheb = max(adx, max(ady, adz));
        if (R > 1 && cheb < R) continue;
        int xx = cx + dx, yy = cy + dy, zz = cz + dz;
        if (xx < 0 || xx >= G || yy < 0 || yy >= G || zz < 0 || zz >= G) continue;
        int cell = (zz * G + yy) * G + xx;
        int js = offs[cell], je = offs[cell + 1];
        for (int j = js; j < je; ++j) {
          float4 s = spts[j];
          float p0 = qx * s.x, p1 = qy * s.y, p2 = qz * s.z;
          float dt = (p0 + p1) + p2;
          float S  = sy + s.w;
          float dd = S - 2.0f * dt;
          ins3(dd, sidx[j], d0, d1, d2v, i0, i1, i2);
        }
      }
    }
    e0 = d0; e1 = d1; e2 = d2v; j0 = i0; j1 = i1; j2 = i2;
    #pragma unroll
    for (int msk = 1; msk < 16; msk <<= 1) {
      float o0 = __shfl_xor(e0, msk), o1 = __shfl_xor(e1, msk), o2 = __shfl_xor(e2, msk);
      int   p0 = __shfl_xor(j0, msk), p1 = __shfl_xor(j1, msk), p2 = __shfl_xor(j2, msk);
      ins3(o0, p0, e0, e1, e2, j0, j1, j2);
      ins3(o1, p1, e0, e1, e2, j0, j1, j2);
      ins3(o2, p2, e0, e1, e2, j0, j1, j2);
    }
    float bnd = (float)R * cs;
    done = done || (e2 <= bnd * bnd - 1e-6f);
    if (__all(done)) break;
  }

  if (sl == 0) {
    float w0 = 1.0f / fmaxf(e0, 1e-16f);
    float w1 = 1.0f / fmaxf(e1, 1e-16f);
    float w2 = 1.0f / fmaxf(e2, 1e-16f);
    float inv = 1.0f / (w0 + w1 + w2);
    w0 *= inv; w1 *= inv; w2 *= inv;
    if (mode == 0) {
      w_out[(size_t)q * 3 + 0] = w0; w_out[(size_t)q * 3 + 1] = w1; w_out[(size_t)q * 3 + 2] = w2;
      i_out[(size_t)q * 3 + 0] = j0; i_out[(size_t)q * 3 + 1] = j1; i_out[(size_t)q * 3 + 2] = j2;
    } else {
      #pragma unroll
      for (int f = 0; f < 3; ++f) {
        float v = w0 * feat3[(size_t)j0 * 3 + f]
                + w1 * feat3[(size_t)j1 * 3 + f]
                + w2 * feat3[(size_t)j2 * 3 + f];
        out3[(size_t)q * 3 + f] = (mode == 1) ? (base3[(size_t)q * 3 + f] - v) : v;
      }
    }
  }
}

// ---------------------------------------------------------------------------
// t[q, :] = emb1[q, :] - sum_k w_k * emb2[idx_k, :]     (F = 256, float4)
// ---------------------------------------------------------------------------
__global__ __launch_bounds__(256) void build_t_kernel(
    const float* __restrict__ emb1, const float* __restrict__ emb2,
    const float* __restrict__ w, const int* __restrict__ idx,
    float* __restrict__ t, int Nq)
{
  int gid = blockIdx.x * 256 + threadIdx.x;
  int q = gid >> 6, c4 = gid & 63;
  if (q >= Nq) return;
  float w0 = w[(size_t)q * 3 + 0], w1 = w[(size_t)q * 3 + 1], w2 = w[(size_t)q * 3 + 2];
  int i0 = idx[(size_t)q * 3 + 0], i1 = idx[(size_t)q * 3 + 1], i2 = idx[(size_t)q * 3 + 2];
  const float4* e1 = (const float4*)emb1;
  const float4* e2 = (const float4*)emb2;
  float4 a  = e1[(size_t)q * 64 + c4];
  float4 f0 = e2[(size_t)i0 * 64 + c4];
  float4 f1 = e2[(size_t)i1 * 64 + c4];
  float4 f2 = e2[(size_t)i2 * 64 + c4];
  float4 r;
  r.x = a.x - (w0 * f0.x + w1 * f1.x + w2 * f2.x);
  r.y = a.y - (w0 * f0.y + w1 * f1.y + w2 * f2.y);
  r.z = a.z - (w0 * f0.z + w1 * f1.z + w2 * f2.z);
  r.w = a.w - (w0 * f0.w + w1 * f1.w + w2 * f2.w);
  ((float4*)t)[(size_t)q * 64 + c4] = r;
}

// ---------------------------------------------------------------------------
// C = act(A[M,K] @ W[K,N] + b), fp32 vector GEMM.
// 64x64 tile, ONE 64-lane wave per block, 8x8 micro-tile, BK=32.
// 8x8 micro => 64 FMA per 4 ds_read_b128 per k: LDS-unit vs SIMD balanced at
// 4 blocks/CU (grid 1024). Next k-tile's global loads issue before the
// compute loop (latency hidden under 4096 FMA cycles).
// FMA K-order identical to rounds 8-10 (ascending k, one fmaf chain/output).
// ---------------------------------------------------------------------------
#define TBM 64
#define TBN 64
#define TBK 32
__global__ __launch_bounds__(64) void gemm_bias_act_kernel(
    const float* __restrict__ A, const float* __restrict__ W,
    const float* __restrict__ bias, float* __restrict__ C,
    int M, int N, int K, int relu)
{
  __shared__ float As[TBK][68];   // transposed A tile; 68 % 32 == 4 pad
  __shared__ float Bs[TBK][68];
  const int tid = threadIdx.x;    // 0..63
  const int row0 = blockIdx.x * TBM;
  const int col0 = blockIdx.y * TBN;
  const int ty = tid >> 3, tx = tid & 7;   // 8x8 threads, 8x8 outputs each

  float acc[8][8];
  #pragma unroll
  for (int i = 0; i < 8; ++i)
    #pragma unroll
    for (int j = 0; j < 8; ++j) acc[i][j] = 0.0f;

  float4 av[8], bv[8];
  // slot s = tid + 64*i over 512 float4: A row = s>>3, c4 = (s&7)*4
  //                                      B row = s>>4, c4 = (s&15)*4
  #pragma unroll
  for (int i = 0; i < 8; ++i) {
    int s = tid + (i << 6);
    av[i] = *(const float4*)&A[(size_t)(row0 + (s >> 3)) * K + ((s & 7) << 2)];
    bv[i] = *(const float4*)&W[(size_t)(s >> 4) * N + col0 + ((s & 15) << 2)];
  }

  for (int k0 = 0; k0 < K; k0 += TBK) {
    __syncthreads();
    #pragma unroll
    for (int i = 0; i < 8; ++i) {
      int s = tid + (i << 6);
      int ar = s >> 3, ac = (s & 7) << 2;
      As[ac + 0][ar] = av[i].x;
      As[ac + 1][ar] = av[i].y;
      As[ac + 2][ar] = av[i].z;
      As[ac + 3][ar] = av[i].w;
      *(float4*)&Bs[s >> 4][(s & 15) << 2] = bv[i];
    }
    __syncthreads();
    if (k0 + TBK < K) {
      int k1 = k0 + TBK;
      #pragma unroll
      for (int i = 0; i < 8; ++i) {
        int s = tid + (i << 6);
        av[i] = *(const float4*)&A[(size_t)(row0 + (s >> 3)) * K + k1 + ((s & 7) << 2)];
        bv[i] = *(const float4*)&W[(size_t)(k1 + (s >> 4)) * N + col0 + ((s & 15) << 2)];
      }
    }
    #pragma unroll
    for (int k = 0; k < TBK; ++k) {
      float a[8], b[8];
      *(float4*)&a[0] = *(const float4*)&As[k][ty * 8 + 0];
      *(float4*)&a[4] = *(const float4*)&As[k][ty * 8 + 4];
      *(float4*)&b[0] = *(const float4*)&Bs[k][tx * 8 + 0];
      *(float4*)&b[4] = *(const float4*)&Bs[k][tx * 8 + 4];
      #pragma unroll
      for (int i = 0; i < 8; ++i)
        #pragma unroll
        for (int j = 0; j < 8; ++j)
          acc[i][j] = fmaf(a[i], b[j], acc[i][j]);
    }
  }

  #pragma unroll
  for (int i = 0; i < 8; ++i) {
    size_t r = (size_t)(row0 + ty * 8 + i);
    int c = col0 + tx * 8;
    float4 v0, v1;
    v0.x = acc[i][0] + bias[c + 0];
    v0.y = acc[i][1] + bias[c + 1];
    v0.z = acc[i][2] + bias[c + 2];
    v0.w = acc[i][3] + bias[c + 3];
    v1.x = acc[i][4] + bias[c + 4];
    v1.y = acc[i][5] + bias[c + 5];
    v1.z = acc[i][6] + bias[c + 6];
    v1.w = acc[i][7] + bias[c + 7];
    if (relu) {
      v0.x = fmaxf(v0.x, 0.0f); v0.y = fmaxf(v0.y, 0.0f);
      v0.z = fmaxf(v0.z, 0.0f); v0.w = fmaxf(v0.w, 0.0f);
      v1.x = fmaxf(v1.x, 0.0f); v1.y = fmaxf(v1.y, 0.0f);
      v1.z = fmaxf(v1.z, 0.0f); v1.w = fmaxf(v1.w, 0.0f);
    }
    *(float4*)&C[r * N + c] = v0;
    *(float4*)&C[r * N + c + 4] = v1;
  }
}

// ---------------------------------------------------------------------------
// out[r, :] = h2[r, :] @ W3[256,3] + b3 + res[r, :]   (wave per row)
// ---------------------------------------------------------------------------
__global__ __launch_bounds__(256) void final_kernel(
    const float* __restrict__ h2, const float* __restrict__ W3,
    const float* __restrict__ b3, const float* __restrict__ res,
    float* __restrict__ out, int M)
{
  __shared__ float sW3[768];
  const int tid = threadIdx.x;
  for (int i = tid; i < 768; i += 256) sW3[i] = W3[i];
  __syncthreads();

  const int wave = tid >> 6, lane = tid & 63;
  const int r = blockIdx.x * 4 + wave;
  if (r >= M) return;

  float4 h = ((const float4*)h2)[(size_t)r * 64 + lane];
  const int c = lane * 4;
  float a0 = h.x * sW3[(c + 0) * 3 + 0] + h.y * sW3[(c + 1) * 3 + 0]
           + h.z * sW3[(c + 2) * 3 + 0] + h.w * sW3[(c + 3) * 3 + 0];
  float a1 = h.x * sW3[(c + 0) * 3 + 1] + h.y * sW3[(c + 1) * 3 + 1]
           + h.z * sW3[(c + 2) * 3 + 1] + h.w * sW3[(c + 3) * 3 + 1];
  float a2 = h.x * sW3[(c + 0) * 3 + 2] + h.y * sW3[(c + 1) * 3 + 2]
           + h.z * sW3[(c + 2) * 3 + 2] + h.w * sW3[(c + 3) * 3 + 2];

  #pragma unroll
  for (int off = 32; off; off >>= 1) {
    a0 += __shfl_xor(a0, off);
    a1 += __shfl_xor(a1, off);
    a2 += __shfl_xor(a2, off);
  }
  if (lane == 0) {
    out[(size_t)r * 3 + 0] = a0 + b3[0] + res[(size_t)r * 3 + 0];
    out[(size_t)r * 3 + 1] = a1 + b3[1] + res[(size_t)r * 3 + 1];
    out[(size_t)r * 3 + 2] = a2 + b3[2] + res[(size_t)r * 3 + 2];
  }
}

// ---------------------------------------------------------------------------
extern "C" void kernel_launch(void* const* d_in, const int* in_sizes, int n_in,
                              void* d_out, int out_size, void* d_ws, size_t ws_size,
                              hipStream_t stream) {
  (void)in_sizes; (void)n_in; (void)out_size; (void)ws_size;
  const float* emb1   = (const float*)d_in[0];
  const float* l_y1   = (const float*)d_in[1];
  const float* l_pos1 = (const float*)d_in[2];
  const float* h_pos1 = (const float*)d_in[3];
  const float* emb2   = (const float*)d_in[4];
  const float* l_y2   = (const float*)d_in[5];
  const float* l_pos2 = (const float*)d_in[6];
  const float* h_pos2 = (const float*)d_in[7];
  const float* W1     = (const float*)d_in[8];
  const float* b1     = (const float*)d_in[9];
  const float* W2     = (const float*)d_in[10];
  const float* b2     = (const float*)d_in[11];
  const float* W3     = (const float*)d_in[12];
  const float* b3     = (const float*)d_in[13];
  float* out = (float*)d_out;

  const int Nh = 16384, Nl = 4096, H = 256;
  const int G1 = 16, G2 = 10;
  const int M1 = G1 * G1 * G1, M2 = G2 * G2 * G2;

  // ---- workspace carve-up (sequential bump allocator, 256B aligned) ----
  char* wsp = (char*)d_ws;
  size_t off = 0;
  auto alloc = [&](size_t bytes) -> void* {
    void* p = wsp + off;
    off += (bytes + 255) & ~(size_t)255;
    return p;
  };
  int*    idxA    = (int*)   alloc((size_t)Nh * 3 * 4);
  float*  wA      = (float*) alloc((size_t)Nh * 3 * 4);
  float*  tbuf    = (float*) alloc((size_t)Nh * H * 4);   // 16 MB (also h2)
  float*  h1      = (float*) alloc((size_t)Nh * H * 4);   // 16 MB
  float*  h2      = tbuf;
  float*  diff    = (float*) alloc((size_t)Nl * 3 * 4);
  float*  res     = (float*) alloc((size_t)Nh * 3 * 4);
  int*    cnts    = (int*)   alloc((size_t)(M1 + M2 + M2) * 4);
  int*    cnt1 = cnts, *cnt2 = cnts + M1, *cnt3 = cnts + M1 + M2;
  int*    offs1   = (int*)   alloc((size_t)(M1 + 1) * 4);
  int*    cur1    = (int*)   alloc((size_t)M1 * 4);
  int*    offs2   = (int*)   alloc((size_t)(M2 + 1) * 4);
  int*    cur2    = (int*)   alloc((size_t)M2 * 4);
  int*    offs3   = (int*)   alloc((size_t)(M2 + 1) * 4);
  int*    cur3    = (int*)   alloc((size_t)M2 * 4);
  float4* spts1   = (float4*)alloc((size_t)Nh * 16);
  int*    sidx1   = (int*)   alloc((size_t)Nh * 4);
  float4* spts2   = (float4*)alloc((size_t)Nl * 16);
  int*    sidx2   = (int*)   alloc((size_t)Nl * 4);
  float4* spts3   = (float4*)alloc((size_t)Nl * 16);
  int*    sidx3   = (int*)   alloc((size_t)Nl * 4);

  // ---- build the 3 source grids ----
  const int ncnt = M1 + M2 + M2;
  zero_kernel<<<(ncnt + 255) / 256, 256, 0, stream>>>(cnts, ncnt);
  cell_count3_kernel<<<96, 256, 0, stream>>>(
      h_pos2, Nh, G1, cnt1,  l_pos2, Nl, G2, cnt2,  l_pos1, Nl, G2, cnt3);
  prefix3_kernel<<<3, 256, 0, stream>>>(
      cnt1, offs1, cur1, M1,  cnt2, offs2, cur2, M2,  cnt3, offs3, cur3, M2);
  scatter3_kernel<<<96, 256, 0, stream>>>(
      h_pos2, Nh, G1, cur1, spts1, sidx1,
      l_pos2, Nl, G2, cur2, spts2, sidx2,
      l_pos1, Nl, G2, cur3, spts3, sidx3);

  // ---- branch 1: x = mlp(emb1 - interp(emb2; h_pos2 -> h_pos1)) ----
  knn_wave_kernel<<<Nh / 16, 256, 0, stream>>>(
      h_pos1, Nh, G1, offs1, spts1, sidx1,
      0, nullptr, nullptr, wA, idxA, nullptr);
  build_t_kernel<<<Nh * 64 / 256, 256, 0, stream>>>(
      emb1, emb2, wA, idxA, tbuf, Nh);
  gemm_bias_act_kernel<<<dim3(Nh / TBM, H / TBN), 64, 0, stream>>>(
      tbuf, W1, b1, h1, Nh, H, H, 1);
  gemm_bias_act_kernel<<<dim3(Nh / TBM, H / TBN), 64, 0, stream>>>(
      h1, W2, b2, h2, Nh, H, H, 1);

  // ---- branch 2: res = interp(l_y1 - interp(l_y2; l_pos2->l_pos1); l_pos1->h_pos1) ----
  knn_wave_kernel<<<Nl / 16, 256, 0, stream>>>(
      l_pos1, Nl, G2, offs2, spts2, sidx2,
      1, l_y1, l_y2, nullptr, nullptr, diff);
  knn_wave_kernel<<<Nh / 16, 256, 0, stream>>>(
      h_pos1, Nh, G2, offs3, spts3, sidx3,
      2, nullptr, diff, nullptr, nullptr, res);

  // ---- final: out = (h2 @ W3 + b3) + res ----
  final_kernel<<<Nh / 4, 256, 0, stream>>>(h2, W3, b3, res, out, Nh);
}

// Round 12
// 183.204 us; speedup vs baseline: 1.2492x; 1.2492x over previous
//
#include <hip/hip_runtime.h>
#include <math.h>

#define BIGF 3.0e38f

typedef short  s16x8 __attribute__((ext_vector_type(8)));
typedef float  f32x4 __attribute__((ext_vector_type(4)));

// bf16 helpers (manual RNE; storage = ushort, no __bf16 type dependency)
__device__ __forceinline__ unsigned short f2bf(float x) {
  unsigned int b = __float_as_uint(x);
  unsigned int r = b + 0x7FFFu + ((b >> 16) & 1u);
  return (unsigned short)(r >> 16);
}
__device__ __forceinline__ float bf2f(unsigned short h) {
  return __uint_as_float(((unsigned int)h) << 16);
}

// ===========================================================================
// Spatial-hash KNN (K=3), 16 lanes per query.
// Selection must replicate the np reference's fp32 expansion distance:
//   sx  = (x*x + y*y) + z*z            (sequential, individually rounded)
//   dot = (p0 + p1) + p2, p_k = q_k*s_k
//   d2  = (sy + sx) - 2*dot
// evaluated with fp contract(off) — verified rounds 3-6. DO NOT TOUCH.
// Tie-break: lexicographic (d, idx) == stable top_k smallest-index-first.
// ===========================================================================

__device__ __forceinline__ int cell_clamp(float v, int G) {
  int c = (int)(v * (float)G);
  return min(G - 1, max(0, c));
}

__device__ __forceinline__ void ins3(float d, int id,
                                     float& d0, float& d1, float& d2,
                                     int& i0, int& i1, int& i2) {
  bool l0 = (d < d0) || (d == d0 && id < i0);
  bool l1 = (d < d1) || (d == d1 && id < i1);
  bool l2 = (d < d2) || (d == d2 && id < i2);
  float nd0 = l0 ? d  : d0;  int ni0 = l0 ? id : i0;
  float nd1 = l0 ? d0 : (l1 ? d  : d1);
  int   ni1 = l0 ? i0 : (l1 ? id : i1);
  float nd2 = l1 ? d1 : (l2 ? d  : d2);
  int   ni2 = l1 ? i1 : (l2 ? id : i2);
  d0 = nd0; d1 = nd1; d2 = nd2; i0 = ni0; i1 = ni1; i2 = ni2;
}

__global__ __launch_bounds__(256) void zero_kernel(int* __restrict__ p, int n) {
  int i = blockIdx.x * 256 + threadIdx.x;
  if (i < n) p[i] = 0;
}

__global__ __launch_bounds__(256) void cell_count3_kernel(
    const float* __restrict__ p1, int n1, int g1, int* __restrict__ c1,
    const float* __restrict__ p2, int n2, int g2, int* __restrict__ c2,
    const float* __restrict__ p3, int n3, int g3, int* __restrict__ c3)
{
  int b = blockIdx.x;
  const float* p; int n, G; int* cnt; int i;
  if (b < 64)      { p = p1; n = n1; G = g1; cnt = c1; i = b * 256 + threadIdx.x; }
  else if (b < 80) { p = p2; n = n2; G = g2; cnt = c2; i = (b - 64) * 256 + threadIdx.x; }
  else             { p = p3; n = n3; G = g3; cnt = c3; i = (b - 80) * 256 + threadIdx.x; }
  if (i >= n) return;
  int cx = cell_clamp(p[3 * i],     G);
  int cy = cell_clamp(p[3 * i + 1], G);
  int cz = cell_clamp(p[3 * i + 2], G);
  atomicAdd(&cnt[(cz * G + cy) * G + cx], 1);
}

__global__ __launch_bounds__(256) void prefix3_kernel(
    const int* __restrict__ c1, int* __restrict__ o1, int* __restrict__ u1, int m1,
    const int* __restrict__ c2, int* __restrict__ o2, int* __restrict__ u2, int m2,
    const int* __restrict__ c3, int* __restrict__ o3, int* __restrict__ u3, int m3)
{
  const int* cnt; int* offs; int* cur; int M;
  if (blockIdx.x == 0)      { cnt = c1; offs = o1; cur = u1; M = m1; }
  else if (blockIdx.x == 1) { cnt = c2; offs = o2; cur = u2; M = m2; }
  else                      { cnt = c3; offs = o3; cur = u3; M = m3; }
  __shared__ int ps[256];
  const int tid = threadIdx.x;
  const int per = (M + 255) >> 8;
  const int base = tid * per;
  int s = 0;
  for (int j = 0; j < per; ++j) if (base + j < M) s += cnt[base + j];
  ps[tid] = s;
  __syncthreads();
  for (int off = 1; off < 256; off <<= 1) {
    int v = (tid >= off) ? ps[tid - off] : 0;
    __syncthreads();
    ps[tid] += v;
    __syncthreads();
  }
  int run = (tid > 0) ? ps[tid - 1] : 0;
  for (int j = 0; j < per; ++j) {
    if (base + j < M) {
      offs[base + j] = run; cur[base + j] = run;
      run += cnt[base + j];
    }
  }
  if (tid == 255) offs[M] = run;
}

__global__ __launch_bounds__(256) void scatter3_kernel(
    const float* __restrict__ p1, int n1, int g1, int* __restrict__ u1, float4* __restrict__ s1, int* __restrict__ x1,
    const float* __restrict__ p2, int n2, int g2, int* __restrict__ u2, float4* __restrict__ s2, int* __restrict__ x2,
    const float* __restrict__ p3, int n3, int g3, int* __restrict__ u3, float4* __restrict__ s3, int* __restrict__ x3)
{
  #pragma clang fp contract(off)
  int b = blockIdx.x;
  const float* p; int n, G; int* cur; float4* spts; int* sidx; int i;
  if (b < 64)      { p = p1; n = n1; G = g1; cur = u1; spts = s1; sidx = x1; i = b * 256 + threadIdx.x; }
  else if (b < 80) { p = p2; n = n2; G = g2; cur = u2; spts = s2; sidx = x2; i = (b - 64) * 256 + threadIdx.x; }
  else             { p = p3; n = n3; G = g3; cur = u3; spts = s3; sidx = x3; i = (b - 80) * 256 + threadIdx.x; }
  if (i >= n) return;
  float x = p[3 * i], y = p[3 * i + 1], z = p[3 * i + 2];
  int cx = cell_clamp(x, G), cy = cell_clamp(y, G), cz = cell_clamp(z, G);
  int c = (cz * G + cy) * G + cx;
  int pos = atomicAdd(&cur[c], 1);
  float sx = (x * x + y * y) + z * z;   // sequential, no contraction
  spts[pos] = make_float4(x, y, z, sx);
  sidx[pos] = i;
}

__global__ __launch_bounds__(256) void knn_wave_kernel(
    const float* __restrict__ qpos, int Nq, int G,
    const int* __restrict__ offs,
    const float4* __restrict__ spts,
    const int* __restrict__ sidx,
    int mode,
    const float* __restrict__ base3,
    const float* __restrict__ feat3,
    float* __restrict__ w_out, int* __restrict__ i_out,
    float* __restrict__ out3)
{
  #pragma clang fp contract(off)
  const int sl = threadIdx.x & 15;
  const int q = blockIdx.x * 16 + (threadIdx.x >> 4);
  if (q >= Nq) return;

  const float qx = qpos[3 * q], qy = qpos[3 * q + 1], qz = qpos[3 * q + 2];
  const float sy = (qx * qx + qy * qy) + qz * qz;  // sequential, no contraction
  const float cs = 1.0f / (float)G;
  const int cx = cell_clamp(qx, G), cy = cell_clamp(qy, G), cz = cell_clamp(qz, G);

  float d0 = BIGF, d1 = BIGF, d2v = BIGF;
  int i0 = -1, i1 = -1, i2 = -1;
  float e0 = BIGF, e1 = BIGF, e2 = BIGF;
  int j0 = -1, j1 = -1, j2 = -1;
  bool done = false;

  for (int R = 1; R <= G; ++R) {
    if (!done) {
      const int W = 2 * R + 1;
      const int ncells = W * W * W;
      for (int m = sl; m < ncells; m += 16) {
        int a = m % W;
        int t = m / W;
        int b = t % W;
        int c = t / W;
        int dx = a - R, dy = b - R, dz = c - R;
        int adx = dx < 0 ? -dx : dx, ady = dy < 0 ? -dy : dy, adz = dz < 0 ? -dz : dz;
        int cheb = max(adx, max(ady, adz));
        if (R > 1 && cheb < R) continue;
        int xx = cx + dx, yy = cy + dy, zz = cz + dz;
        if (xx < 0 || xx >= G || yy < 0 || yy >= G || zz < 0 || zz >= G) continue;
        int cell = (zz * G + yy) * G + xx;
        int js = offs[cell], je = offs[cell + 1];
        for (int j = js; j < je; ++j) {
          float4 s = spts[j];
          float p0 = qx * s.x, p1 = qy * s.y, p2 = qz * s.z;
          float dt = (p0 + p1) + p2;
          float S  = sy + s.w;
          float dd = S - 2.0f * dt;
          ins3(dd, sidx[j], d0, d1, d2v, i0, i1, i2);
        }
      }
    }
    e0 = d0; e1 = d1; e2 = d2v; j0 = i0; j1 = i1; j2 = i2;
    #pragma unroll
    for (int msk = 1; msk < 16; msk <<= 1) {
      float o0 = __shfl_xor(e0, msk), o1 = __shfl_xor(e1, msk), o2 = __shfl_xor(e2, msk);
      int   p0 = __shfl_xor(j0, msk), p1 = __shfl_xor(j1, msk), p2 = __shfl_xor(j2, msk);
      ins3(o0, p0, e0, e1, e2, j0, j1, j2);
      ins3(o1, p1, e0, e1, e2, j0, j1, j2);
      ins3(o2, p2, e0, e1, e2, j0, j1, j2);
    }
    float bnd = (float)R * cs;
    done = done || (e2 <= bnd * bnd - 1e-6f);
    if (__all(done)) break;
  }

  if (sl == 0) {
    float w0 = 1.0f / fmaxf(e0, 1e-16f);
    float w1 = 1.0f / fmaxf(e1, 1e-16f);
    float w2 = 1.0f / fmaxf(e2, 1e-16f);
    float inv = 1.0f / (w0 + w1 + w2);
    w0 *= inv; w1 *= inv; w2 *= inv;
    if (mode == 0) {
      w_out[(size_t)q * 3 + 0] = w0; w_out[(size_t)q * 3 + 1] = w1; w_out[(size_t)q * 3 + 2] = w2;
      i_out[(size_t)q * 3 + 0] = j0; i_out[(size_t)q * 3 + 1] = j1; i_out[(size_t)q * 3 + 2] = j2;
    } else {
      #pragma unroll
      for (int f = 0; f < 3; ++f) {
        float v = w0 * feat3[(size_t)j0 * 3 + f]
                + w1 * feat3[(size_t)j1 * 3 + f]
                + w2 * feat3[(size_t)j2 * 3 + f];
        out3[(size_t)q * 3 + f] = (mode == 1) ? (base3[(size_t)q * 3 + f] - v) : v;
      }
    }
  }
}

// ---------------------------------------------------------------------------
// W [256 K][256 N] fp32 -> transposed bf16 splits WT_hi/WT_lo [n][k]
// ---------------------------------------------------------------------------
__global__ __launch_bounds__(256) void split_wt_kernel(
    const float* __restrict__ W,
    unsigned short* __restrict__ hiT, unsigned short* __restrict__ loT)
{
  int id = blockIdx.x * 256 + threadIdx.x;   // 65536
  int k = id >> 8, n = id & 255;
  float x = W[id];
  unsigned short h = f2bf(x);
  unsigned short l = f2bf(x - bf2f(h));
  hiT[n * 256 + k] = h;
  loT[n * 256 + k] = l;
}

// ---------------------------------------------------------------------------
// t = emb1 - interp(emb2), emitted directly as bf16 hi/lo splits
// ---------------------------------------------------------------------------
__global__ __launch_bounds__(256) void build_t_kernel(
    const float* __restrict__ emb1, const float* __restrict__ emb2,
    const float* __restrict__ w, const int* __restrict__ idx,
    unsigned short* __restrict__ t_hi, unsigned short* __restrict__ t_lo, int Nq)
{
  int gid = blockIdx.x * 256 + threadIdx.x;
  int q = gid >> 6, c4 = gid & 63;
  if (q >= Nq) return;
  float w0 = w[(size_t)q * 3 + 0], w1 = w[(size_t)q * 3 + 1], w2 = w[(size_t)q * 3 + 2];
  int i0 = idx[(size_t)q * 3 + 0], i1 = idx[(size_t)q * 3 + 1], i2 = idx[(size_t)q * 3 + 2];
  const float4* e1 = (const float4*)emb1;
  const float4* e2 = (const float4*)emb2;
  float4 a  = e1[(size_t)q * 64 + c4];
  float4 f0 = e2[(size_t)i0 * 64 + c4];
  float4 f1 = e2[(size_t)i1 * 64 + c4];
  float4 f2 = e2[(size_t)i2 * 64 + c4];
  float4 r;
  r.x = a.x - (w0 * f0.x + w1 * f1.x + w2 * f2.x);
  r.y = a.y - (w0 * f0.y + w1 * f1.y + w2 * f2.y);
  r.z = a.z - (w0 * f0.z + w1 * f1.z + w2 * f2.z);
  r.w = a.w - (w0 * f0.w + w1 * f1.w + w2 * f2.w);
  ushort4 h, l;
  h.x = f2bf(r.x); l.x = f2bf(r.x - bf2f(h.x));
  h.y = f2bf(r.y); l.y = f2bf(r.y - bf2f(h.y));
  h.z = f2bf(r.z); l.z = f2bf(r.z - bf2f(h.z));
  h.w = f2bf(r.w); l.w = f2bf(r.w - bf2f(h.w));
  size_t o = (size_t)q * 256 + c4 * 4;
  *(ushort4*)&t_hi[o] = h;
  *(ushort4*)&t_lo[o] = l;
}

// ---------------------------------------------------------------------------
// bf16x3-split MFMA GEMM: C = act(A @ W + b), A [M][256], W via WT splits.
// acc += A_hi*W_hi + A_lo*W_hi + A_hi*W_lo  (fp32 accum; ~1e-5 rel error).
// Block: 256 thr = 4 waves; tile 64 rows x 64 cols (wave w: rows w*16..+16,
// 4 col-tiles of 16). K staged in LDS in 2 halves of 128 (33.8 KB).
// mfma_f32_16x16x32_bf16 fragments: A[l&15][8*(l>>4)+j], B[8*(l>>4)+j][l&15],
// D[4*(l>>4)+r][l&15]  (D verified learn_hip m89/m91).
// XCD-grouped swizzle: each XCD owns a 2 MB contiguous A-row range (L2-fit).
// ---------------------------------------------------------------------------
__global__ __launch_bounds__(256) void mfma_gemm_kernel(
    const unsigned short* __restrict__ A_hi, const unsigned short* __restrict__ A_lo,
    const unsigned short* __restrict__ BT_hi, const unsigned short* __restrict__ BT_lo,
    const float* __restrict__ bias,
    float* __restrict__ outf,
    unsigned short* __restrict__ out_hi, unsigned short* __restrict__ out_lo,
    int relu, int split_out)
{
  __shared__ unsigned short Bs_hi[64][132];
  __shared__ unsigned short Bs_lo[64][132];
  const int t = threadIdx.x;
  const int d = blockIdx.x;
  const int xcd = d & 7, slot = d >> 3;
  const int lin = xcd * ((int)gridDim.x >> 3) + slot;
  const int row0 = (lin >> 2) * 64;
  const int col0 = (lin & 3) * 64;

  const int l = t & 63, w = t >> 6;
  const int lr = l & 15;
  const int lk = (l >> 4) << 3;
  const unsigned short* arh = A_hi + (size_t)(row0 + w * 16 + lr) * 256;
  const unsigned short* arl = A_lo + (size_t)(row0 + w * 16 + lr) * 256;

  const int sc = t >> 2;               // staging: col 0..63
  const int sk = (t & 3) << 5;         // 32 k-elements per thread

  f32x4 acc0 = {0.f,0.f,0.f,0.f}, acc1 = {0.f,0.f,0.f,0.f};
  f32x4 acc2 = {0.f,0.f,0.f,0.f}, acc3 = {0.f,0.f,0.f,0.f};

  #define KSTEP(CT, ACC)                                                      \
    { s16x8 bh = *(const s16x8*)&Bs_hi[CT * 16 + lr][kc + lk];                \
      s16x8 bl = *(const s16x8*)&Bs_lo[CT * 16 + lr][kc + lk];                \
      ACC = __builtin_amdgcn_mfma_f32_16x16x32_bf16(ah, bh, ACC, 0, 0, 0);    \
      ACC = __builtin_amdgcn_mfma_f32_16x16x32_bf16(al, bh, ACC, 0, 0, 0);    \
      ACC = __builtin_amdgcn_mfma_f32_16x16x32_bf16(ah, bl, ACC, 0, 0, 0); }

  for (int half = 0; half < 2; ++half) {
    if (half) __syncthreads();
    {
      const int4* sh = (const int4*)&BT_hi[(size_t)(col0 + sc) * 256 + half * 128 + sk];
      const int4* slo = (const int4*)&BT_lo[(size_t)(col0 + sc) * 256 + half * 128 + sk];
      int4* dh = (int4*)&Bs_hi[sc][sk];
      int4* dl = (int4*)&Bs_lo[sc][sk];
      #pragma unroll
      for (int i = 0; i < 4; ++i) { dh[i] = sh[i]; dl[i] = slo[i]; }
    }
    __syncthreads();
    const int kbase = half * 128;
    #pragma unroll
    for (int kc = 0; kc < 128; kc += 32) {
      s16x8 ah = *(const s16x8*)&arh[kbase + kc + lk];
      s16x8 al = *(const s16x8*)&arl[kbase + kc + lk];
      KSTEP(0, acc0)
      KSTEP(1, acc1)
      KSTEP(2, acc2)
      KSTEP(3, acc3)
    }
  }
  #undef KSTEP

  const int orow = row0 + w * 16 + ((l >> 4) << 2);
  #define EPILOG(CT, ACC)                                                     \
    { int col = col0 + CT * 16 + lr;                                          \
      float bb = bias[col];                                                   \
      _Pragma("unroll")                                                       \
      for (int r = 0; r < 4; ++r) {                                           \
        float v = ACC[r] + bb;                                                \
        if (relu) v = fmaxf(v, 0.0f);                                         \
        size_t o = (size_t)(orow + r) * 256 + col;                            \
        if (split_out) {                                                      \
          unsigned short hh = f2bf(v);                                        \
          out_hi[o] = hh; out_lo[o] = f2bf(v - bf2f(hh));                     \
        } else {                                                              \
          outf[o] = v;                                                        \
        }                                                                     \
      } }
  EPILOG(0, acc0)
  EPILOG(1, acc1)
  EPILOG(2, acc2)
  EPILOG(3, acc3)
  #undef EPILOG
}

// ---------------------------------------------------------------------------
// out[r, :] = h2[r, :] @ W3[256,3] + b3 + res[r, :]   (wave per row)
// ---------------------------------------------------------------------------
__global__ __launch_bounds__(256) void final_kernel(
    const float* __restrict__ h2, const float* __restrict__ W3,
    const float* __restrict__ b3, const float* __restrict__ res,
    float* __restrict__ out, int M)
{
  __shared__ float sW3[768];
  const int tid = threadIdx.x;
  for (int i = tid; i < 768; i += 256) sW3[i] = W3[i];
  __syncthreads();

  const int wave = tid >> 6, lane = tid & 63;
  const int r = blockIdx.x * 4 + wave;
  if (r >= M) return;

  float4 h = ((const float4*)h2)[(size_t)r * 64 + lane];
  const int c = lane * 4;
  float a0 = h.x * sW3[(c + 0) * 3 + 0] + h.y * sW3[(c + 1) * 3 + 0]
           + h.z * sW3[(c + 2) * 3 + 0] + h.w * sW3[(c + 3) * 3 + 0];
  float a1 = h.x * sW3[(c + 0) * 3 + 1] + h.y * sW3[(c + 1) * 3 + 1]
           + h.z * sW3[(c + 2) * 3 + 1] + h.w * sW3[(c + 3) * 3 + 1];
  float a2 = h.x * sW3[(c + 0) * 3 + 2] + h.y * sW3[(c + 1) * 3 + 2]
           + h.z * sW3[(c + 2) * 3 + 2] + h.w * sW3[(c + 3) * 3 + 2];

  #pragma unroll
  for (int off = 32; off; off >>= 1) {
    a0 += __shfl_xor(a0, off);
    a1 += __shfl_xor(a1, off);
    a2 += __shfl_xor(a2, off);
  }
  if (lane == 0) {
    out[(size_t)r * 3 + 0] = a0 + b3[0] + res[(size_t)r * 3 + 0];
    out[(size_t)r * 3 + 1] = a1 + b3[1] + res[(size_t)r * 3 + 1];
    out[(size_t)r * 3 + 2] = a2 + b3[2] + res[(size_t)r * 3 + 2];
  }
}

// ---------------------------------------------------------------------------
extern "C" void kernel_launch(void* const* d_in, const int* in_sizes, int n_in,
                              void* d_out, int out_size, void* d_ws, size_t ws_size,
                              hipStream_t stream) {
  (void)in_sizes; (void)n_in; (void)out_size; (void)ws_size;
  const float* emb1   = (const float*)d_in[0];
  const float* l_y1   = (const float*)d_in[1];
  const float* l_pos1 = (const float*)d_in[2];
  const float* h_pos1 = (const float*)d_in[3];
  const float* emb2   = (const float*)d_in[4];
  const float* l_y2   = (const float*)d_in[5];
  const float* l_pos2 = (const float*)d_in[6];
  const float* h_pos2 = (const float*)d_in[7];
  const float* W1     = (const float*)d_in[8];
  const float* b1     = (const float*)d_in[9];
  const float* W2     = (const float*)d_in[10];
  const float* b2     = (const float*)d_in[11];
  const float* W3     = (const float*)d_in[12];
  const float* b3     = (const float*)d_in[13];
  float* out = (float*)d_out;

  const int Nh = 16384, Nl = 4096, H = 256;
  const int G1 = 16, G2 = 10;
  const int M1 = G1 * G1 * G1, M2 = G2 * G2 * G2;

  // ---- workspace carve-up (sequential bump allocator, 256B aligned) ----
  char* wsp = (char*)d_ws;
  size_t off = 0;
  auto alloc = [&](size_t bytes) -> void* {
    void* p = wsp + off;
    off += (bytes + 255) & ~(size_t)255;
    return p;
  };
  int*            idxA   = (int*)           alloc((size_t)Nh * 3 * 4);
  float*          wA     = (float*)         alloc((size_t)Nh * 3 * 4);
  unsigned short* t_hi   = (unsigned short*)alloc((size_t)Nh * H * 2);  // 8 MB
  unsigned short* t_lo   = (unsigned short*)alloc((size_t)Nh * H * 2);  // 8 MB (adjacent)
  unsigned short* h1_hi  = (unsigned short*)alloc((size_t)Nh * H * 2);
  unsigned short* h1_lo  = (unsigned short*)alloc((size_t)Nh * H * 2);
  float*          h2     = (float*)t_hi;    // 16 MB alias over t_hi+t_lo (t dead)
  unsigned short* w1t_hi = (unsigned short*)alloc((size_t)H * H * 2);
  unsigned short* w1t_lo = (unsigned short*)alloc((size_t)H * H * 2);
  unsigned short* w2t_hi = (unsigned short*)alloc((size_t)H * H * 2);
  unsigned short* w2t_lo = (unsigned short*)alloc((size_t)H * H * 2);
  float*          diff   = (float*)         alloc((size_t)Nl * 3 * 4);
  float*          res    = (float*)         alloc((size_t)Nh * 3 * 4);
  int*            cnts   = (int*)           alloc((size_t)(M1 + M2 + M2) * 4);
  int*            cnt1 = cnts, *cnt2 = cnts + M1, *cnt3 = cnts + M1 + M2;
  int*            offs1  = (int*)           alloc((size_t)(M1 + 1) * 4);
  int*            cur1   = (int*)           alloc((size_t)M1 * 4);
  int*            offs2  = (int*)           alloc((size_t)(M2 + 1) * 4);
  int*            cur2   = (int*)           alloc((size_t)M2 * 4);
  int*            offs3  = (int*)           alloc((size_t)(M2 + 1) * 4);
  int*            cur3   = (int*)           alloc((size_t)M2 * 4);
  float4*         spts1  = (float4*)        alloc((size_t)Nh * 16);
  int*            sidx1  = (int*)           alloc((size_t)Nh * 4);
  float4*         spts2  = (float4*)        alloc((size_t)Nl * 16);
  int*            sidx2  = (int*)           alloc((size_t)Nl * 4);
  float4*         spts3  = (float4*)        alloc((size_t)Nl * 16);
  int*            sidx3  = (int*)           alloc((size_t)Nl * 4);

  // ---- build the 3 source grids + weight splits ----
  const int ncnt = M1 + M2 + M2;
  zero_kernel<<<(ncnt + 255) / 256, 256, 0, stream>>>(cnts, ncnt);
  cell_count3_kernel<<<96, 256, 0, stream>>>(
      h_pos2, Nh, G1, cnt1,  l_pos2, Nl, G2, cnt2,  l_pos1, Nl, G2, cnt3);
  prefix3_kernel<<<3, 256, 0, stream>>>(
      cnt1, offs1, cur1, M1,  cnt2, offs2, cur2, M2,  cnt3, offs3, cur3, M2);
  scatter3_kernel<<<96, 256, 0, stream>>>(
      h_pos2, Nh, G1, cur1, spts1, sidx1,
      l_pos2, Nl, G2, cur2, spts2, sidx2,
      l_pos1, Nl, G2, cur3, spts3, sidx3);
  split_wt_kernel<<<H * H / 256, 256, 0, stream>>>(W1, w1t_hi, w1t_lo);
  split_wt_kernel<<<H * H / 256, 256, 0, stream>>>(W2, w2t_hi, w2t_lo);

  // ---- branch 1: x = mlp(emb1 - interp(emb2; h_pos2 -> h_pos1)) ----
  knn_wave_kernel<<<Nh / 16, 256, 0, stream>>>(
      h_pos1, Nh, G1, offs1, spts1, sidx1,
      0, nullptr, nullptr, wA, idxA, nullptr);
  build_t_kernel<<<Nh * 64 / 256, 256, 0, stream>>>(
      emb1, emb2, wA, idxA, t_hi, t_lo, Nh);
  mfma_gemm_kernel<<<(Nh / 64) * 4, 256, 0, stream>>>(
      t_hi, t_lo, w1t_hi, w1t_lo, b1, nullptr, h1_hi, h1_lo, 1, 1);
  mfma_gemm_kernel<<<(Nh / 64) * 4, 256, 0, stream>>>(
      h1_hi, h1_lo, w2t_hi, w2t_lo, b2, h2, nullptr, nullptr, 1, 0);

  // ---- branch 2: res = interp(l_y1 - interp(l_y2); l_pos1 -> h_pos1) ----
  knn_wave_kernel<<<Nl / 16, 256, 0, stream>>>(
      l_pos1, Nl, G2, offs2, spts2, sidx2,
      1, l_y1, l_y2, nullptr, nullptr, diff);
  knn_wave_kernel<<<Nh / 16, 256, 0, stream>>>(
      h_pos1, Nh, G2, offs3, spts3, sidx3,
      2, nullptr, diff, nullptr, nullptr, res);

  // ---- final: out = (h2 @ W3 + b3) + res ----
  final_kernel<<<Nh / 4, 256, 0, stream>>>(h2, W3, b3, res, out, Nh);
}

// Round 13
// 150.210 us; speedup vs baseline: 1.5236x; 1.2196x over previous
//
#include <hip/hip_runtime.h>
#include <math.h>

#define BIGF 3.0e38f

typedef short  s16x8 __attribute__((ext_vector_type(8)));
typedef float  f32x4 __attribute__((ext_vector_type(4)));

// bf16 helpers (manual RNE)
__device__ __forceinline__ unsigned short f2bf(float x) {
  unsigned int b = __float_as_uint(x);
  unsigned int r = b + 0x7FFFu + ((b >> 16) & 1u);
  return (unsigned short)(r >> 16);
}
__device__ __forceinline__ float bf2f(unsigned short h) {
  return __uint_as_float(((unsigned int)h) << 16);
}

// ===========================================================================
// Spatial-hash KNN (K=3), 16 lanes per query, row-range shell scan.
// Selection replicates the np reference's fp32 expansion distance:
//   sx  = (x*x + y*y) + z*z            (sequential, individually rounded)
//   dot = (p0 + p1) + p2, p_k = q_k*s_k
//   d2  = (sy + sx) - 2*dot
// under fp contract(off) — verified rounds 3-6. DO NOT TOUCH.
// Tie-break: lexicographic (d, idx). Every candidate visited EXACTLY once
// (duplicates would corrupt the lex top-3).
// ===========================================================================

__device__ __forceinline__ int cell_clamp(float v, int G) {
  int c = (int)(v * (float)G);
  return min(G - 1, max(0, c));
}

__device__ __forceinline__ void ins3(float d, int id,
                                     float& d0, float& d1, float& d2,
                                     int& i0, int& i1, int& i2) {
  bool l0 = (d < d0) || (d == d0 && id < i0);
  bool l1 = (d < d1) || (d == d1 && id < i1);
  bool l2 = (d < d2) || (d == d2 && id < i2);
  float nd0 = l0 ? d  : d0;  int ni0 = l0 ? id : i0;
  float nd1 = l0 ? d0 : (l1 ? d  : d1);
  int   ni1 = l0 ? i0 : (l1 ? id : i1);
  float nd2 = l1 ? d1 : (l2 ? d  : d2);
  int   ni2 = l1 ? i1 : (l2 ? id : i2);
  d0 = nd0; d1 = nd1; d2 = nd2; i0 = ni0; i1 = ni1; i2 = ni2;
}

// mode 0: write w[Nq,3], idx[Nq,3]
// mode 1: out3 = base3 - sum_k w_k * feat3[idx_k]
// mode 2: out3 =         sum_k w_k * feat3[idx_k]
__device__ void knn_body(
    int bid, const float* __restrict__ qpos, int Nq, int G,
    const int* __restrict__ offs,
    const float4* __restrict__ spts,
    const int* __restrict__ sidx,
    int mode,
    const float* __restrict__ base3,
    const float* __restrict__ feat3,
    float* __restrict__ w_out, int* __restrict__ i_out,
    float* __restrict__ out3)
{
  #pragma clang fp contract(off)
  const int sl = threadIdx.x & 15;
  const int q = bid * 16 + (threadIdx.x >> 4);
  if (q >= Nq) return;

  const float qx = qpos[3 * q], qy = qpos[3 * q + 1], qz = qpos[3 * q + 2];
  const float sy = (qx * qx + qy * qy) + qz * qz;  // sequential, no contraction
  const float cs = 1.0f / (float)G;
  const int cx = cell_clamp(qx, G), cy = cell_clamp(qy, G), cz = cell_clamp(qz, G);

  float d0 = BIGF, d1 = BIGF, d2v = BIGF;   // per-lane local top-3 (disjoint)
  int i0 = -1, i1 = -1, i2 = -1;
  float e0 = BIGF, e1 = BIGF, e2 = BIGF;    // merged top-3
  int j0 = -1, j1 = -1, j2 = -1;
  bool done = false;

  #define SCAN()                                                              \
    for (int j = js; j < je; ++j) {                                           \
      float4 s = spts[j];                                                     \
      float p0 = qx * s.x, p1 = qy * s.y, p2 = qz * s.z;                      \
      float dt = (p0 + p1) + p2;                                              \
      float S  = sy + s.w;                                                    \
      float dd = S - 2.0f * dt;                                               \
      ins3(dd, sidx[j], d0, d1, d2v, i0, i1, i2);                             \
    }

  for (int R = 1; R <= G; ++R) {
    if (!done) {
      if (R == 1) {
        // 3x3x3 box = 9 x-contiguous row ranges (includes center)
        if (sl < 9) {
          int dy = sl % 3 - 1, dz = sl / 3 - 1;
          int yy = cy + dy, zz = cz + dz;
          if (yy >= 0 && yy < G && zz >= 0 && zz < G) {
            int xs = max(cx - 1, 0), xe = min(cx + 1, G - 1);
            int base = (zz * G + yy) * G;
            int js = offs[base + xs], je = offs[base + xe + 1];
            SCAN()
          }
        }
      } else {
        // Chebyshev shell R, exact-once:
        //  full rows (|dz|=R any dy; |dy|=R with |dz|<R): one clamped x-range
        //  inner rows (|dy|<R,|dz|<R): two single cells x = cx +/- R
        const int twoR1 = 2 * R + 1, inner = 2 * R - 1;
        const int nfz = 2 * twoR1;
        const int nfull = nfz + 2 * inner;
        const int half = inner * inner;
        const int nitems = nfull + 2 * half;
        for (int m = sl; m < nitems; m += 16) {
          int dy, dz, js, je;
          if (m < nfull) {
            if (m < nfz) { dz = (m < twoR1) ? -R : R; dy = (m % twoR1) - R; }
            else { int u = m - nfz; dy = (u < inner) ? -R : R; dz = (u % inner) - (R - 1); }
            int yy = cy + dy, zz = cz + dz;
            if (yy < 0 || yy >= G || zz < 0 || zz >= G) continue;
            int xs = max(cx - R, 0), xe = min(cx + R, G - 1);
            int base = (zz * G + yy) * G;
            js = offs[base + xs]; je = offs[base + xe + 1];
          } else {
            int u = m - nfull;
            int xc = (u < half) ? (cx - R) : (cx + R);
            int r2 = (u < half) ? u : u - half;
            dy = r2 % inner - (R - 1); dz = r2 / inner - (R - 1);
            int yy = cy + dy, zz = cz + dz;
            if (xc < 0 || xc >= G || yy < 0 || yy >= G || zz < 0 || zz >= G) continue;
            int c = (zz * G + yy) * G + xc;
            js = offs[c]; je = offs[c + 1];
          }
          SCAN()
        }
      }
    }
    // merge a fresh copy (locals keep accumulating; lane sets disjoint)
    e0 = d0; e1 = d1; e2 = d2v; j0 = i0; j1 = i1; j2 = i2;
    #pragma unroll
    for (int msk = 1; msk < 16; msk <<= 1) {
      float o0 = __shfl_xor(e0, msk), o1 = __shfl_xor(e1, msk), o2 = __shfl_xor(e2, msk);
      int   p0 = __shfl_xor(j0, msk), p1 = __shfl_xor(j1, msk), p2 = __shfl_xor(j2, msk);
      ins3(o0, p0, e0, e1, e2, j0, j1, j2);
      ins3(o1, p1, e0, e1, e2, j0, j1, j2);
      ins3(o2, p2, e0, e1, e2, j0, j1, j2);
    }
    float bnd = (float)R * cs;
    done = done || (e2 <= bnd * bnd - 1e-6f);
    if (__all(done)) break;
  }
  #undef SCAN

  if (sl == 0) {
    float w0 = 1.0f / fmaxf(e0, 1e-16f);
    float w1 = 1.0f / fmaxf(e1, 1e-16f);
    float w2 = 1.0f / fmaxf(e2, 1e-16f);
    float inv = 1.0f / (w0 + w1 + w2);
    w0 *= inv; w1 *= inv; w2 *= inv;
    if (mode == 0) {
      w_out[(size_t)q * 3 + 0] = w0; w_out[(size_t)q * 3 + 1] = w1; w_out[(size_t)q * 3 + 2] = w2;
      i_out[(size_t)q * 3 + 0] = j0; i_out[(size_t)q * 3 + 1] = j1; i_out[(size_t)q * 3 + 2] = j2;
    } else {
      #pragma unroll
      for (int f = 0; f < 3; ++f) {
        float v = w0 * feat3[(size_t)j0 * 3 + f]
                + w1 * feat3[(size_t)j1 * 3 + f]
                + w2 * feat3[(size_t)j2 * 3 + f];
        out3[(size_t)q * 3 + f] = (mode == 1) ? (base3[(size_t)q * 3 + f] - v) : v;
      }
    }
  }
}

// t = emb1 - interp(emb2), emitted as bf16 hi/lo splits (device body)
__device__ void build_t_body(
    int bid, const float* __restrict__ emb1, const float* __restrict__ emb2,
    const float* __restrict__ w, const int* __restrict__ idx,
    unsigned short* __restrict__ t_hi, unsigned short* __restrict__ t_lo, int Nq)
{
  int gid = bid * 256 + threadIdx.x;
  int q = gid >> 6, c4 = gid & 63;
  if (q >= Nq) return;
  float w0 = w[(size_t)q * 3 + 0], w1 = w[(size_t)q * 3 + 1], w2 = w[(size_t)q * 3 + 2];
  int i0 = idx[(size_t)q * 3 + 0], i1 = idx[(size_t)q * 3 + 1], i2 = idx[(size_t)q * 3 + 2];
  const float4* e1 = (const float4*)emb1;
  const float4* e2 = (const float4*)emb2;
  float4 a  = e1[(size_t)q * 64 + c4];
  float4 f0 = e2[(size_t)i0 * 64 + c4];
  float4 f1 = e2[(size_t)i1 * 64 + c4];
  float4 f2 = e2[(size_t)i2 * 64 + c4];
  float4 r;
  r.x = a.x - (w0 * f0.x + w1 * f1.x + w2 * f2.x);
  r.y = a.y - (w0 * f0.y + w1 * f1.y + w2 * f2.y);
  r.z = a.z - (w0 * f0.z + w1 * f1.z + w2 * f2.z);
  r.w = a.w - (w0 * f0.w + w1 * f1.w + w2 * f2.w);
  ushort4 h, l;
  h.x = f2bf(r.x); l.x = f2bf(r.x - bf2f(h.x));
  h.y = f2bf(r.y); l.y = f2bf(r.y - bf2f(h.y));
  h.z = f2bf(r.z); l.z = f2bf(r.z - bf2f(h.z));
  h.w = f2bf(r.w); l.w = f2bf(r.w - bf2f(h.w));
  size_t o = (size_t)q * 256 + c4 * 4;
  *(ushort4*)&t_hi[o] = h;
  *(ushort4*)&t_lo[o] = l;
}

// ---- fused dispatch wrappers (4:1 block interleave for pipe overlap) ------
__global__ __launch_bounds__(256) void knn_dual_kernel(
    const float* qA, int NqA, int GA, const int* offsA, const float4* sptsA, const int* sidxA,
    float* wA, int* iA,
    const float* qB, int NqB, int GB, const int* offsB, const float4* sptsB, const int* sidxB,
    const float* base3B, const float* feat3B, float* out3B)
{
  int g = blockIdx.x / 5, r = blockIdx.x % 5;
  if (r < 4)
    knn_body(g * 4 + r, qA, NqA, GA, offsA, sptsA, sidxA, 0,
             nullptr, nullptr, wA, iA, nullptr);
  else
    knn_body(g, qB, NqB, GB, offsB, sptsB, sidxB, 1,
             base3B, feat3B, nullptr, nullptr, out3B);
}

__global__ __launch_bounds__(256) void bt_knn2_kernel(
    const float* emb1, const float* emb2, const float* w, const int* idx,
    unsigned short* t_hi, unsigned short* t_lo, int Nq_bt,
    const float* qC, int NqC, int GC, const int* offsC, const float4* sptsC, const int* sidxC,
    const float* feat3C, float* out3C)
{
  int g = blockIdx.x / 5, r = blockIdx.x % 5;
  if (r < 4)
    build_t_body(g * 4 + r, emb1, emb2, w, idx, t_hi, t_lo, Nq_bt);
  else
    knn_body(g, qC, NqC, GC, offsC, sptsC, sidxC, 2,
             nullptr, feat3C, nullptr, nullptr, out3C);
}

// ---- grid build ------------------------------------------------------------
__global__ __launch_bounds__(256) void zero_kernel(int* __restrict__ p, int n) {
  int i = blockIdx.x * 256 + threadIdx.x;
  if (i < n) p[i] = 0;
}

__global__ __launch_bounds__(256) void cell_count3_kernel(
    const float* __restrict__ p1, int n1, int g1, int* __restrict__ c1,
    const float* __restrict__ p2, int n2, int g2, int* __restrict__ c2,
    const float* __restrict__ p3, int n3, int g3, int* __restrict__ c3)
{
  int b = blockIdx.x;
  const float* p; int n, G; int* cnt; int i;
  if (b < 64)      { p = p1; n = n1; G = g1; cnt = c1; i = b * 256 + threadIdx.x; }
  else if (b < 80) { p = p2; n = n2; G = g2; cnt = c2; i = (b - 64) * 256 + threadIdx.x; }
  else             { p = p3; n = n3; G = g3; cnt = c3; i = (b - 80) * 256 + threadIdx.x; }
  if (i >= n) return;
  int cx = cell_clamp(p[3 * i],     G);
  int cy = cell_clamp(p[3 * i + 1], G);
  int cz = cell_clamp(p[3 * i + 2], G);
  atomicAdd(&cnt[(cz * G + cy) * G + cx], 1);
}

__global__ __launch_bounds__(256) void prefix3_kernel(
    const int* __restrict__ c1, int* __restrict__ o1, int* __restrict__ u1, int m1,
    const int* __restrict__ c2, int* __restrict__ o2, int* __restrict__ u2, int m2,
    const int* __restrict__ c3, int* __restrict__ o3, int* __restrict__ u3, int m3)
{
  const int* cnt; int* offs; int* cur; int M;
  if (blockIdx.x == 0)      { cnt = c1; offs = o1; cur = u1; M = m1; }
  else if (blockIdx.x == 1) { cnt = c2; offs = o2; cur = u2; M = m2; }
  else                      { cnt = c3; offs = o3; cur = u3; M = m3; }
  __shared__ int ps[256];
  const int tid = threadIdx.x;
  const int per = (M + 255) >> 8;
  const int base = tid * per;
  int s = 0;
  for (int j = 0; j < per; ++j) if (base + j < M) s += cnt[base + j];
  ps[tid] = s;
  __syncthreads();
  for (int off = 1; off < 256; off <<= 1) {
    int v = (tid >= off) ? ps[tid - off] : 0;
    __syncthreads();
    ps[tid] += v;
    __syncthreads();
  }
  int run = (tid > 0) ? ps[tid - 1] : 0;
  for (int j = 0; j < per; ++j) {
    if (base + j < M) {
      offs[base + j] = run; cur[base + j] = run;
      run += cnt[base + j];
    }
  }
  if (tid == 255) offs[M] = run;
}

__global__ __launch_bounds__(256) void scatter3_kernel(
    const float* __restrict__ p1, int n1, int g1, int* __restrict__ u1, float4* __restrict__ s1, int* __restrict__ x1,
    const float* __restrict__ p2, int n2, int g2, int* __restrict__ u2, float4* __restrict__ s2, int* __restrict__ x2,
    const float* __restrict__ p3, int n3, int g3, int* __restrict__ u3, float4* __restrict__ s3, int* __restrict__ x3)
{
  #pragma clang fp contract(off)
  int b = blockIdx.x;
  const float* p; int n, G; int* cur; float4* spts; int* sidx; int i;
  if (b < 64)      { p = p1; n = n1; G = g1; cur = u1; spts = s1; sidx = x1; i = b * 256 + threadIdx.x; }
  else if (b < 80) { p = p2; n = n2; G = g2; cur = u2; spts = s2; sidx = x2; i = (b - 64) * 256 + threadIdx.x; }
  else             { p = p3; n = n3; G = g3; cur = u3; spts = s3; sidx = x3; i = (b - 80) * 256 + threadIdx.x; }
  if (i >= n) return;
  float x = p[3 * i], y = p[3 * i + 1], z = p[3 * i + 2];
  int cx = cell_clamp(x, G), cy = cell_clamp(y, G), cz = cell_clamp(z, G);
  int c = (cz * G + cy) * G + cx;
  int pos = atomicAdd(&cur[c], 1);
  float sx = (x * x + y * y) + z * z;   // sequential, no contraction
  spts[pos] = make_float4(x, y, z, sx);
  sidx[pos] = i;
}

// ---- both weight transposed-splits in one dispatch (512 blocks) -----------
__global__ __launch_bounds__(256) void split_wt2_kernel(
    const float* __restrict__ W1, unsigned short* __restrict__ h1T, unsigned short* __restrict__ l1T,
    const float* __restrict__ W2, unsigned short* __restrict__ h2T, unsigned short* __restrict__ l2T)
{
  int b = blockIdx.x;
  const float* W = (b < 256) ? W1 : W2;
  unsigned short* hiT = (b < 256) ? h1T : h2T;
  unsigned short* loT = (b < 256) ? l1T : l2T;
  int id = (b & 255) * 256 + threadIdx.x;
  int k = id >> 8, n = id & 255;
  float x = W[id];
  unsigned short h = f2bf(x);
  unsigned short l = f2bf(x - bf2f(h));
  hiT[n * 256 + k] = h;
  loT[n * 256 + k] = l;
}

// ---------------------------------------------------------------------------
// bf16x3-split MFMA GEMM (unchanged from round 12 — verified absmax 0.0625)
// ---------------------------------------------------------------------------
__global__ __launch_bounds__(256) void mfma_gemm_kernel(
    const unsigned short* __restrict__ A_hi, const unsigned short* __restrict__ A_lo,
    const unsigned short* __restrict__ BT_hi, const unsigned short* __restrict__ BT_lo,
    const float* __restrict__ bias,
    float* __restrict__ outf,
    unsigned short* __restrict__ out_hi, unsigned short* __restrict__ out_lo,
    int relu, int split_out)
{
  __shared__ unsigned short Bs_hi[64][132];
  __shared__ unsigned short Bs_lo[64][132];
  const int t = threadIdx.x;
  const int d = blockIdx.x;
  const int xcd = d & 7, slot = d >> 3;
  const int lin = xcd * ((int)gridDim.x >> 3) + slot;
  const int row0 = (lin >> 2) * 64;
  const int col0 = (lin & 3) * 64;

  const int l = t & 63, w = t >> 6;
  const int lr = l & 15;
  const int lk = (l >> 4) << 3;
  const unsigned short* arh = A_hi + (size_t)(row0 + w * 16 + lr) * 256;
  const unsigned short* arl = A_lo + (size_t)(row0 + w * 16 + lr) * 256;

  const int sc = t >> 2;
  const int sk = (t & 3) << 5;

  f32x4 acc0 = {0.f,0.f,0.f,0.f}, acc1 = {0.f,0.f,0.f,0.f};
  f32x4 acc2 = {0.f,0.f,0.f,0.f}, acc3 = {0.f,0.f,0.f,0.f};

  #define KSTEP(CT, ACC)                                                      \
    { s16x8 bh = *(const s16x8*)&Bs_hi[CT * 16 + lr][kc + lk];                \
      s16x8 bl = *(const s16x8*)&Bs_lo[CT * 16 + lr][kc + lk];                \
      ACC = __builtin_amdgcn_mfma_f32_16x16x32_bf16(ah, bh, ACC, 0, 0, 0);    \
      ACC = __builtin_amdgcn_mfma_f32_16x16x32_bf16(al, bh, ACC, 0, 0, 0);    \
      ACC = __builtin_amdgcn_mfma_f32_16x16x32_bf16(ah, bl, ACC, 0, 0, 0); }

  for (int half = 0; half < 2; ++half) {
    if (half) __syncthreads();
    {
      const int4* sh = (const int4*)&BT_hi[(size_t)(col0 + sc) * 256 + half * 128 + sk];
      const int4* slo = (const int4*)&BT_lo[(size_t)(col0 + sc) * 256 + half * 128 + sk];
      int4* dh = (int4*)&Bs_hi[sc][sk];
      int4* dl = (int4*)&Bs_lo[sc][sk];
      #pragma unroll
      for (int i = 0; i < 4; ++i) { dh[i] = sh[i]; dl[i] = slo[i]; }
    }
    __syncthreads();
    const int kbase = half * 128;
    #pragma unroll
    for (int kc = 0; kc < 128; kc += 32) {
      s16x8 ah = *(const s16x8*)&arh[kbase + kc + lk];
      s16x8 al = *(const s16x8*)&arl[kbase + kc + lk];
      KSTEP(0, acc0)
      KSTEP(1, acc1)
      KSTEP(2, acc2)
      KSTEP(3, acc3)
    }
  }
  #undef KSTEP

  const int orow = row0 + w * 16 + ((l >> 4) << 2);
  #define EPILOG(CT, ACC)                                                     \
    { int col = col0 + CT * 16 + lr;                                          \
      float bb = bias[col];                                                   \
      _Pragma("unroll")                                                       \
      for (int r = 0; r < 4; ++r) {                                           \
        float v = ACC[r] + bb;                                                \
        if (relu) v = fmaxf(v, 0.0f);                                         \
        size_t o = (size_t)(orow + r) * 256 + col;                            \
        if (split_out) {                                                      \
          unsigned short hh = f2bf(v);                                        \
          out_hi[o] = hh; out_lo[o] = f2bf(v - bf2f(hh));                     \
        } else {                                                              \
          outf[o] = v;                                                        \
        }                                                                     \
      } }
  EPILOG(0, acc0)
  EPILOG(1, acc1)
  EPILOG(2, acc2)
  EPILOG(3, acc3)
  #undef EPILOG
}

// ---------------------------------------------------------------------------
// out[r, :] = h2[r, :] @ W3[256,3] + b3 + res[r, :]   (wave per row)
// ---------------------------------------------------------------------------
__global__ __launch_bounds__(256) void final_kernel(
    const float* __restrict__ h2, const float* __restrict__ W3,
    const float* __restrict__ b3, const float* __restrict__ res,
    float* __restrict__ out, int M)
{
  __shared__ float sW3[768];
  const int tid = threadIdx.x;
  for (int i = tid; i < 768; i += 256) sW3[i] = W3[i];
  __syncthreads();

  const int wave = tid >> 6, lane = tid & 63;
  const int r = blockIdx.x * 4 + wave;
  if (r >= M) return;

  float4 h = ((const float4*)h2)[(size_t)r * 64 + lane];
  const int c = lane * 4;
  float a0 = h.x * sW3[(c + 0) * 3 + 0] + h.y * sW3[(c + 1) * 3 + 0]
           + h.z * sW3[(c + 2) * 3 + 0] + h.w * sW3[(c + 3) * 3 + 0];
  float a1 = h.x * sW3[(c + 0) * 3 + 1] + h.y * sW3[(c + 1) * 3 + 1]
           + h.z * sW3[(c + 2) * 3 + 1] + h.w * sW3[(c + 3) * 3 + 1];
  float a2 = h.x * sW3[(c + 0) * 3 + 2] + h.y * sW3[(c + 1) * 3 + 2]
           + h.z * sW3[(c + 2) * 3 + 2] + h.w * sW3[(c + 3) * 3 + 2];

  #pragma unroll
  for (int off = 32; off; off >>= 1) {
    a0 += __shfl_xor(a0, off);
    a1 += __shfl_xor(a1, off);
    a2 += __shfl_xor(a2, off);
  }
  if (lane == 0) {
    out[(size_t)r * 3 + 0] = a0 + b3[0] + res[(size_t)r * 3 + 0];
    out[(size_t)r * 3 + 1] = a1 + b3[1] + res[(size_t)r * 3 + 1];
    out[(size_t)r * 3 + 2] = a2 + b3[2] + res[(size_t)r * 3 + 2];
  }
}

// ---------------------------------------------------------------------------
extern "C" void kernel_launch(void* const* d_in, const int* in_sizes, int n_in,
                              void* d_out, int out_size, void* d_ws, size_t ws_size,
                              hipStream_t stream) {
  (void)in_sizes; (void)n_in; (void)out_size; (void)ws_size;
  const float* emb1   = (const float*)d_in[0];
  const float* l_y1   = (const float*)d_in[1];
  const float* l_pos1 = (const float*)d_in[2];
  const float* h_pos1 = (const float*)d_in[3];
  const float* emb2   = (const float*)d_in[4];
  const float* l_y2   = (const float*)d_in[5];
  const float* l_pos2 = (const float*)d_in[6];
  const float* h_pos2 = (const float*)d_in[7];
  const float* W1     = (const float*)d_in[8];
  const float* b1     = (const float*)d_in[9];
  const float* W2     = (const float*)d_in[10];
  const float* b2     = (const float*)d_in[11];
  const float* W3     = (const float*)d_in[12];
  const float* b3     = (const float*)d_in[13];
  float* out = (float*)d_out;

  const int Nh = 16384, Nl = 4096, H = 256;
  const int G1 = 16, G2 = 10;
  const int M1 = G1 * G1 * G1, M2 = G2 * G2 * G2;

  // ---- workspace carve-up (sequential bump allocator, 256B aligned) ----
  char* wsp = (char*)d_ws;
  size_t off = 0;
  auto alloc = [&](size_t bytes) -> void* {
    void* p = wsp + off;
    off += (bytes + 255) & ~(size_t)255;
    return p;
  };
  int*            idxA   = (int*)           alloc((size_t)Nh * 3 * 4);
  float*          wA     = (float*)         alloc((size_t)Nh * 3 * 4);
  unsigned short* t_hi   = (unsigned short*)alloc((size_t)Nh * H * 2);
  unsigned short* t_lo   = (unsigned short*)alloc((size_t)Nh * H * 2);
  unsigned short* h1_hi  = (unsigned short*)alloc((size_t)Nh * H * 2);
  unsigned short* h1_lo  = (unsigned short*)alloc((size_t)Nh * H * 2);
  float*          h2     = (float*)t_hi;    // alias over t_hi+t_lo (t dead)
  unsigned short* w1t_hi = (unsigned short*)alloc((size_t)H * H * 2);
  unsigned short* w1t_lo = (unsigned short*)alloc((size_t)H * H * 2);
  unsigned short* w2t_hi = (unsigned short*)alloc((size_t)H * H * 2);
  unsigned short* w2t_lo = (unsigned short*)alloc((size_t)H * H * 2);
  float*          diff   = (float*)         alloc((size_t)Nl * 3 * 4);
  float*          res    = (float*)         alloc((size_t)Nh * 3 * 4);
  int*            cnts   = (int*)           alloc((size_t)(M1 + M2 + M2) * 4);
  int*            cnt1 = cnts, *cnt2 = cnts + M1, *cnt3 = cnts + M1 + M2;
  int*            offs1  = (int*)           alloc((size_t)(M1 + 1) * 4);
  int*            cur1   = (int*)           alloc((size_t)M1 * 4);
  int*            offs2  = (int*)           alloc((size_t)(M2 + 1) * 4);
  int*            cur2   = (int*)           alloc((size_t)M2 * 4);
  int*            offs3  = (int*)           alloc((size_t)(M2 + 1) * 4);
  int*            cur3   = (int*)           alloc((size_t)M2 * 4);
  float4*         spts1  = (float4*)        alloc((size_t)Nh * 16);
  int*            sidx1  = (int*)           alloc((size_t)Nh * 4);
  float4*         spts2  = (float4*)        alloc((size_t)Nl * 16);
  int*            sidx2  = (int*)           alloc((size_t)Nl * 4);
  float4*         spts3  = (float4*)        alloc((size_t)Nl * 16);
  int*            sidx3  = (int*)           alloc((size_t)Nl * 4);

  // ---- build grids + weight splits ----
  const int ncnt = M1 + M2 + M2;
  zero_kernel<<<(ncnt + 255) / 256, 256, 0, stream>>>(cnts, ncnt);
  cell_count3_kernel<<<96, 256, 0, stream>>>(
      h_pos2, Nh, G1, cnt1,  l_pos2, Nl, G2, cnt2,  l_pos1, Nl, G2, cnt3);
  prefix3_kernel<<<3, 256, 0, stream>>>(
      cnt1, offs1, cur1, M1,  cnt2, offs2, cur2, M2,  cnt3, offs3, cur3, M2);
  scatter3_kernel<<<96, 256, 0, stream>>>(
      h_pos2, Nh, G1, cur1, spts1, sidx1,
      l_pos2, Nl, G2, cur2, spts2, sidx2,
      l_pos1, Nl, G2, cur3, spts3, sidx3);
  split_wt2_kernel<<<512, 256, 0, stream>>>(
      W1, w1t_hi, w1t_lo, W2, w2t_hi, w2t_lo);

  // ---- knn0 (Nh, grid1, mode0)  ||  knn1 (Nl, grid2, mode1 -> diff) ----
  // blocks: 1024 A + 256 B, interleaved 4:1 -> 1280 blocks
  knn_dual_kernel<<<1280, 256, 0, stream>>>(
      h_pos1, Nh, G1, offs1, spts1, sidx1, wA, idxA,
      l_pos1, Nl, G2, offs2, spts2, sidx2, l_y1, l_y2, diff);

  // ---- build_t (4096 blocks)  ||  knn2 (Nh, grid3, mode2 -> res, 1024) ----
  bt_knn2_kernel<<<5120, 256, 0, stream>>>(
      emb1, emb2, wA, idxA, t_hi, t_lo, Nh,
      h_pos1, Nh, G2, offs3, spts3, sidx3, diff, res);

  // ---- MLP ----
  mfma_gemm_kernel<<<(Nh / 64) * 4, 256, 0, stream>>>(
      t_hi, t_lo, w1t_hi, w1t_lo, b1, nullptr, h1_hi, h1_lo, 1, 1);
  mfma_gemm_kernel<<<(Nh / 64) * 4, 256, 0, stream>>>(
      h1_hi, h1_lo, w2t_hi, w2t_lo, b2, h2, nullptr, nullptr, 1, 0);

  // ---- final: out = (h2 @ W3 + b3) + res ----
  final_kernel<<<Nh / 4, 256, 0, stream>>>(h2, W3, b3, res, out, Nh);
}

// Round 14
// 145.526 us; speedup vs baseline: 1.5727x; 1.0322x over previous
//
#include <hip/hip_runtime.h>
#include <math.h>

#define BIGF 3.0e38f

typedef short  s16x8 __attribute__((ext_vector_type(8)));
typedef float  f32x4 __attribute__((ext_vector_type(4)));

// bf16 helpers (manual RNE)
__device__ __forceinline__ unsigned short f2bf(float x) {
  unsigned int b = __float_as_uint(x);
  unsigned int r = b + 0x7FFFu + ((b >> 16) & 1u);
  return (unsigned short)(r >> 16);
}
__device__ __forceinline__ float bf2f(unsigned short h) {
  return __uint_as_float(((unsigned int)h) << 16);
}

// ===========================================================================
// Spatial-hash KNN (K=3), 16 lanes per query, row-range shell scan,
// MORTON-ish (cell-sorted) query order for wave locality.
// Selection replicates the np reference's fp32 expansion distance:
//   sx  = (x*x + y*y) + z*z            (sequential, individually rounded)
//   dot = (p0 + p1) + p2, p_k = q_k*s_k
//   d2  = (sy + sx) - 2*dot
// under fp contract(off) — verified rounds 3-6. DO NOT TOUCH.
// Tie-break: lexicographic (d, idx). Every candidate visited EXACTLY once.
// Query positions+|q|^2 come pre-sorted from the scatter pass (identical
// formula); outputs are written at the ORIGINAL index -> results unchanged.
// ===========================================================================

__device__ __forceinline__ int cell_clamp(float v, int G) {
  int c = (int)(v * (float)G);
  return min(G - 1, max(0, c));
}

__device__ __forceinline__ void ins3(float d, int id,
                                     float& d0, float& d1, float& d2,
                                     int& i0, int& i1, int& i2) {
  bool l0 = (d < d0) || (d == d0 && id < i0);
  bool l1 = (d < d1) || (d == d1 && id < i1);
  bool l2 = (d < d2) || (d == d2 && id < i2);
  float nd0 = l0 ? d  : d0;  int ni0 = l0 ? id : i0;
  float nd1 = l0 ? d0 : (l1 ? d  : d1);
  int   ni1 = l0 ? i0 : (l1 ? id : i1);
  float nd2 = l1 ? d1 : (l2 ? d  : d2);
  int   ni2 = l1 ? i1 : (l2 ? id : i2);
  d0 = nd0; d1 = nd1; d2 = nd2; i0 = ni0; i1 = ni1; i2 = ni2;
}

// mode 0: w_out/i_out at orig idx;  mode 1: out3 = base3 - interp;  mode 2: out3 = interp
__device__ void knn_body(
    int bid,
    const float4* __restrict__ qspts, const int* __restrict__ qsidx, int Nq, int G,
    const int* __restrict__ offs,
    const float4* __restrict__ spts,
    const int* __restrict__ sidx,
    int mode,
    const float* __restrict__ base3,
    const float* __restrict__ feat3,
    float* __restrict__ w_out, int* __restrict__ i_out,
    float* __restrict__ out3)
{
  #pragma clang fp contract(off)
  const int sl = threadIdx.x & 15;
  const int qs = bid * 16 + (threadIdx.x >> 4);
  if (qs >= Nq) return;

  float4 qv = qspts[qs];
  const float qx = qv.x, qy = qv.y, qz = qv.z;
  const float sy = qv.w;                       // |q|^2, exact same formula (scatter)
  const int qorig = qsidx[qs];
  const float cs = 1.0f / (float)G;
  const int cx = cell_clamp(qx, G), cy = cell_clamp(qy, G), cz = cell_clamp(qz, G);

  float d0 = BIGF, d1 = BIGF, d2v = BIGF;   // per-lane local top-3 (disjoint)
  int i0 = -1, i1 = -1, i2 = -1;
  float e0 = BIGF, e1 = BIGF, e2 = BIGF;    // merged top-3
  int j0 = -1, j1 = -1, j2 = -1;
  bool done = false;

  #define SCAN()                                                              \
    for (int j = js; j < je; ++j) {                                           \
      float4 s = spts[j];                                                     \
      float p0 = qx * s.x, p1 = qy * s.y, p2 = qz * s.z;                      \
      float dt = (p0 + p1) + p2;                                              \
      float S  = sy + s.w;                                                    \
      float dd = S - 2.0f * dt;                                               \
      ins3(dd, sidx[j], d0, d1, d2v, i0, i1, i2);                             \
    }

  for (int R = 1; R <= G; ++R) {
    if (!done) {
      if (R == 1) {
        if (sl < 9) {
          int dy = sl % 3 - 1, dz = sl / 3 - 1;
          int yy = cy + dy, zz = cz + dz;
          if (yy >= 0 && yy < G && zz >= 0 && zz < G) {
            int xs = max(cx - 1, 0), xe = min(cx + 1, G - 1);
            int base = (zz * G + yy) * G;
            int js = offs[base + xs], je = offs[base + xe + 1];
            SCAN()
          }
        }
      } else {
        const int twoR1 = 2 * R + 1, inner = 2 * R - 1;
        const int nfz = 2 * twoR1;
        const int nfull = nfz + 2 * inner;
        const int half = inner * inner;
        const int nitems = nfull + 2 * half;
        for (int m = sl; m < nitems; m += 16) {
          int dy, dz, js, je;
          if (m < nfull) {
            if (m < nfz) { dz = (m < twoR1) ? -R : R; dy = (m % twoR1) - R; }
            else { int u = m - nfz; dy = (u < inner) ? -R : R; dz = (u % inner) - (R - 1); }
            int yy = cy + dy, zz = cz + dz;
            if (yy < 0 || yy >= G || zz < 0 || zz >= G) continue;
            int xs = max(cx - R, 0), xe = min(cx + R, G - 1);
            int base = (zz * G + yy) * G;
            js = offs[base + xs]; je = offs[base + xe + 1];
          } else {
            int u = m - nfull;
            int xc = (u < half) ? (cx - R) : (cx + R);
            int r2 = (u < half) ? u : u - half;
            dy = r2 % inner - (R - 1); dz = r2 / inner - (R - 1);
            int yy = cy + dy, zz = cz + dz;
            if (xc < 0 || xc >= G || yy < 0 || yy >= G || zz < 0 || zz >= G) continue;
            int c = (zz * G + yy) * G + xc;
            js = offs[c]; je = offs[c + 1];
          }
          SCAN()
        }
      }
    }
    e0 = d0; e1 = d1; e2 = d2v; j0 = i0; j1 = i1; j2 = i2;
    #pragma unroll
    for (int msk = 1; msk < 16; msk <<= 1) {
      float o0 = __shfl_xor(e0, msk), o1 = __shfl_xor(e1, msk), o2 = __shfl_xor(e2, msk);
      int   p0 = __shfl_xor(j0, msk), p1 = __shfl_xor(j1, msk), p2 = __shfl_xor(j2, msk);
      ins3(o0, p0, e0, e1, e2, j0, j1, j2);
      ins3(o1, p1, e0, e1, e2, j0, j1, j2);
      ins3(o2, p2, e0, e1, e2, j0, j1, j2);
    }
    float bnd = (float)R * cs;
    done = done || (e2 <= bnd * bnd - 1e-6f);
    if (__all(done)) break;
  }
  #undef SCAN

  if (sl == 0) {
    float w0 = 1.0f / fmaxf(e0, 1e-16f);
    float w1 = 1.0f / fmaxf(e1, 1e-16f);
    float w2 = 1.0f / fmaxf(e2, 1e-16f);
    float inv = 1.0f / (w0 + w1 + w2);
    w0 *= inv; w1 *= inv; w2 *= inv;
    if (mode == 0) {
      w_out[(size_t)qorig * 3 + 0] = w0; w_out[(size_t)qorig * 3 + 1] = w1; w_out[(size_t)qorig * 3 + 2] = w2;
      i_out[(size_t)qorig * 3 + 0] = j0; i_out[(size_t)qorig * 3 + 1] = j1; i_out[(size_t)qorig * 3 + 2] = j2;
    } else {
      #pragma unroll
      for (int f = 0; f < 3; ++f) {
        float v = w0 * feat3[(size_t)j0 * 3 + f]
                + w1 * feat3[(size_t)j1 * 3 + f]
                + w2 * feat3[(size_t)j2 * 3 + f];
        out3[(size_t)qorig * 3 + f] = (mode == 1) ? (base3[(size_t)qorig * 3 + f] - v) : v;
      }
    }
  }
}

// t = emb1 - interp(emb2), emitted as bf16 hi/lo splits (device body)
__device__ void build_t_body(
    int bid, const float* __restrict__ emb1, const float* __restrict__ emb2,
    const float* __restrict__ w, const int* __restrict__ idx,
    unsigned short* __restrict__ t_hi, unsigned short* __restrict__ t_lo, int Nq)
{
  int gid = bid * 256 + threadIdx.x;
  int q = gid >> 6, c4 = gid & 63;
  if (q >= Nq) return;
  float w0 = w[(size_t)q * 3 + 0], w1 = w[(size_t)q * 3 + 1], w2 = w[(size_t)q * 3 + 2];
  int i0 = idx[(size_t)q * 3 + 0], i1 = idx[(size_t)q * 3 + 1], i2 = idx[(size_t)q * 3 + 2];
  const float4* e1 = (const float4*)emb1;
  const float4* e2 = (const float4*)emb2;
  float4 a  = e1[(size_t)q * 64 + c4];
  float4 f0 = e2[(size_t)i0 * 64 + c4];
  float4 f1 = e2[(size_t)i1 * 64 + c4];
  float4 f2 = e2[(size_t)i2 * 64 + c4];
  float4 r;
  r.x = a.x - (w0 * f0.x + w1 * f1.x + w2 * f2.x);
  r.y = a.y - (w0 * f0.y + w1 * f1.y + w2 * f2.y);
  r.z = a.z - (w0 * f0.z + w1 * f1.z + w2 * f2.z);
  r.w = a.w - (w0 * f0.w + w1 * f1.w + w2 * f2.w);
  ushort4 h, l;
  h.x = f2bf(r.x); l.x = f2bf(r.x - bf2f(h.x));
  h.y = f2bf(r.y); l.y = f2bf(r.y - bf2f(h.y));
  h.z = f2bf(r.z); l.z = f2bf(r.z - bf2f(h.z));
  h.w = f2bf(r.w); l.w = f2bf(r.w - bf2f(h.w));
  size_t o = (size_t)q * 256 + c4 * 4;
  *(ushort4*)&t_hi[o] = h;
  *(ushort4*)&t_lo[o] = l;
}

// ---- fused dispatch wrappers (4:1 block interleave) ------------------------
__global__ __launch_bounds__(256) void knn_dual_kernel(
    const float4* qsA, const int* qiA, int NqA, int GA, const int* offsA, const float4* sptsA, const int* sidxA,
    float* wA, int* iA,
    const float4* qsB, const int* qiB, int NqB, int GB, const int* offsB, const float4* sptsB, const int* sidxB,
    const float* base3B, const float* feat3B, float* out3B)
{
  int g = blockIdx.x / 5, r = blockIdx.x % 5;
  if (r < 4)
    knn_body(g * 4 + r, qsA, qiA, NqA, GA, offsA, sptsA, sidxA, 0,
             nullptr, nullptr, wA, iA, nullptr);
  else
    knn_body(g, qsB, qiB, NqB, GB, offsB, sptsB, sidxB, 1,
             base3B, feat3B, nullptr, nullptr, out3B);
}

__global__ __launch_bounds__(256) void bt_knn2_kernel(
    const float* emb1, const float* emb2, const float* w, const int* idx,
    unsigned short* t_hi, unsigned short* t_lo, int Nq_bt,
    const float4* qsC, const int* qiC, int NqC, int GC, const int* offsC, const float4* sptsC, const int* sidxC,
    const float* feat3C, float* out3C)
{
  int g = blockIdx.x / 5, r = blockIdx.x % 5;
  if (r < 4)
    build_t_body(g * 4 + r, emb1, emb2, w, idx, t_hi, t_lo, Nq_bt);
  else
    knn_body(g, qsC, qiC, NqC, GC, offsC, sptsC, sidxC, 2,
             nullptr, feat3C, nullptr, nullptr, out3C);
}

// ---- grid build: 4 point sets (3 source grids + sorted h_pos1 queries) ----
__global__ __launch_bounds__(256) void zero_kernel(int* __restrict__ p, int n) {
  int i = blockIdx.x * 256 + threadIdx.x;
  if (i < n) p[i] = 0;
}

__global__ __launch_bounds__(256) void cell_count4_kernel(
    const float* __restrict__ p1, int n1, int g1, int* __restrict__ c1,
    const float* __restrict__ p2, int n2, int g2, int* __restrict__ c2,
    const float* __restrict__ p3, int n3, int g3, int* __restrict__ c3,
    const float* __restrict__ p4, int n4, int g4, int* __restrict__ c4)
{
  int b = blockIdx.x;
  const float* p; int n, G; int* cnt; int i;
  if (b < 64)       { p = p1; n = n1; G = g1; cnt = c1; i = b * 256 + threadIdx.x; }
  else if (b < 80)  { p = p2; n = n2; G = g2; cnt = c2; i = (b - 64) * 256 + threadIdx.x; }
  else if (b < 96)  { p = p3; n = n3; G = g3; cnt = c3; i = (b - 80) * 256 + threadIdx.x; }
  else              { p = p4; n = n4; G = g4; cnt = c4; i = (b - 96) * 256 + threadIdx.x; }
  if (i >= n) return;
  int cx = cell_clamp(p[3 * i],     G);
  int cy = cell_clamp(p[3 * i + 1], G);
  int cz = cell_clamp(p[3 * i + 2], G);
  atomicAdd(&cnt[(cz * G + cy) * G + cx], 1);
}

__global__ __launch_bounds__(256) void prefix4_kernel(
    const int* __restrict__ c1, int* __restrict__ o1, int* __restrict__ u1, int m1,
    const int* __restrict__ c2, int* __restrict__ o2, int* __restrict__ u2, int m2,
    const int* __restrict__ c3, int* __restrict__ o3, int* __restrict__ u3, int m3,
    const int* __restrict__ c4, int* __restrict__ o4, int* __restrict__ u4, int m4)
{
  const int* cnt; int* offs; int* cur; int M;
  if (blockIdx.x == 0)      { cnt = c1; offs = o1; cur = u1; M = m1; }
  else if (blockIdx.x == 1) { cnt = c2; offs = o2; cur = u2; M = m2; }
  else if (blockIdx.x == 2) { cnt = c3; offs = o3; cur = u3; M = m3; }
  else                      { cnt = c4; offs = o4; cur = u4; M = m4; }
  __shared__ int ps[256];
  const int tid = threadIdx.x;
  const int per = (M + 255) >> 8;
  const int base = tid * per;
  int s = 0;
  for (int j = 0; j < per; ++j) if (base + j < M) s += cnt[base + j];
  ps[tid] = s;
  __syncthreads();
  for (int off = 1; off < 256; off <<= 1) {
    int v = (tid >= off) ? ps[tid - off] : 0;
    __syncthreads();
    ps[tid] += v;
    __syncthreads();
  }
  int run = (tid > 0) ? ps[tid - 1] : 0;
  for (int j = 0; j < per; ++j) {
    if (base + j < M) {
      offs[base + j] = run; cur[base + j] = run;
      run += cnt[base + j];
    }
  }
  if (tid == 255) offs[M] = run;
}

__global__ __launch_bounds__(256) void scatter4_kernel(
    const float* __restrict__ p1, int n1, int g1, int* __restrict__ u1, float4* __restrict__ s1, int* __restrict__ x1,
    const float* __restrict__ p2, int n2, int g2, int* __restrict__ u2, float4* __restrict__ s2, int* __restrict__ x2,
    const float* __restrict__ p3, int n3, int g3, int* __restrict__ u3, float4* __restrict__ s3, int* __restrict__ x3,
    const float* __restrict__ p4, int n4, int g4, int* __restrict__ u4, float4* __restrict__ s4, int* __restrict__ x4)
{
  #pragma clang fp contract(off)
  int b = blockIdx.x;
  const float* p; int n, G; int* cur; float4* spts; int* sidx; int i;
  if (b < 64)       { p = p1; n = n1; G = g1; cur = u1; spts = s1; sidx = x1; i = b * 256 + threadIdx.x; }
  else if (b < 80)  { p = p2; n = n2; G = g2; cur = u2; spts = s2; sidx = x2; i = (b - 64) * 256 + threadIdx.x; }
  else if (b < 96)  { p = p3; n = n3; G = g3; cur = u3; spts = s3; sidx = x3; i = (b - 80) * 256 + threadIdx.x; }
  else              { p = p4; n = n4; G = g4; cur = u4; spts = s4; sidx = x4; i = (b - 96) * 256 + threadIdx.x; }
  if (i >= n) return;
  float x = p[3 * i], y = p[3 * i + 1], z = p[3 * i + 2];
  int cx = cell_clamp(x, G), cy = cell_clamp(y, G), cz = cell_clamp(z, G);
  int c = (cz * G + cy) * G + cx;
  int pos = atomicAdd(&cur[c], 1);
  float sx = (x * x + y * y) + z * z;   // sequential, no contraction
  spts[pos] = make_float4(x, y, z, sx);
  sidx[pos] = i;
}

// ---- both weight transposed-splits in one dispatch ------------------------
__global__ __launch_bounds__(256) void split_wt2_kernel(
    const float* __restrict__ W1, unsigned short* __restrict__ h1T, unsigned short* __restrict__ l1T,
    const float* __restrict__ W2, unsigned short* __restrict__ h2T, unsigned short* __restrict__ l2T)
{
  int b = blockIdx.x;
  const float* W = (b < 256) ? W1 : W2;
  unsigned short* hiT = (b < 256) ? h1T : h2T;
  unsigned short* loT = (b < 256) ? l1T : l2T;
  int id = (b & 255) * 256 + threadIdx.x;
  int k = id >> 8, n = id & 255;
  float x = W[id];
  unsigned short h = f2bf(x);
  unsigned short l = f2bf(x - bf2f(h));
  hiT[n * 256 + k] = h;
  loT[n * 256 + k] = l;
}

// ---------------------------------------------------------------------------
// bf16x3-split MFMA GEMM (verified round 12 — absmax 0.0625)
// ---------------------------------------------------------------------------
__global__ __launch_bounds__(256) void mfma_gemm_kernel(
    const unsigned short* __restrict__ A_hi, const unsigned short* __restrict__ A_lo,
    const unsigned short* __restrict__ BT_hi, const unsigned short* __restrict__ BT_lo,
    const float* __restrict__ bias,
    float* __restrict__ outf,
    unsigned short* __restrict__ out_hi, unsigned short* __restrict__ out_lo,
    int relu, int split_out)
{
  __shared__ unsigned short Bs_hi[64][132];
  __shared__ unsigned short Bs_lo[64][132];
  const int t = threadIdx.x;
  const int d = blockIdx.x;
  const int xcd = d & 7, slot = d >> 3;
  const int lin = xcd * ((int)gridDim.x >> 3) + slot;
  const int row0 = (lin >> 2) * 64;
  const int col0 = (lin & 3) * 64;

  const int l = t & 63, w = t >> 6;
  const int lr = l & 15;
  const int lk = (l >> 4) << 3;
  const unsigned short* arh = A_hi + (size_t)(row0 + w * 16 + lr) * 256;
  const unsigned short* arl = A_lo + (size_t)(row0 + w * 16 + lr) * 256;

  const int sc = t >> 2;
  const int sk = (t & 3) << 5;

  f32x4 acc0 = {0.f,0.f,0.f,0.f}, acc1 = {0.f,0.f,0.f,0.f};
  f32x4 acc2 = {0.f,0.f,0.f,0.f}, acc3 = {0.f,0.f,0.f,0.f};

  #define KSTEP(CT, ACC)                                                      \
    { s16x8 bh = *(const s16x8*)&Bs_hi[CT * 16 + lr][kc + lk];                \
      s16x8 bl = *(const s16x8*)&Bs_lo[CT * 16 + lr][kc + lk];                \
      ACC = __builtin_amdgcn_mfma_f32_16x16x32_bf16(ah, bh, ACC, 0, 0, 0);    \
      ACC = __builtin_amdgcn_mfma_f32_16x16x32_bf16(al, bh, ACC, 0, 0, 0);    \
      ACC = __builtin_amdgcn_mfma_f32_16x16x32_bf16(ah, bl, ACC, 0, 0, 0); }

  for (int half = 0; half < 2; ++half) {
    if (half) __syncthreads();
    {
      const int4* sh = (const int4*)&BT_hi[(size_t)(col0 + sc) * 256 + half * 128 + sk];
      const int4* slo = (const int4*)&BT_lo[(size_t)(col0 + sc) * 256 + half * 128 + sk];
      int4* dh = (int4*)&Bs_hi[sc][sk];
      int4* dl = (int4*)&Bs_lo[sc][sk];
      #pragma unroll
      for (int i = 0; i < 4; ++i) { dh[i] = sh[i]; dl[i] = slo[i]; }
    }
    __syncthreads();
    const int kbase = half * 128;
    #pragma unroll
    for (int kc = 0; kc < 128; kc += 32) {
      s16x8 ah = *(const s16x8*)&arh[kbase + kc + lk];
      s16x8 al = *(const s16x8*)&arl[kbase + kc + lk];
      KSTEP(0, acc0)
      KSTEP(1, acc1)
      KSTEP(2, acc2)
      KSTEP(3, acc3)
    }
  }
  #undef KSTEP

  const int orow = row0 + w * 16 + ((l >> 4) << 2);
  #define EPILOG(CT, ACC)                                                     \
    { int col = col0 + CT * 16 + lr;                                          \
      float bb = bias[col];                                                   \
      _Pragma("unroll")                                                       \
      for (int r = 0; r < 4; ++r) {                                           \
        float v = ACC[r] + bb;                                                \
        if (relu) v = fmaxf(v, 0.0f);                                         \
        size_t o = (size_t)(orow + r) * 256 + col;                            \
        if (split_out) {                                                      \
          unsigned short hh = f2bf(v);                                        \
          out_hi[o] = hh; out_lo[o] = f2bf(v - bf2f(hh));                     \
        } else {                                                              \
          outf[o] = v;                                                        \
        }                                                                     \
      } }
  EPILOG(0, acc0)
  EPILOG(1, acc1)
  EPILOG(2, acc2)
  EPILOG(3, acc3)
  #undef EPILOG
}

// ---------------------------------------------------------------------------
// out[r, :] = h2[r, :] @ W3[256,3] + b3 + res[r, :]   (wave per row)
// ---------------------------------------------------------------------------
__global__ __launch_bounds__(256) void final_kernel(
    const float* __restrict__ h2, const float* __restrict__ W3,
    const float* __restrict__ b3, const float* __restrict__ res,
    float* __restrict__ out, int M)
{
  __shared__ float sW3[768];
  const int tid = threadIdx.x;
  for (int i = tid; i < 768; i += 256) sW3[i] = W3[i];
  __syncthreads();

  const int wave = tid >> 6, lane = tid & 63;
  const int r = blockIdx.x * 4 + wave;
  if (r >= M) return;

  float4 h = ((const float4*)h2)[(size_t)r * 64 + lane];
  const int c = lane * 4;
  float a0 = h.x * sW3[(c + 0) * 3 + 0] + h.y * sW3[(c + 1) * 3 + 0]
           + h.z * sW3[(c + 2) * 3 + 0] + h.w * sW3[(c + 3) * 3 + 0];
  float a1 = h.x * sW3[(c + 0) * 3 + 1] + h.y * sW3[(c + 1) * 3 + 1]
           + h.z * sW3[(c + 2) * 3 + 1] + h.w * sW3[(c + 3) * 3 + 1];
  float a2 = h.x * sW3[(c + 0) * 3 + 2] + h.y * sW3[(c + 1) * 3 + 2]
           + h.z * sW3[(c + 2) * 3 + 2] + h.w * sW3[(c + 3) * 3 + 2];

  #pragma unroll
  for (int off = 32; off; off >>= 1) {
    a0 += __shfl_xor(a0, off);
    a1 += __shfl_xor(a1, off);
    a2 += __shfl_xor(a2, off);
  }
  if (lane == 0) {
    out[(size_t)r * 3 + 0] = a0 + b3[0] + res[(size_t)r * 3 + 0];
    out[(size_t)r * 3 + 1] = a1 + b3[1] + res[(size_t)r * 3 + 1];
    out[(size_t)r * 3 + 2] = a2 + b3[2] + res[(size_t)r * 3 + 2];
  }
}

// ---------------------------------------------------------------------------
extern "C" void kernel_launch(void* const* d_in, const int* in_sizes, int n_in,
                              void* d_out, int out_size, void* d_ws, size_t ws_size,
                              hipStream_t stream) {
  (void)in_sizes; (void)n_in; (void)out_size; (void)ws_size;
  const float* emb1   = (const float*)d_in[0];
  const float* l_y1   = (const float*)d_in[1];
  const float* l_pos1 = (const float*)d_in[2];
  const float* h_pos1 = (const float*)d_in[3];
  const float* emb2   = (const float*)d_in[4];
  const float* l_y2   = (const float*)d_in[5];
  const float* l_pos2 = (const float*)d_in[6];
  const float* h_pos2 = (const float*)d_in[7];
  const float* W1     = (const float*)d_in[8];
  const float* b1     = (const float*)d_in[9];
  const float* W2     = (const float*)d_in[10];
  const float* b2     = (const float*)d_in[11];
  const float* W3     = (const float*)d_in[12];
  const float* b3     = (const float*)d_in[13];
  float* out = (float*)d_out;

  const int Nh = 16384, Nl = 4096, H = 256;
  const int G1 = 16, G2 = 10;
  const int M1 = G1 * G1 * G1, M2 = G2 * G2 * G2;

  // ---- workspace carve-up (sequential bump allocator, 256B aligned) ----
  char* wsp = (char*)d_ws;
  size_t off = 0;
  auto alloc = [&](size_t bytes) -> void* {
    void* p = wsp + off;
    off += (bytes + 255) & ~(size_t)255;
    return p;
  };
  int*            idxA   = (int*)           alloc((size_t)Nh * 3 * 4);
  float*          wA     = (float*)         alloc((size_t)Nh * 3 * 4);
  unsigned short* t_hi   = (unsigned short*)alloc((size_t)Nh * H * 2);
  unsigned short* t_lo   = (unsigned short*)alloc((size_t)Nh * H * 2);
  unsigned short* h1_hi  = (unsigned short*)alloc((size_t)Nh * H * 2);
  unsigned short* h1_lo  = (unsigned short*)alloc((size_t)Nh * H * 2);
  float*          h2     = (float*)t_hi;    // alias over t_hi+t_lo (t dead)
  unsigned short* w1t_hi = (unsigned short*)alloc((size_t)H * H * 2);
  unsigned short* w1t_lo = (unsigned short*)alloc((size_t)H * H * 2);
  unsigned short* w2t_hi = (unsigned short*)alloc((size_t)H * H * 2);
  unsigned short* w2t_lo = (unsigned short*)alloc((size_t)H * H * 2);
  float*          diff   = (float*)         alloc((size_t)Nl * 3 * 4);
  float*          res    = (float*)         alloc((size_t)Nh * 3 * 4);
  int*            cnts   = (int*)           alloc((size_t)(M1 + M2 + M2 + M1) * 4);
  int* cnt1 = cnts, *cnt2 = cnts + M1, *cnt3 = cnts + M1 + M2, *cnt4 = cnts + M1 + 2 * M2;
  int*            offs1  = (int*)           alloc((size_t)(M1 + 1) * 4);
  int*            cur1   = (int*)           alloc((size_t)M1 * 4);
  int*            offs2  = (int*)           alloc((size_t)(M2 + 1) * 4);
  int*            cur2   = (int*)           alloc((size_t)M2 * 4);
  int*            offs3  = (int*)           alloc((size_t)(M2 + 1) * 4);
  int*            cur3   = (int*)           alloc((size_t)M2 * 4);
  int*            offs4  = (int*)           alloc((size_t)(M1 + 1) * 4);
  int*            cur4   = (int*)           alloc((size_t)M1 * 4);
  float4*         spts1  = (float4*)        alloc((size_t)Nh * 16);
  int*            sidx1  = (int*)           alloc((size_t)Nh * 4);
  float4*         spts2  = (float4*)        alloc((size_t)Nl * 16);
  int*            sidx2  = (int*)           alloc((size_t)Nl * 4);
  float4*         spts3  = (float4*)        alloc((size_t)Nl * 16);
  int*            sidx3  = (int*)           alloc((size_t)Nl * 4);
  float4*         qspts  = (float4*)        alloc((size_t)Nh * 16);   // sorted h_pos1
  int*            qsidx  = (int*)           alloc((size_t)Nh * 4);

  // ---- build grids (3 source + 1 query sort) + weight splits ----
  const int ncnt = M1 + M2 + M2 + M1;
  zero_kernel<<<(ncnt + 255) / 256, 256, 0, stream>>>(cnts, ncnt);
  cell_count4_kernel<<<160, 256, 0, stream>>>(
      h_pos2, Nh, G1, cnt1,  l_pos2, Nl, G2, cnt2,
      l_pos1, Nl, G2, cnt3,  h_pos1, Nh, G1, cnt4);
  prefix4_kernel<<<4, 256, 0, stream>>>(
      cnt1, offs1, cur1, M1,  cnt2, offs2, cur2, M2,
      cnt3, offs3, cur3, M2,  cnt4, offs4, cur4, M1);
  scatter4_kernel<<<160, 256, 0, stream>>>(
      h_pos2, Nh, G1, cur1, spts1, sidx1,
      l_pos2, Nl, G2, cur2, spts2, sidx2,
      l_pos1, Nl, G2, cur3, spts3, sidx3,
      h_pos1, Nh, G1, cur4, qspts, qsidx);
  split_wt2_kernel<<<512, 256, 0, stream>>>(
      W1, w1t_hi, w1t_lo, W2, w2t_hi, w2t_lo);

  // ---- knn0 (sorted h_pos1 vs grid1, mode0) || knn1 (sorted l_pos1=grid3 order vs grid2, mode1) ----
  knn_dual_kernel<<<1280, 256, 0, stream>>>(
      qspts, qsidx, Nh, G1, offs1, spts1, sidx1, wA, idxA,
      spts3, sidx3, Nl, G2, offs2, spts2, sidx2, l_y1, l_y2, diff);

  // ---- build_t || knn2 (sorted h_pos1 vs grid3, mode2 -> res) ----
  bt_knn2_kernel<<<5120, 256, 0, stream>>>(
      emb1, emb2, wA, idxA, t_hi, t_lo, Nh,
      qspts, qsidx, Nh, G2, offs3, spts3, sidx3, diff, res);

  // ---- MLP ----
  mfma_gemm_kernel<<<(Nh / 64) * 4, 256, 0, stream>>>(
      t_hi, t_lo, w1t_hi, w1t_lo, b1, nullptr, h1_hi, h1_lo, 1, 1);
  mfma_gemm_kernel<<<(Nh / 64) * 4, 256, 0, stream>>>(
      h1_hi, h1_lo, w2t_hi, w2t_lo, b2, h2, nullptr, nullptr, 1, 0);

  // ---- final: out = (h2 @ W3 + b3) + res ----
  final_kernel<<<Nh / 4, 256, 0, stream>>>(h2, W3, b3, res, out, Nh);
}

// Round 15
// 132.836 us; speedup vs baseline: 1.7229x; 1.0955x over previous
//
#include <hip/hip_runtime.h>
#include <math.h>

#define BIGF 3.0e38f

typedef short  s16x8 __attribute__((ext_vector_type(8)));
typedef float  f32x4 __attribute__((ext_vector_type(4)));

// bf16 helpers (manual RNE)
__device__ __forceinline__ unsigned short f2bf(float x) {
  unsigned int b = __float_as_uint(x);
  unsigned int r = b + 0x7FFFu + ((b >> 16) & 1u);
  return (unsigned short)(r >> 16);
}
__device__ __forceinline__ float bf2f(unsigned short h) {
  return __uint_as_float(((unsigned int)h) << 16);
}

// ===========================================================================
// Spatial-hash KNN (K=3), 16 lanes per query, row-range shell scan,
// cell-sorted query order. Selection replicates the np reference's fp32
// expansion distance:
//   sx  = (x*x + y*y) + z*z            (sequential, individually rounded)
//   dot = (p0 + p1) + p2, p_k = q_k*s_k
//   d2  = (sy + sx) - 2*dot
// under fp contract(off) — verified rounds 3-6. DO NOT TOUCH.
// Tie-break: lexicographic (d, idx). Every candidate visited EXACTLY once.
// ===========================================================================

__device__ __forceinline__ int cell_clamp(float v, int G) {
  int c = (int)(v * (float)G);
  return min(G - 1, max(0, c));
}

__device__ __forceinline__ void ins3(float d, int id,
                                     float& d0, float& d1, float& d2,
                                     int& i0, int& i1, int& i2) {
  bool l0 = (d < d0) || (d == d0 && id < i0);
  bool l1 = (d < d1) || (d == d1 && id < i1);
  bool l2 = (d < d2) || (d == d2 && id < i2);
  float nd0 = l0 ? d  : d0;  int ni0 = l0 ? id : i0;
  float nd1 = l0 ? d0 : (l1 ? d  : d1);
  int   ni1 = l0 ? i0 : (l1 ? id : i1);
  float nd2 = l1 ? d1 : (l2 ? d  : d2);
  int   ni2 = l1 ? i1 : (l2 ? id : i2);
  d0 = nd0; d1 = nd1; d2 = nd2; i0 = ni0; i1 = ni1; i2 = ni2;
}

// mode 0: w_out/i_out at orig idx;  mode 1: out3 = base3 - interp
__device__ void knn_body(
    int bid,
    const float4* __restrict__ qspts, const int* __restrict__ qsidx, int Nq, int G,
    const int* __restrict__ offs,
    const float4* __restrict__ spts,
    const int* __restrict__ sidx,
    int mode,
    const float* __restrict__ base3,
    const float* __restrict__ feat3,
    float* __restrict__ w_out, int* __restrict__ i_out,
    float* __restrict__ out3)
{
  #pragma clang fp contract(off)
  const int sl = threadIdx.x & 15;
  const int qs = bid * 16 + (threadIdx.x >> 4);
  if (qs >= Nq) return;

  float4 qv = qspts[qs];
  const float qx = qv.x, qy = qv.y, qz = qv.z;
  const float sy = qv.w;                       // |q|^2, same formula (scatter)
  const int qorig = qsidx[qs];
  const float cs = 1.0f / (float)G;
  const int cx = cell_clamp(qx, G), cy = cell_clamp(qy, G), cz = cell_clamp(qz, G);

  float d0 = BIGF, d1 = BIGF, d2v = BIGF;   // per-lane local top-3 (disjoint)
  int i0 = -1, i1 = -1, i2 = -1;
  float e0 = BIGF, e1 = BIGF, e2 = BIGF;    // merged top-3
  int j0 = -1, j1 = -1, j2 = -1;
  bool done = false;

  #define SCAN()                                                              \
    for (int j = js; j < je; ++j) {                                           \
      float4 s = spts[j];                                                     \
      float p0 = qx * s.x, p1 = qy * s.y, p2 = qz * s.z;                      \
      float dt = (p0 + p1) + p2;                                              \
      float S  = sy + s.w;                                                    \
      float dd = S - 2.0f * dt;                                               \
      ins3(dd, sidx[j], d0, d1, d2v, i0, i1, i2);                             \
    }

  for (int R = 1; R <= G; ++R) {
    if (!done) {
      if (R == 1) {
        if (sl < 9) {
          int dy = sl % 3 - 1, dz = sl / 3 - 1;
          int yy = cy + dy, zz = cz + dz;
          if (yy >= 0 && yy < G && zz >= 0 && zz < G) {
            int xs = max(cx - 1, 0), xe = min(cx + 1, G - 1);
            int base = (zz * G + yy) * G;
            int js = offs[base + xs], je = offs[base + xe + 1];
            SCAN()
          }
        }
      } else {
        const int twoR1 = 2 * R + 1, inner = 2 * R - 1;
        const int nfz = 2 * twoR1;
        const int nfull = nfz + 2 * inner;
        const int half = inner * inner;
        const int nitems = nfull + 2 * half;
        for (int m = sl; m < nitems; m += 16) {
          int dy, dz, js, je;
          if (m < nfull) {
            if (m < nfz) { dz = (m < twoR1) ? -R : R; dy = (m % twoR1) - R; }
            else { int u = m - nfz; dy = (u < inner) ? -R : R; dz = (u % inner) - (R - 1); }
            int yy = cy + dy, zz = cz + dz;
            if (yy < 0 || yy >= G || zz < 0 || zz >= G) continue;
            int xs = max(cx - R, 0), xe = min(cx + R, G - 1);
            int base = (zz * G + yy) * G;
            js = offs[base + xs]; je = offs[base + xe + 1];
          } else {
            int u = m - nfull;
            int xc = (u < half) ? (cx - R) : (cx + R);
            int r2 = (u < half) ? u : u - half;
            dy = r2 % inner - (R - 1); dz = r2 / inner - (R - 1);
            int yy = cy + dy, zz = cz + dz;
            if (xc < 0 || xc >= G || yy < 0 || yy >= G || zz < 0 || zz >= G) continue;
            int c = (zz * G + yy) * G + xc;
            js = offs[c]; je = offs[c + 1];
          }
          SCAN()
        }
      }
    }
    e0 = d0; e1 = d1; e2 = d2v; j0 = i0; j1 = i1; j2 = i2;
    #pragma unroll
    for (int msk = 1; msk < 16; msk <<= 1) {
      float o0 = __shfl_xor(e0, msk), o1 = __shfl_xor(e1, msk), o2 = __shfl_xor(e2, msk);
      int   p0 = __shfl_xor(j0, msk), p1 = __shfl_xor(j1, msk), p2 = __shfl_xor(j2, msk);
      ins3(o0, p0, e0, e1, e2, j0, j1, j2);
      ins3(o1, p1, e0, e1, e2, j0, j1, j2);
      ins3(o2, p2, e0, e1, e2, j0, j1, j2);
    }
    float bnd = (float)R * cs;
    done = done || (e2 <= bnd * bnd - 1e-6f);
    if (__all(done)) break;
  }
  #undef SCAN

  if (sl == 0) {
    float w0 = 1.0f / fmaxf(e0, 1e-16f);
    float w1 = 1.0f / fmaxf(e1, 1e-16f);
    float w2 = 1.0f / fmaxf(e2, 1e-16f);
    float inv = 1.0f / (w0 + w1 + w2);
    w0 *= inv; w1 *= inv; w2 *= inv;
    if (mode == 0) {
      w_out[(size_t)qorig * 3 + 0] = w0; w_out[(size_t)qorig * 3 + 1] = w1; w_out[(size_t)qorig * 3 + 2] = w2;
      i_out[(size_t)qorig * 3 + 0] = j0; i_out[(size_t)qorig * 3 + 1] = j1; i_out[(size_t)qorig * 3 + 2] = j2;
    } else {
      #pragma unroll
      for (int f = 0; f < 3; ++f) {
        float v = w0 * feat3[(size_t)j0 * 3 + f]
                + w1 * feat3[(size_t)j1 * 3 + f]
                + w2 * feat3[(size_t)j2 * 3 + f];
        out3[(size_t)qorig * 3 + f] = (mode == 1) ? (base3[(size_t)qorig * 3 + f] - v) : v;
      }
    }
  }
}

// t = emb1 - interp(emb2), emitted as bf16 hi/lo splits (device body)
__device__ void build_t_body(
    int bid, const float* __restrict__ emb1, const float* __restrict__ emb2,
    const float* __restrict__ w, const int* __restrict__ idx,
    unsigned short* __restrict__ t_hi, unsigned short* __restrict__ t_lo, int Nq)
{
  int gid = bid * 256 + threadIdx.x;
  int q = gid >> 6, c4 = gid & 63;
  if (q >= Nq) return;
  float w0 = w[(size_t)q * 3 + 0], w1 = w[(size_t)q * 3 + 1], w2 = w[(size_t)q * 3 + 2];
  int i0 = idx[(size_t)q * 3 + 0], i1 = idx[(size_t)q * 3 + 1], i2 = idx[(size_t)q * 3 + 2];
  const float4* e1 = (const float4*)emb1;
  const float4* e2 = (const float4*)emb2;
  float4 a  = e1[(size_t)q * 64 + c4];
  float4 f0 = e2[(size_t)i0 * 64 + c4];
  float4 f1 = e2[(size_t)i1 * 64 + c4];
  float4 f2 = e2[(size_t)i2 * 64 + c4];
  float4 r;
  r.x = a.x - (w0 * f0.x + w1 * f1.x + w2 * f2.x);
  r.y = a.y - (w0 * f0.y + w1 * f1.y + w2 * f2.y);
  r.z = a.z - (w0 * f0.z + w1 * f1.z + w2 * f2.z);
  r.w = a.w - (w0 * f0.w + w1 * f1.w + w2 * f2.w);
  ushort4 h, l;
  h.x = f2bf(r.x); l.x = f2bf(r.x - bf2f(h.x));
  h.y = f2bf(r.y); l.y = f2bf(r.y - bf2f(h.y));
  h.z = f2bf(r.z); l.z = f2bf(r.z - bf2f(h.z));
  h.w = f2bf(r.w); l.w = f2bf(r.w - bf2f(h.w));
  size_t o = (size_t)q * 256 + c4 * 4;
  *(ushort4*)&t_hi[o] = h;
  *(ushort4*)&t_lo[o] = l;
}

// res[q,:] = sum_k wC[q,k] * diff[idxC[q,k],:]   (one thread per query)
__device__ void res_gather_body(
    int bid, const float* __restrict__ wC, const int* __restrict__ idxC,
    const float* __restrict__ diff, float* __restrict__ res, int Nq)
{
  int q = bid * 256 + threadIdx.x;
  if (q >= Nq) return;
  float w0 = wC[(size_t)q * 3 + 0], w1 = wC[(size_t)q * 3 + 1], w2 = wC[(size_t)q * 3 + 2];
  int i0 = idxC[(size_t)q * 3 + 0], i1 = idxC[(size_t)q * 3 + 1], i2 = idxC[(size_t)q * 3 + 2];
  #pragma unroll
  for (int f = 0; f < 3; ++f) {
    res[(size_t)q * 3 + f] = w0 * diff[(size_t)i0 * 3 + f]
                           + w1 * diff[(size_t)i1 * 3 + f]
                           + w2 * diff[(size_t)i2 * 3 + f];
  }
}

// ---- knn_triple: knn0 || knn1 || knn2-search (all independent) ------------
// 2304 blocks = 256 groups x {4 knn0, 1 knn1, 4 knn2s}
__global__ __launch_bounds__(256) void knn_triple_kernel(
    const float4* qspts, const int* qsidx, int Nh, int G1,
    const int* offs1, const float4* spts1, const int* sidx1, float* wA, int* idxA,
    const float4* spts3, const int* sidx3, int Nl, int G2,
    const int* offs2, const float4* spts2, const int* sidx2,
    const float* l_y1, const float* l_y2, float* diff,
    const int* offs3, float* wC, int* idxC)
{
  int g = blockIdx.x / 9, r = blockIdx.x % 9;
  if (r < 4)
    knn_body(g * 4 + r, qspts, qsidx, Nh, G1, offs1, spts1, sidx1, 0,
             nullptr, nullptr, wA, idxA, nullptr);
  else if (r == 4)
    knn_body(g, spts3, sidx3, Nl, G2, offs2, spts2, sidx2, 1,
             l_y1, l_y2, nullptr, nullptr, diff);
  else
    knn_body(g * 4 + (r - 5), qspts, qsidx, Nh, G2, offs3, spts3, sidx3, 0,
             nullptr, nullptr, wC, idxC, nullptr);
}

// ---- bt_gather: res-gather (blocks 0..63) || build_t (blocks 64..4159) ----
__global__ __launch_bounds__(256) void bt_gather_kernel(
    const float* emb1, const float* emb2, const float* w, const int* idx,
    unsigned short* t_hi, unsigned short* t_lo, int Nq_bt,
    const float* wC, const int* idxC, const float* diff, float* res, int NqG)
{
  if (blockIdx.x < 64)
    res_gather_body(blockIdx.x, wC, idxC, diff, res, NqG);
  else
    build_t_body(blockIdx.x - 64, emb1, emb2, w, idx, t_hi, t_lo, Nq_bt);
}

// ---- grid build: 4 point sets (3 source grids + sorted h_pos1 queries) ----
__global__ __launch_bounds__(256) void zero_kernel(int* __restrict__ p, int n) {
  int i = blockIdx.x * 256 + threadIdx.x;
  if (i < n) p[i] = 0;
}

__global__ __launch_bounds__(256) void cell_count4_kernel(
    const float* __restrict__ p1, int n1, int g1, int* __restrict__ c1,
    const float* __restrict__ p2, int n2, int g2, int* __restrict__ c2,
    const float* __restrict__ p3, int n3, int g3, int* __restrict__ c3,
    const float* __restrict__ p4, int n4, int g4, int* __restrict__ c4)
{
  int b = blockIdx.x;
  const float* p; int n, G; int* cnt; int i;
  if (b < 64)       { p = p1; n = n1; G = g1; cnt = c1; i = b * 256 + threadIdx.x; }
  else if (b < 80)  { p = p2; n = n2; G = g2; cnt = c2; i = (b - 64) * 256 + threadIdx.x; }
  else if (b < 96)  { p = p3; n = n3; G = g3; cnt = c3; i = (b - 80) * 256 + threadIdx.x; }
  else              { p = p4; n = n4; G = g4; cnt = c4; i = (b - 96) * 256 + threadIdx.x; }
  if (i >= n) return;
  int cx = cell_clamp(p[3 * i],     G);
  int cy = cell_clamp(p[3 * i + 1], G);
  int cz = cell_clamp(p[3 * i + 2], G);
  atomicAdd(&cnt[(cz * G + cy) * G + cx], 1);
}

__global__ __launch_bounds__(256) void prefix4_kernel(
    const int* __restrict__ c1, int* __restrict__ o1, int* __restrict__ u1, int m1,
    const int* __restrict__ c2, int* __restrict__ o2, int* __restrict__ u2, int m2,
    const int* __restrict__ c3, int* __restrict__ o3, int* __restrict__ u3, int m3,
    const int* __restrict__ c4, int* __restrict__ o4, int* __restrict__ u4, int m4)
{
  const int* cnt; int* offs; int* cur; int M;
  if (blockIdx.x == 0)      { cnt = c1; offs = o1; cur = u1; M = m1; }
  else if (blockIdx.x == 1) { cnt = c2; offs = o2; cur = u2; M = m2; }
  else if (blockIdx.x == 2) { cnt = c3; offs = o3; cur = u3; M = m3; }
  else                      { cnt = c4; offs = o4; cur = u4; M = m4; }
  __shared__ int ps[256];
  const int tid = threadIdx.x;
  const int per = (M + 255) >> 8;
  const int base = tid * per;
  int s = 0;
  for (int j = 0; j < per; ++j) if (base + j < M) s += cnt[base + j];
  ps[tid] = s;
  __syncthreads();
  for (int off = 1; off < 256; off <<= 1) {
    int v = (tid >= off) ? ps[tid - off] : 0;
    __syncthreads();
    ps[tid] += v;
    __syncthreads();
  }
  int run = (tid > 0) ? ps[tid - 1] : 0;
  for (int j = 0; j < per; ++j) {
    if (base + j < M) {
      offs[base + j] = run; cur[base + j] = run;
      run += cnt[base + j];
    }
  }
  if (tid == 255) offs[M] = run;
}

__global__ __launch_bounds__(256) void scatter4_kernel(
    const float* __restrict__ p1, int n1, int g1, int* __restrict__ u1, float4* __restrict__ s1, int* __restrict__ x1,
    const float* __restrict__ p2, int n2, int g2, int* __restrict__ u2, float4* __restrict__ s2, int* __restrict__ x2,
    const float* __restrict__ p3, int n3, int g3, int* __restrict__ u3, float4* __restrict__ s3, int* __restrict__ x3,
    const float* __restrict__ p4, int n4, int g4, int* __restrict__ u4, float4* __restrict__ s4, int* __restrict__ x4)
{
  #pragma clang fp contract(off)
  int b = blockIdx.x;
  const float* p; int n, G; int* cur; float4* spts; int* sidx; int i;
  if (b < 64)       { p = p1; n = n1; G = g1; cur = u1; spts = s1; sidx = x1; i = b * 256 + threadIdx.x; }
  else if (b < 80)  { p = p2; n = n2; G = g2; cur = u2; spts = s2; sidx = x2; i = (b - 64) * 256 + threadIdx.x; }
  else if (b < 96)  { p = p3; n = n3; G = g3; cur = u3; spts = s3; sidx = x3; i = (b - 80) * 256 + threadIdx.x; }
  else              { p = p4; n = n4; G = g4; cur = u4; spts = s4; sidx = x4; i = (b - 96) * 256 + threadIdx.x; }
  if (i >= n) return;
  float x = p[3 * i], y = p[3 * i + 1], z = p[3 * i + 2];
  int cx = cell_clamp(x, G), cy = cell_clamp(y, G), cz = cell_clamp(z, G);
  int c = (cz * G + cy) * G + cx;
  int pos = atomicAdd(&cur[c], 1);
  float sx = (x * x + y * y) + z * z;   // sequential, no contraction
  spts[pos] = make_float4(x, y, z, sx);
  sidx[pos] = i;
}

// ---- both weight transposed-splits in one dispatch ------------------------
__global__ __launch_bounds__(256) void split_wt2_kernel(
    const float* __restrict__ W1, unsigned short* __restrict__ h1T, unsigned short* __restrict__ l1T,
    const float* __restrict__ W2, unsigned short* __restrict__ h2T, unsigned short* __restrict__ l2T)
{
  int b = blockIdx.x;
  const float* W = (b < 256) ? W1 : W2;
  unsigned short* hiT = (b < 256) ? h1T : h2T;
  unsigned short* loT = (b < 256) ? l1T : l2T;
  int id = (b & 255) * 256 + threadIdx.x;
  int k = id >> 8, n = id & 255;
  float x = W[id];
  unsigned short h = f2bf(x);
  unsigned short l = f2bf(x - bf2f(h));
  hiT[n * 256 + k] = h;
  loT[n * 256 + k] = l;
}

// ---------------------------------------------------------------------------
// bf16x3-split MFMA GEMM (verified round 12 — absmax 0.0625)
// ---------------------------------------------------------------------------
__global__ __launch_bounds__(256) void mfma_gemm_kernel(
    const unsigned short* __restrict__ A_hi, const unsigned short* __restrict__ A_lo,
    const unsigned short* __restrict__ BT_hi, const unsigned short* __restrict__ BT_lo,
    const float* __restrict__ bias,
    float* __restrict__ outf,
    unsigned short* __restrict__ out_hi, unsigned short* __restrict__ out_lo,
    int relu, int split_out)
{
  __shared__ unsigned short Bs_hi[64][132];
  __shared__ unsigned short Bs_lo[64][132];
  const int t = threadIdx.x;
  const int d = blockIdx.x;
  const int xcd = d & 7, slot = d >> 3;
  const int lin = xcd * ((int)gridDim.x >> 3) + slot;
  const int row0 = (lin >> 2) * 64;
  const int col0 = (lin & 3) * 64;

  const int l = t & 63, w = t >> 6;
  const int lr = l & 15;
  const int lk = (l >> 4) << 3;
  const unsigned short* arh = A_hi + (size_t)(row0 + w * 16 + lr) * 256;
  const unsigned short* arl = A_lo + (size_t)(row0 + w * 16 + lr) * 256;

  const int sc = t >> 2;
  const int sk = (t & 3) << 5;

  f32x4 acc0 = {0.f,0.f,0.f,0.f}, acc1 = {0.f,0.f,0.f,0.f};
  f32x4 acc2 = {0.f,0.f,0.f,0.f}, acc3 = {0.f,0.f,0.f,0.f};

  #define KSTEP(CT, ACC)                                                      \
    { s16x8 bh = *(const s16x8*)&Bs_hi[CT * 16 + lr][kc + lk];                \
      s16x8 bl = *(const s16x8*)&Bs_lo[CT * 16 + lr][kc + lk];                \
      ACC = __builtin_amdgcn_mfma_f32_16x16x32_bf16(ah, bh, ACC, 0, 0, 0);    \
      ACC = __builtin_amdgcn_mfma_f32_16x16x32_bf16(al, bh, ACC, 0, 0, 0);    \
      ACC = __builtin_amdgcn_mfma_f32_16x16x32_bf16(ah, bl, ACC, 0, 0, 0); }

  for (int half = 0; half < 2; ++half) {
    if (half) __syncthreads();
    {
      const int4* sh = (const int4*)&BT_hi[(size_t)(col0 + sc) * 256 + half * 128 + sk];
      const int4* slo = (const int4*)&BT_lo[(size_t)(col0 + sc) * 256 + half * 128 + sk];
      int4* dh = (int4*)&Bs_hi[sc][sk];
      int4* dl = (int4*)&Bs_lo[sc][sk];
      #pragma unroll
      for (int i = 0; i < 4; ++i) { dh[i] = sh[i]; dl[i] = slo[i]; }
    }
    __syncthreads();
    const int kbase = half * 128;
    #pragma unroll
    for (int kc = 0; kc < 128; kc += 32) {
      s16x8 ah = *(const s16x8*)&arh[kbase + kc + lk];
      s16x8 al = *(const s16x8*)&arl[kbase + kc + lk];
      KSTEP(0, acc0)
      KSTEP(1, acc1)
      KSTEP(2, acc2)
      KSTEP(3, acc3)
    }
  }
  #undef KSTEP

  const int orow = row0 + w * 16 + ((l >> 4) << 2);
  #define EPILOG(CT, ACC)                                                     \
    { int col = col0 + CT * 16 + lr;                                          \
      float bb = bias[col];                                                   \
      _Pragma("unroll")                                                       \
      for (int r = 0; r < 4; ++r) {                                           \
        float v = ACC[r] + bb;                                                \
        if (relu) v = fmaxf(v, 0.0f);                                         \
        size_t o = (size_t)(orow + r) * 256 + col;                            \
        if (split_out) {                                                      \
          unsigned short hh = f2bf(v);                                        \
          out_hi[o] = hh; out_lo[o] = f2bf(v - bf2f(hh));                     \
        } else {                                                              \
          outf[o] = v;                                                        \
        }                                                                     \
      } }
  EPILOG(0, acc0)
  EPILOG(1, acc1)
  EPILOG(2, acc2)
  EPILOG(3, acc3)
  #undef EPILOG
}

// ---------------------------------------------------------------------------
// out[r, :] = h2[r, :] @ W3[256,3] + b3 + res[r, :]   (wave per row)
// ---------------------------------------------------------------------------
__global__ __launch_bounds__(256) void final_kernel(
    const float* __restrict__ h2, const float* __restrict__ W3,
    const float* __restrict__ b3, const float* __restrict__ res,
    float* __restrict__ out, int M)
{
  __shared__ float sW3[768];
  const int tid = threadIdx.x;
  for (int i = tid; i < 768; i += 256) sW3[i] = W3[i];
  __syncthreads();

  const int wave = tid >> 6, lane = tid & 63;
  const int r = blockIdx.x * 4 + wave;
  if (r >= M) return;

  float4 h = ((const float4*)h2)[(size_t)r * 64 + lane];
  const int c = lane * 4;
  float a0 = h.x * sW3[(c + 0) * 3 + 0] + h.y * sW3[(c + 1) * 3 + 0]
           + h.z * sW3[(c + 2) * 3 + 0] + h.w * sW3[(c + 3) * 3 + 0];
  float a1 = h.x * sW3[(c + 0) * 3 + 1] + h.y * sW3[(c + 1) * 3 + 1]
           + h.z * sW3[(c + 2) * 3 + 1] + h.w * sW3[(c + 3) * 3 + 1];
  float a2 = h.x * sW3[(c + 0) * 3 + 2] + h.y * sW3[(c + 1) * 3 + 2]
           + h.z * sW3[(c + 2) * 3 + 2] + h.w * sW3[(c + 3) * 3 + 2];

  #pragma unroll
  for (int off = 32; off; off >>= 1) {
    a0 += __shfl_xor(a0, off);
    a1 += __shfl_xor(a1, off);
    a2 += __shfl_xor(a2, off);
  }
  if (lane == 0) {
    out[(size_t)r * 3 + 0] = a0 + b3[0] + res[(size_t)r * 3 + 0];
    out[(size_t)r * 3 + 1] = a1 + b3[1] + res[(size_t)r * 3 + 1];
    out[(size_t)r * 3 + 2] = a2 + b3[2] + res[(size_t)r * 3 + 2];
  }
}

// ---------------------------------------------------------------------------
extern "C" void kernel_launch(void* const* d_in, const int* in_sizes, int n_in,
                              void* d_out, int out_size, void* d_ws, size_t ws_size,
                              hipStream_t stream) {
  (void)in_sizes; (void)n_in; (void)out_size; (void)ws_size;
  const float* emb1   = (const float*)d_in[0];
  const float* l_y1   = (const float*)d_in[1];
  const float* l_pos1 = (const float*)d_in[2];
  const float* h_pos1 = (const float*)d_in[3];
  const float* emb2   = (const float*)d_in[4];
  const float* l_y2   = (const float*)d_in[5];
  const float* l_pos2 = (const float*)d_in[6];
  const float* h_pos2 = (const float*)d_in[7];
  const float* W1     = (const float*)d_in[8];
  const float* b1     = (const float*)d_in[9];
  const float* W2     = (const float*)d_in[10];
  const float* b2     = (const float*)d_in[11];
  const float* W3     = (const float*)d_in[12];
  const float* b3     = (const float*)d_in[13];
  float* out = (float*)d_out;

  const int Nh = 16384, Nl = 4096, H = 256;
  const int G1 = 16, G2 = 10;
  const int M1 = G1 * G1 * G1, M2 = G2 * G2 * G2;

  // ---- workspace carve-up (sequential bump allocator, 256B aligned) ----
  char* wsp = (char*)d_ws;
  size_t off = 0;
  auto alloc = [&](size_t bytes) -> void* {
    void* p = wsp + off;
    off += (bytes + 255) & ~(size_t)255;
    return p;
  };
  int*            idxA   = (int*)           alloc((size_t)Nh * 3 * 4);
  float*          wA     = (float*)         alloc((size_t)Nh * 3 * 4);
  int*            idxC   = (int*)           alloc((size_t)Nh * 3 * 4);
  float*          wC     = (float*)         alloc((size_t)Nh * 3 * 4);
  unsigned short* t_hi   = (unsigned short*)alloc((size_t)Nh * H * 2);
  unsigned short* t_lo   = (unsigned short*)alloc((size_t)Nh * H * 2);
  unsigned short* h1_hi  = (unsigned short*)alloc((size_t)Nh * H * 2);
  unsigned short* h1_lo  = (unsigned short*)alloc((size_t)Nh * H * 2);
  float*          h2     = (float*)t_hi;    // alias over t_hi+t_lo (t dead)
  unsigned short* w1t_hi = (unsigned short*)alloc((size_t)H * H * 2);
  unsigned short* w1t_lo = (unsigned short*)alloc((size_t)H * H * 2);
  unsigned short* w2t_hi = (unsigned short*)alloc((size_t)H * H * 2);
  unsigned short* w2t_lo = (unsigned short*)alloc((size_t)H * H * 2);
  float*          diff   = (float*)         alloc((size_t)Nl * 3 * 4);
  float*          res    = (float*)         alloc((size_t)Nh * 3 * 4);
  int*            cnts   = (int*)           alloc((size_t)(M1 + M2 + M2 + M1) * 4);
  int* cnt1 = cnts, *cnt2 = cnts + M1, *cnt3 = cnts + M1 + M2, *cnt4 = cnts + M1 + 2 * M2;
  int*            offs1  = (int*)           alloc((size_t)(M1 + 1) * 4);
  int*            cur1   = (int*)           alloc((size_t)M1 * 4);
  int*            offs2  = (int*)           alloc((size_t)(M2 + 1) * 4);
  int*            cur2   = (int*)           alloc((size_t)M2 * 4);
  int*            offs3  = (int*)           alloc((size_t)(M2 + 1) * 4);
  int*            cur3   = (int*)           alloc((size_t)M2 * 4);
  int*            offs4  = (int*)           alloc((size_t)(M1 + 1) * 4);
  int*            cur4   = (int*)           alloc((size_t)M1 * 4);
  float4*         spts1  = (float4*)        alloc((size_t)Nh * 16);
  int*            sidx1  = (int*)           alloc((size_t)Nh * 4);
  float4*         spts2  = (float4*)        alloc((size_t)Nl * 16);
  int*            sidx2  = (int*)           alloc((size_t)Nl * 4);
  float4*         spts3  = (float4*)        alloc((size_t)Nl * 16);
  int*            sidx3  = (int*)           alloc((size_t)Nl * 4);
  float4*         qspts  = (float4*)        alloc((size_t)Nh * 16);   // sorted h_pos1
  int*            qsidx  = (int*)           alloc((size_t)Nh * 4);

  // ---- build grids (3 source + 1 query sort) + weight splits ----
  const int ncnt = M1 + M2 + M2 + M1;
  zero_kernel<<<(ncnt + 255) / 256, 256, 0, stream>>>(cnts, ncnt);
  cell_count4_kernel<<<160, 256, 0, stream>>>(
      h_pos2, Nh, G1, cnt1,  l_pos2, Nl, G2, cnt2,
      l_pos1, Nl, G2, cnt3,  h_pos1, Nh, G1, cnt4);
  prefix4_kernel<<<4, 256, 0, stream>>>(
      cnt1, offs1, cur1, M1,  cnt2, offs2, cur2, M2,
      cnt3, offs3, cur3, M2,  cnt4, offs4, cur4, M1);
  scatter4_kernel<<<160, 256, 0, stream>>>(
      h_pos2, Nh, G1, cur1, spts1, sidx1,
      l_pos2, Nl, G2, cur2, spts2, sidx2,
      l_pos1, Nl, G2, cur3, spts3, sidx3,
      h_pos1, Nh, G1, cur4, qspts, qsidx);
  split_wt2_kernel<<<512, 256, 0, stream>>>(
      W1, w1t_hi, w1t_lo, W2, w2t_hi, w2t_lo);

  // ---- all three KNN searches concurrently ----
  knn_triple_kernel<<<2304, 256, 0, stream>>>(
      qspts, qsidx, Nh, G1, offs1, spts1, sidx1, wA, idxA,
      spts3, sidx3, Nl, G2, offs2, spts2, sidx2, l_y1, l_y2, diff,
      offs3, wC, idxC);

  // ---- build_t || res-gather ----
  bt_gather_kernel<<<4160, 256, 0, stream>>>(
      emb1, emb2, wA, idxA, t_hi, t_lo, Nh,
      wC, idxC, diff, res, Nh);

  // ---- MLP ----
  mfma_gemm_kernel<<<(Nh / 64) * 4, 256, 0, stream>>>(
      t_hi, t_lo, w1t_hi, w1t_lo, b1, nullptr, h1_hi, h1_lo, 1, 1);
  mfma_gemm_kernel<<<(Nh / 64) * 4, 256, 0, stream>>>(
      h1_hi, h1_lo, w2t_hi, w2t_lo, b2, h2, nullptr, nullptr, 1, 0);

  // ---- final: out = (h2 @ W3 + b3) + res ----
  final_kernel<<<Nh / 4, 256, 0, stream>>>(h2, W3, b3, res, out, Nh);
}

// Round 16
// 127.777 us; speedup vs baseline: 1.7911x; 1.0396x over previous
//
#include <hip/hip_runtime.h>
#include <math.h>

#define BIGF 3.0e38f

typedef short  s16x8 __attribute__((ext_vector_type(8)));
typedef float  f32x4 __attribute__((ext_vector_type(4)));

// bf16 helpers (manual RNE)
__device__ __forceinline__ unsigned short f2bf(float x) {
  unsigned int b = __float_as_uint(x);
  unsigned int r = b + 0x7FFFu + ((b >> 16) & 1u);
  return (unsigned short)(r >> 16);
}
__device__ __forceinline__ float bf2f(unsigned short h) {
  return __uint_as_float(((unsigned int)h) << 16);
}

// ===========================================================================
// Spatial-hash KNN (K=3), 16 lanes per query, row-range shell scan,
// cell-sorted query order, 1-deep scan prefetch, dual-grid ILP fusion.
// Selection replicates the np reference's fp32 expansion distance:
//   sx  = (x*x + y*y) + z*z            (sequential, individually rounded)
//   dot = (p0 + p1) + p2, p_k = q_k*s_k
//   d2  = (sy + sx) - 2*dot
// under fp contract(off) — verified rounds 3-6. DO NOT TOUCH.
// Tie-break: lexicographic (d, idx). Every candidate visited EXACTLY once,
// in the same per-lane order as rounds 12-15 (prefetch only moves loads).
// ===========================================================================

__device__ __forceinline__ int cell_clamp(float v, int G) {
  int c = (int)(v * (float)G);
  return min(G - 1, max(0, c));
}

__device__ __forceinline__ void ins3(float d, int id,
                                     float& d0, float& d1, float& d2,
                                     int& i0, int& i1, int& i2) {
  bool l0 = (d < d0) || (d == d0 && id < i0);
  bool l1 = (d < d1) || (d == d1 && id < i1);
  bool l2 = (d < d2) || (d == d2 && id < i2);
  float nd0 = l0 ? d  : d0;  int ni0 = l0 ? id : i0;
  float nd1 = l0 ? d0 : (l1 ? d  : d1);
  int   ni1 = l0 ? i0 : (l1 ? id : i1);
  float nd2 = l1 ? d1 : (l2 ? d  : d2);
  int   ni2 = l1 ? i1 : (l2 ? id : i2);
  d0 = nd0; d1 = nd1; d2 = nd2; i0 = ni0; i1 = ni1; i2 = ni2;
}

// scan one Chebyshev shell R of grid G; per-lane local top-3 accumulate.
// 1-deep software pipeline: point j+1's load issues before point j's insert.
__device__ __forceinline__ void scan_shell(
    int R, int sl, int G, int cx, int cy, int cz,
    const int* __restrict__ offs, const float4* __restrict__ spts,
    const int* __restrict__ sidx,
    float qx, float qy, float qz, float sy,
    float& d0, float& d1, float& d2v, int& i0, int& i1, int& i2)
{
  #pragma clang fp contract(off)
  #define SCANP()                                                             \
    { int j = js;                                                             \
      if (j < je) {                                                           \
        float4 sc = spts[j]; int idc = sidx[j];                               \
        for (++j; ; ++j) {                                                    \
          bool more = (j < je);                                               \
          float4 sn; int idn;                                                 \
          if (more) { sn = spts[j]; idn = sidx[j]; }                          \
          float p0 = qx * sc.x, p1 = qy * sc.y, p2 = qz * sc.z;               \
          float dt = (p0 + p1) + p2;                                          \
          float S  = sy + sc.w;                                               \
          float dd = S - 2.0f * dt;                                           \
          ins3(dd, idc, d0, d1, d2v, i0, i1, i2);                             \
          if (!more) break;                                                   \
          sc = sn; idc = idn;                                                 \
        }                                                                     \
      } }

  if (R == 1) {
    if (sl < 9) {
      int dy = sl % 3 - 1, dz = sl / 3 - 1;
      int yy = cy + dy, zz = cz + dz;
      if (yy >= 0 && yy < G && zz >= 0 && zz < G) {
        int xs = max(cx - 1, 0), xe = min(cx + 1, G - 1);
        int base = (zz * G + yy) * G;
        int js = offs[base + xs], je = offs[base + xe + 1];
        SCANP()
      }
    }
  } else {
    const int twoR1 = 2 * R + 1, inner = 2 * R - 1;
    const int nfz = 2 * twoR1;
    const int nfull = nfz + 2 * inner;
    const int half = inner * inner;
    const int nitems = nfull + 2 * half;
    for (int m = sl; m < nitems; m += 16) {
      int dy, dz, js, je;
      if (m < nfull) {
        if (m < nfz) { dz = (m < twoR1) ? -R : R; dy = (m % twoR1) - R; }
        else { int u = m - nfz; dy = (u < inner) ? -R : R; dz = (u % inner) - (R - 1); }
        int yy = cy + dy, zz = cz + dz;
        if (yy < 0 || yy >= G || zz < 0 || zz >= G) continue;
        int xs = max(cx - R, 0), xe = min(cx + R, G - 1);
        int base = (zz * G + yy) * G;
        js = offs[base + xs]; je = offs[base + xe + 1];
      } else {
        int u = m - nfull;
        int xc = (u < half) ? (cx - R) : (cx + R);
        int r2 = (u < half) ? u : u - half;
        dy = r2 % inner - (R - 1); dz = r2 / inner - (R - 1);
        int yy = cy + dy, zz = cz + dz;
        if (xc < 0 || xc >= G || yy < 0 || yy >= G || zz < 0 || zz >= G) continue;
        int c = (zz * G + yy) * G + xc;
        js = offs[c]; je = offs[c + 1];
      }
      SCANP()
    }
  }
  #undef SCANP
}

#define MERGE16(E0, E1, E2, J0, J1, J2)                                       \
  { _Pragma("unroll")                                                         \
    for (int msk = 1; msk < 16; msk <<= 1) {                                  \
      float o0 = __shfl_xor(E0, msk), o1 = __shfl_xor(E1, msk), o2 = __shfl_xor(E2, msk); \
      int   p0 = __shfl_xor(J0, msk), p1 = __shfl_xor(J1, msk), p2 = __shfl_xor(J2, msk); \
      ins3(o0, p0, E0, E1, E2, J0, J1, J2);                                   \
      ins3(o1, p1, E0, E1, E2, J0, J1, J2);                                   \
      ins3(o2, p2, E0, E1, E2, J0, J1, J2);                                   \
    } }

// ---- dual-grid KNN: one query, two independent searches (ILP-fused) -------
// writes (wA,iA) for grid A and (wB,iB) for grid B, both at qorig.
__device__ void knn_dualgrid_body(
    int bid,
    const float4* __restrict__ qspts, const int* __restrict__ qsidx, int Nq,
    int GA, const int* __restrict__ offsA, const float4* __restrict__ sptsA, const int* __restrict__ sidxA,
    float* __restrict__ wA_out, int* __restrict__ iA_out,
    int GB, const int* __restrict__ offsB, const float4* __restrict__ sptsB, const int* __restrict__ sidxB,
    float* __restrict__ wB_out, int* __restrict__ iB_out)
{
  #pragma clang fp contract(off)
  const int sl = threadIdx.x & 15;
  const int qs = bid * 16 + (threadIdx.x >> 4);
  if (qs >= Nq) return;

  float4 qv = qspts[qs];
  const float qx = qv.x, qy = qv.y, qz = qv.z;
  const float sy = qv.w;
  const int qorig = qsidx[qs];
  const float csA = 1.0f / (float)GA, csB = 1.0f / (float)GB;
  const int cxA = cell_clamp(qx, GA), cyA = cell_clamp(qy, GA), czA = cell_clamp(qz, GA);
  const int cxB = cell_clamp(qx, GB), cyB = cell_clamp(qy, GB), czB = cell_clamp(qz, GB);

  float a0 = BIGF, a1 = BIGF, a2 = BIGF;  int ia0 = -1, ia1 = -1, ia2 = -1;
  float b0 = BIGF, b1 = BIGF, b2 = BIGF;  int ib0 = -1, ib1 = -1, ib2 = -1;
  float eA0 = BIGF, eA1 = BIGF, eA2 = BIGF; int jA0 = -1, jA1 = -1, jA2 = -1;
  float eB0 = BIGF, eB1 = BIGF, eB2 = BIGF; int jB0 = -1, jB1 = -1, jB2 = -1;
  bool doneA = false, doneB = false;

  const int Gmax = max(GA, GB);
  for (int R = 1; R <= Gmax; ++R) {
    // both scans issue in the same iteration: independent chains interleave
    if (!doneA && R <= GA)
      scan_shell(R, sl, GA, cxA, cyA, czA, offsA, sptsA, sidxA,
                 qx, qy, qz, sy, a0, a1, a2, ia0, ia1, ia2);
    if (!doneB && R <= GB)
      scan_shell(R, sl, GB, cxB, cyB, czB, offsB, sptsB, sidxB,
                 qx, qy, qz, sy, b0, b1, b2, ib0, ib1, ib2);
    if (!doneA && R <= GA) {
      eA0 = a0; eA1 = a1; eA2 = a2; jA0 = ia0; jA1 = ia1; jA2 = ia2;
      MERGE16(eA0, eA1, eA2, jA0, jA1, jA2)
      float bnd = (float)R * csA;
      doneA = (eA2 <= bnd * bnd - 1e-6f) || (R >= GA);
    }
    if (!doneB && R <= GB) {
      eB0 = b0; eB1 = b1; eB2 = b2; jB0 = ib0; jB1 = ib1; jB2 = ib2;
      MERGE16(eB0, eB1, eB2, jB0, jB1, jB2)
      float bnd = (float)R * csB;
      doneB = (eB2 <= bnd * bnd - 1e-6f) || (R >= GB);
    }
    if (__all(doneA && doneB)) break;
  }

  if (sl == 0) {
    {
      float w0 = 1.0f / fmaxf(eA0, 1e-16f);
      float w1 = 1.0f / fmaxf(eA1, 1e-16f);
      float w2 = 1.0f / fmaxf(eA2, 1e-16f);
      float inv = 1.0f / (w0 + w1 + w2);
      wA_out[(size_t)qorig * 3 + 0] = w0 * inv;
      wA_out[(size_t)qorig * 3 + 1] = w1 * inv;
      wA_out[(size_t)qorig * 3 + 2] = w2 * inv;
      iA_out[(size_t)qorig * 3 + 0] = jA0;
      iA_out[(size_t)qorig * 3 + 1] = jA1;
      iA_out[(size_t)qorig * 3 + 2] = jA2;
    }
    {
      float w0 = 1.0f / fmaxf(eB0, 1e-16f);
      float w1 = 1.0f / fmaxf(eB1, 1e-16f);
      float w2 = 1.0f / fmaxf(eB2, 1e-16f);
      float inv = 1.0f / (w0 + w1 + w2);
      wB_out[(size_t)qorig * 3 + 0] = w0 * inv;
      wB_out[(size_t)qorig * 3 + 1] = w1 * inv;
      wB_out[(size_t)qorig * 3 + 2] = w2 * inv;
      iB_out[(size_t)qorig * 3 + 0] = jB0;
      iB_out[(size_t)qorig * 3 + 1] = jB1;
      iB_out[(size_t)qorig * 3 + 2] = jB2;
    }
  }
}

// ---- single-grid KNN body (knn1: mode1 -> out3 = base3 - interp) ----------
__device__ void knn_single_body(
    int bid,
    const float4* __restrict__ qspts, const int* __restrict__ qsidx, int Nq, int G,
    const int* __restrict__ offs, const float4* __restrict__ spts, const int* __restrict__ sidx,
    const float* __restrict__ base3, const float* __restrict__ feat3,
    float* __restrict__ out3)
{
  #pragma clang fp contract(off)
  const int sl = threadIdx.x & 15;
  const int qs = bid * 16 + (threadIdx.x >> 4);
  if (qs >= Nq) return;

  float4 qv = qspts[qs];
  const float qx = qv.x, qy = qv.y, qz = qv.z;
  const float sy = qv.w;
  const int qorig = qsidx[qs];
  const float cs = 1.0f / (float)G;
  const int cx = cell_clamp(qx, G), cy = cell_clamp(qy, G), cz = cell_clamp(qz, G);

  float d0 = BIGF, d1 = BIGF, d2v = BIGF;
  int i0 = -1, i1 = -1, i2 = -1;
  float e0 = BIGF, e1 = BIGF, e2 = BIGF;
  int j0 = -1, j1 = -1, j2 = -1;
  bool done = false;

  for (int R = 1; R <= G; ++R) {
    if (!done) {
      scan_shell(R, sl, G, cx, cy, cz, offs, spts, sidx,
                 qx, qy, qz, sy, d0, d1, d2v, i0, i1, i2);
      e0 = d0; e1 = d1; e2 = d2v; j0 = i0; j1 = i1; j2 = i2;
      MERGE16(e0, e1, e2, j0, j1, j2)
      float bnd = (float)R * cs;
      done = (e2 <= bnd * bnd - 1e-6f) || (R >= G);
    }
    if (__all(done)) break;
  }

  if (sl == 0) {
    float w0 = 1.0f / fmaxf(e0, 1e-16f);
    float w1 = 1.0f / fmaxf(e1, 1e-16f);
    float w2 = 1.0f / fmaxf(e2, 1e-16f);
    float inv = 1.0f / (w0 + w1 + w2);
    w0 *= inv; w1 *= inv; w2 *= inv;
    #pragma unroll
    for (int f = 0; f < 3; ++f) {
      float v = w0 * feat3[(size_t)j0 * 3 + f]
              + w1 * feat3[(size_t)j1 * 3 + f]
              + w2 * feat3[(size_t)j2 * 3 + f];
      out3[(size_t)qorig * 3 + f] = base3[(size_t)qorig * 3 + f] - v;
    }
  }
}

// t = emb1 - interp(emb2), emitted as bf16 hi/lo splits (device body)
__device__ void build_t_body(
    int bid, const float* __restrict__ emb1, const float* __restrict__ emb2,
    const float* __restrict__ w, const int* __restrict__ idx,
    unsigned short* __restrict__ t_hi, unsigned short* __restrict__ t_lo, int Nq)
{
  int gid = bid * 256 + threadIdx.x;
  int q = gid >> 6, c4 = gid & 63;
  if (q >= Nq) return;
  float w0 = w[(size_t)q * 3 + 0], w1 = w[(size_t)q * 3 + 1], w2 = w[(size_t)q * 3 + 2];
  int i0 = idx[(size_t)q * 3 + 0], i1 = idx[(size_t)q * 3 + 1], i2 = idx[(size_t)q * 3 + 2];
  const float4* e1 = (const float4*)emb1;
  const float4* e2 = (const float4*)emb2;
  float4 a  = e1[(size_t)q * 64 + c4];
  float4 f0 = e2[(size_t)i0 * 64 + c4];
  float4 f1 = e2[(size_t)i1 * 64 + c4];
  float4 f2 = e2[(size_t)i2 * 64 + c4];
  float4 r;
  r.x = a.x - (w0 * f0.x + w1 * f1.x + w2 * f2.x);
  r.y = a.y - (w0 * f0.y + w1 * f1.y + w2 * f2.y);
  r.z = a.z - (w0 * f0.z + w1 * f1.z + w2 * f2.z);
  r.w = a.w - (w0 * f0.w + w1 * f1.w + w2 * f2.w);
  ushort4 h, l;
  h.x = f2bf(r.x); l.x = f2bf(r.x - bf2f(h.x));
  h.y = f2bf(r.y); l.y = f2bf(r.y - bf2f(h.y));
  h.z = f2bf(r.z); l.z = f2bf(r.z - bf2f(h.z));
  h.w = f2bf(r.w); l.w = f2bf(r.w - bf2f(h.w));
  size_t o = (size_t)q * 256 + c4 * 4;
  *(ushort4*)&t_hi[o] = h;
  *(ushort4*)&t_lo[o] = l;
}

// res[q,:] = sum_k wC[q,k] * diff[idxC[q,k],:]
__device__ void res_gather_body(
    int bid, const float* __restrict__ wC, const int* __restrict__ idxC,
    const float* __restrict__ diff, float* __restrict__ res, int Nq)
{
  int q = bid * 256 + threadIdx.x;
  if (q >= Nq) return;
  float w0 = wC[(size_t)q * 3 + 0], w1 = wC[(size_t)q * 3 + 1], w2 = wC[(size_t)q * 3 + 2];
  int i0 = idxC[(size_t)q * 3 + 0], i1 = idxC[(size_t)q * 3 + 1], i2 = idxC[(size_t)q * 3 + 2];
  #pragma unroll
  for (int f = 0; f < 3; ++f) {
    res[(size_t)q * 3 + f] = w0 * diff[(size_t)i0 * 3 + f]
                           + w1 * diff[(size_t)i1 * 3 + f]
                           + w2 * diff[(size_t)i2 * 3 + f];
  }
}

// ---- fused KNN dispatch: dual-grid (knn0+knn2) || knn1 ---------------------
// 1280 blocks = 256 groups x {4 dual, 1 knn1}
__global__ __launch_bounds__(256) void knn_fused_kernel(
    const float4* qspts, const int* qsidx, int Nh,
    int G1, const int* offs1, const float4* spts1, const int* sidx1, float* wA, int* idxA,
    int G2, const int* offs3, const float4* spts3, const int* sidx3, float* wC, int* idxC,
    int Nl, const int* offs2, const float4* spts2, const int* sidx2,
    const float* l_y1, const float* l_y2, float* diff)
{
  int g = blockIdx.x / 5, r = blockIdx.x % 5;
  if (r < 4)
    knn_dualgrid_body(g * 4 + r, qspts, qsidx, Nh,
                      G1, offs1, spts1, sidx1, wA, idxA,
                      G2, offs3, spts3, sidx3, wC, idxC);
  else
    knn_single_body(g, spts3, sidx3, Nl, G2, offs2, spts2, sidx2,
                    l_y1, l_y2, diff);
}

// ---- bt_gather: res-gather (blocks 0..63) || build_t (blocks 64..4159) ----
__global__ __launch_bounds__(256) void bt_gather_kernel(
    const float* emb1, const float* emb2, const float* w, const int* idx,
    unsigned short* t_hi, unsigned short* t_lo, int Nq_bt,
    const float* wC, const int* idxC, const float* diff, float* res, int NqG)
{
  if (blockIdx.x < 64)
    res_gather_body(blockIdx.x, wC, idxC, diff, res, NqG);
  else
    build_t_body(blockIdx.x - 64, emb1, emb2, w, idx, t_hi, t_lo, Nq_bt);
}

// ---- grid build ------------------------------------------------------------
__global__ __launch_bounds__(256) void zero_kernel(int* __restrict__ p, int n) {
  int i = blockIdx.x * 256 + threadIdx.x;
  if (i < n) p[i] = 0;
}

// count (blocks 0..159) + weight splits (blocks 160..671)
__global__ __launch_bounds__(256) void count_split_kernel(
    const float* __restrict__ p1, int n1, int g1, int* __restrict__ c1,
    const float* __restrict__ p2, int n2, int g2, int* __restrict__ c2,
    const float* __restrict__ p3, int n3, int g3, int* __restrict__ c3,
    const float* __restrict__ p4, int n4, int g4, int* __restrict__ c4,
    const float* __restrict__ W1, unsigned short* __restrict__ h1T, unsigned short* __restrict__ l1T,
    const float* __restrict__ W2, unsigned short* __restrict__ h2T, unsigned short* __restrict__ l2T)
{
  int b = blockIdx.x;
  if (b >= 160) {
    int sb = b - 160;
    const float* W = (sb < 256) ? W1 : W2;
    unsigned short* hiT = (sb < 256) ? h1T : h2T;
    unsigned short* loT = (sb < 256) ? l1T : l2T;
    int id = (sb & 255) * 256 + threadIdx.x;
    int k = id >> 8, n = id & 255;
    float x = W[id];
    unsigned short h = f2bf(x);
    unsigned short l = f2bf(x - bf2f(h));
    hiT[n * 256 + k] = h;
    loT[n * 256 + k] = l;
    return;
  }
  const float* p; int n, G; int* cnt; int i;
  if (b < 64)       { p = p1; n = n1; G = g1; cnt = c1; i = b * 256 + threadIdx.x; }
  else if (b < 80)  { p = p2; n = n2; G = g2; cnt = c2; i = (b - 64) * 256 + threadIdx.x; }
  else if (b < 96)  { p = p3; n = n3; G = g3; cnt = c3; i = (b - 80) * 256 + threadIdx.x; }
  else              { p = p4; n = n4; G = g4; cnt = c4; i = (b - 96) * 256 + threadIdx.x; }
  if (i >= n) return;
  int cx = cell_clamp(p[3 * i],     G);
  int cy = cell_clamp(p[3 * i + 1], G);
  int cz = cell_clamp(p[3 * i + 2], G);
  atomicAdd(&cnt[(cz * G + cy) * G + cx], 1);
}

__global__ __launch_bounds__(256) void prefix4_kernel(
    const int* __restrict__ c1, int* __restrict__ o1, int* __restrict__ u1, int m1,
    const int* __restrict__ c2, int* __restrict__ o2, int* __restrict__ u2, int m2,
    const int* __restrict__ c3, int* __restrict__ o3, int* __restrict__ u3, int m3,
    const int* __restrict__ c4, int* __restrict__ o4, int* __restrict__ u4, int m4)
{
  const int* cnt; int* offs; int* cur; int M;
  if (blockIdx.x == 0)      { cnt = c1; offs = o1; cur = u1; M = m1; }
  else if (blockIdx.x == 1) { cnt = c2; offs = o2; cur = u2; M = m2; }
  else if (blockIdx.x == 2) { cnt = c3; offs = o3; cur = u3; M = m3; }
  else                      { cnt = c4; offs = o4; cur = u4; M = m4; }
  __shared__ int ps[256];
  const int tid = threadIdx.x;
  const int per = (M + 255) >> 8;
  const int base = tid * per;
  int s = 0;
  for (int j = 0; j < per; ++j) if (base + j < M) s += cnt[base + j];
  ps[tid] = s;
  __syncthreads();
  for (int off = 1; off < 256; off <<= 1) {
    int v = (tid >= off) ? ps[tid - off] : 0;
    __syncthreads();
    ps[tid] += v;
    __syncthreads();
  }
  int run = (tid > 0) ? ps[tid - 1] : 0;
  for (int j = 0; j < per; ++j) {
    if (base + j < M) {
      offs[base + j] = run; cur[base + j] = run;
      run += cnt[base + j];
    }
  }
  if (tid == 255) offs[M] = run;
}

__global__ __launch_bounds__(256) void scatter4_kernel(
    const float* __restrict__ p1, int n1, int g1, int* __restrict__ u1, float4* __restrict__ s1, int* __restrict__ x1,
    const float* __restrict__ p2, int n2, int g2, int* __restrict__ u2, float4* __restrict__ s2, int* __restrict__ x2,
    const float* __restrict__ p3, int n3, int g3, int* __restrict__ u3, float4* __restrict__ s3, int* __restrict__ x3,
    const float* __restrict__ p4, int n4, int g4, int* __restrict__ u4, float4* __restrict__ s4, int* __restrict__ x4)
{
  #pragma clang fp contract(off)
  int b = blockIdx.x;
  const float* p; int n, G; int* cur; float4* spts; int* sidx; int i;
  if (b < 64)       { p = p1; n = n1; G = g1; cur = u1; spts = s1; sidx = x1; i = b * 256 + threadIdx.x; }
  else if (b < 80)  { p = p2; n = n2; G = g2; cur = u2; spts = s2; sidx = x2; i = (b - 64) * 256 + threadIdx.x; }
  else if (b < 96)  { p = p3; n = n3; G = g3; cur = u3; spts = s3; sidx = x3; i = (b - 80) * 256 + threadIdx.x; }
  else              { p = p4; n = n4; G = g4; cur = u4; spts = s4; sidx = x4; i = (b - 96) * 256 + threadIdx.x; }
  if (i >= n) return;
  float x = p[3 * i], y = p[3 * i + 1], z = p[3 * i + 2];
  int cx = cell_clamp(x, G), cy = cell_clamp(y, G), cz = cell_clamp(z, G);
  int c = (cz * G + cy) * G + cx;
  int pos = atomicAdd(&cur[c], 1);
  float sx = (x * x + y * y) + z * z;   // sequential, no contraction
  spts[pos] = make_float4(x, y, z, sx);
  sidx[pos] = i;
}

// ---------------------------------------------------------------------------
// bf16x3-split MFMA GEMM (verified round 12 — absmax 0.0625)
// ---------------------------------------------------------------------------
__global__ __launch_bounds__(256) void mfma_gemm_kernel(
    const unsigned short* __restrict__ A_hi, const unsigned short* __restrict__ A_lo,
    const unsigned short* __restrict__ BT_hi, const unsigned short* __restrict__ BT_lo,
    const float* __restrict__ bias,
    float* __restrict__ outf,
    unsigned short* __restrict__ out_hi, unsigned short* __restrict__ out_lo,
    int relu, int split_out)
{
  __shared__ unsigned short Bs_hi[64][132];
  __shared__ unsigned short Bs_lo[64][132];
  const int t = threadIdx.x;
  const int d = blockIdx.x;
  const int xcd = d & 7, slot = d >> 3;
  const int lin = xcd * ((int)gridDim.x >> 3) + slot;
  const int row0 = (lin >> 2) * 64;
  const int col0 = (lin & 3) * 64;

  const int l = t & 63, w = t >> 6;
  const int lr = l & 15;
  const int lk = (l >> 4) << 3;
  const unsigned short* arh = A_hi + (size_t)(row0 + w * 16 + lr) * 256;
  const unsigned short* arl = A_lo + (size_t)(row0 + w * 16 + lr) * 256;

  const int sc = t >> 2;
  const int sk = (t & 3) << 5;

  f32x4 acc0 = {0.f,0.f,0.f,0.f}, acc1 = {0.f,0.f,0.f,0.f};
  f32x4 acc2 = {0.f,0.f,0.f,0.f}, acc3 = {0.f,0.f,0.f,0.f};

  #define KSTEP(CT, ACC)                                                      \
    { s16x8 bh = *(const s16x8*)&Bs_hi[CT * 16 + lr][kc + lk];                \
      s16x8 bl = *(const s16x8*)&Bs_lo[CT * 16 + lr][kc + lk];                \
      ACC = __builtin_amdgcn_mfma_f32_16x16x32_bf16(ah, bh, ACC, 0, 0, 0);    \
      ACC = __builtin_amdgcn_mfma_f32_16x16x32_bf16(al, bh, ACC, 0, 0, 0);    \
      ACC = __builtin_amdgcn_mfma_f32_16x16x32_bf16(ah, bl, ACC, 0, 0, 0); }

  for (int half = 0; half < 2; ++half) {
    if (half) __syncthreads();
    {
      const int4* sh = (const int4*)&BT_hi[(size_t)(col0 + sc) * 256 + half * 128 + sk];
      const int4* slo = (const int4*)&BT_lo[(size_t)(col0 + sc) * 256 + half * 128 + sk];
      int4* dh = (int4*)&Bs_hi[sc][sk];
      int4* dl = (int4*)&Bs_lo[sc][sk];
      #pragma unroll
      for (int i = 0; i < 4; ++i) { dh[i] = sh[i]; dl[i] = slo[i]; }
    }
    __syncthreads();
    const int kbase = half * 128;
    #pragma unroll
    for (int kc = 0; kc < 128; kc += 32) {
      s16x8 ah = *(const s16x8*)&arh[kbase + kc + lk];
      s16x8 al = *(const s16x8*)&arl[kbase + kc + lk];
      KSTEP(0, acc0)
      KSTEP(1, acc1)
      KSTEP(2, acc2)
      KSTEP(3, acc3)
    }
  }
  #undef KSTEP

  const int orow = row0 + w * 16 + ((l >> 4) << 2);
  #define EPILOG(CT, ACC)                                                     \
    { int col = col0 + CT * 16 + lr;                                          \
      float bb = bias[col];                                                   \
      _Pragma("unroll")                                                       \
      for (int r = 0; r < 4; ++r) {                                           \
        float v = ACC[r] + bb;                                                \
        if (relu) v = fmaxf(v, 0.0f);                                         \
        size_t o = (size_t)(orow + r) * 256 + col;                            \
        if (split_out) {                                                      \
          unsigned short hh = f2bf(v);                                        \
          out_hi[o] = hh; out_lo[o] = f2bf(v - bf2f(hh));                     \
        } else {                                                              \
          outf[o] = v;                                                        \
        }                                                                     \
      } }
  EPILOG(0, acc0)
  EPILOG(1, acc1)
  EPILOG(2, acc2)
  EPILOG(3, acc3)
  #undef EPILOG
}

// ---------------------------------------------------------------------------
// out[r, :] = h2[r, :] @ W3[256,3] + b3 + res[r, :]   (wave per row)
// ---------------------------------------------------------------------------
__global__ __launch_bounds__(256) void final_kernel(
    const float* __restrict__ h2, const float* __restrict__ W3,
    const float* __restrict__ b3, const float* __restrict__ res,
    float* __restrict__ out, int M)
{
  __shared__ float sW3[768];
  const int tid = threadIdx.x;
  for (int i = tid; i < 768; i += 256) sW3[i] = W3[i];
  __syncthreads();

  const int wave = tid >> 6, lane = tid & 63;
  const int r = blockIdx.x * 4 + wave;
  if (r >= M) return;

  float4 h = ((const float4*)h2)[(size_t)r * 64 + lane];
  const int c = lane * 4;
  float a0 = h.x * sW3[(c + 0) * 3 + 0] + h.y * sW3[(c + 1) * 3 + 0]
           + h.z * sW3[(c + 2) * 3 + 0] + h.w * sW3[(c + 3) * 3 + 0];
  float a1 = h.x * sW3[(c + 0) * 3 + 1] + h.y * sW3[(c + 1) * 3 + 1]
           + h.z * sW3[(c + 2) * 3 + 1] + h.w * sW3[(c + 3) * 3 + 1];
  float a2 = h.x * sW3[(c + 0) * 3 + 2] + h.y * sW3[(c + 1) * 3 + 2]
           + h.z * sW3[(c + 2) * 3 + 2] + h.w * sW3[(c + 3) * 3 + 2];

  #pragma unroll
  for (int off = 32; off; off >>= 1) {
    a0 += __shfl_xor(a0, off);
    a1 += __shfl_xor(a1, off);
    a2 += __shfl_xor(a2, off);
  }
  if (lane == 0) {
    out[(size_t)r * 3 + 0] = a0 + b3[0] + res[(size_t)r * 3 + 0];
    out[(size_t)r * 3 + 1] = a1 + b3[1] + res[(size_t)r * 3 + 1];
    out[(size_t)r * 3 + 2] = a2 + b3[2] + res[(size_t)r * 3 + 2];
  }
}

// ---------------------------------------------------------------------------
extern "C" void kernel_launch(void* const* d_in, const int* in_sizes, int n_in,
                              void* d_out, int out_size, void* d_ws, size_t ws_size,
                              hipStream_t stream) {
  (void)in_sizes; (void)n_in; (void)out_size; (void)ws_size;
  const float* emb1   = (const float*)d_in[0];
  const float* l_y1   = (const float*)d_in[1];
  const float* l_pos1 = (const float*)d_in[2];
  const float* h_pos1 = (const float*)d_in[3];
  const float* emb2   = (const float*)d_in[4];
  const float* l_y2   = (const float*)d_in[5];
  const float* l_pos2 = (const float*)d_in[6];
  const float* h_pos2 = (const float*)d_in[7];
  const float* W1     = (const float*)d_in[8];
  const float* b1     = (const float*)d_in[9];
  const float* W2     = (const float*)d_in[10];
  const float* b2     = (const float*)d_in[11];
  const float* W3     = (const float*)d_in[12];
  const float* b3     = (const float*)d_in[13];
  float* out = (float*)d_out;

  const int Nh = 16384, Nl = 4096, H = 256;
  const int G1 = 16, G2 = 10;
  const int M1 = G1 * G1 * G1, M2 = G2 * G2 * G2;

  // ---- workspace carve-up (sequential bump allocator, 256B aligned) ----
  char* wsp = (char*)d_ws;
  size_t off = 0;
  auto alloc = [&](size_t bytes) -> void* {
    void* p = wsp + off;
    off += (bytes + 255) & ~(size_t)255;
    return p;
  };
  int*            idxA   = (int*)           alloc((size_t)Nh * 3 * 4);
  float*          wA     = (float*)         alloc((size_t)Nh * 3 * 4);
  int*            idxC   = (int*)           alloc((size_t)Nh * 3 * 4);
  float*          wC     = (float*)         alloc((size_t)Nh * 3 * 4);
  unsigned short* t_hi   = (unsigned short*)alloc((size_t)Nh * H * 2);
  unsigned short* t_lo   = (unsigned short*)alloc((size_t)Nh * H * 2);
  unsigned short* h1_hi  = (unsigned short*)alloc((size_t)Nh * H * 2);
  unsigned short* h1_lo  = (unsigned short*)alloc((size_t)Nh * H * 2);
  float*          h2     = (float*)t_hi;    // alias over t_hi+t_lo (t dead)
  unsigned short* w1t_hi = (unsigned short*)alloc((size_t)H * H * 2);
  unsigned short* w1t_lo = (unsigned short*)alloc((size_t)H * H * 2);
  unsigned short* w2t_hi = (unsigned short*)alloc((size_t)H * H * 2);
  unsigned short* w2t_lo = (unsigned short*)alloc((size_t)H * H * 2);
  float*          diff   = (float*)         alloc((size_t)Nl * 3 * 4);
  float*          res    = (float*)         alloc((size_t)Nh * 3 * 4);
  int*            cnts   = (int*)           alloc((size_t)(M1 + M2 + M2 + M1) * 4);
  int* cnt1 = cnts, *cnt2 = cnts + M1, *cnt3 = cnts + M1 + M2, *cnt4 = cnts + M1 + 2 * M2;
  int*            offs1  = (int*)           alloc((size_t)(M1 + 1) * 4);
  int*            cur1   = (int*)           alloc((size_t)M1 * 4);
  int*            offs2  = (int*)           alloc((size_t)(M2 + 1) * 4);
  int*            cur2   = (int*)           alloc((size_t)M2 * 4);
  int*            offs3  = (int*)           alloc((size_t)(M2 + 1) * 4);
  int*            cur3   = (int*)           alloc((size_t)M2 * 4);
  int*            offs4  = (int*)           alloc((size_t)(M1 + 1) * 4);
  int*            cur4   = (int*)           alloc((size_t)M1 * 4);
  float4*         spts1  = (float4*)        alloc((size_t)Nh * 16);
  int*            sidx1  = (int*)           alloc((size_t)Nh * 4);
  float4*         spts2  = (float4*)        alloc((size_t)Nl * 16);
  int*            sidx2  = (int*)           alloc((size_t)Nl * 4);
  float4*         spts3  = (float4*)        alloc((size_t)Nl * 16);
  int*            sidx3  = (int*)           alloc((size_t)Nl * 4);
  float4*         qspts  = (float4*)        alloc((size_t)Nh * 16);   // sorted h_pos1
  int*            qsidx  = (int*)           alloc((size_t)Nh * 4);

  // ---- build grids (3 source + 1 query sort) + weight splits ----
  const int ncnt = M1 + M2 + M2 + M1;
  zero_kernel<<<(ncnt + 255) / 256, 256, 0, stream>>>(cnts, ncnt);
  count_split_kernel<<<672, 256, 0, stream>>>(
      h_pos2, Nh, G1, cnt1,  l_pos2, Nl, G2, cnt2,
      l_pos1, Nl, G2, cnt3,  h_pos1, Nh, G1, cnt4,
      W1, w1t_hi, w1t_lo, W2, w2t_hi, w2t_lo);
  prefix4_kernel<<<4, 256, 0, stream>>>(
      cnt1, offs1, cur1, M1,  cnt2, offs2, cur2, M2,
      cnt3, offs3, cur3, M2,  cnt4, offs4, cur4, M1);
  scatter4_kernel<<<160, 256, 0, stream>>>(
      h_pos2, Nh, G1, cur1, spts1, sidx1,
      l_pos2, Nl, G2, cur2, spts2, sidx2,
      l_pos1, Nl, G2, cur3, spts3, sidx3,
      h_pos1, Nh, G1, cur4, qspts, qsidx);

  // ---- all KNN searches in one dispatch (dual-grid ILP for knn0+knn2) ----
  knn_fused_kernel<<<1280, 256, 0, stream>>>(
      qspts, qsidx, Nh,
      G1, offs1, spts1, sidx1, wA, idxA,
      G2, offs3, spts3, sidx3, wC, idxC,
      Nl, offs2, spts2, sidx2, l_y1, l_y2, diff);

  // ---- build_t || res-gather ----
  bt_gather_kernel<<<4160, 256, 0, stream>>>(
      emb1, emb2, wA, idxA, t_hi, t_lo, Nh,
      wC, idxC, diff, res, Nh);

  // ---- MLP ----
  mfma_gemm_kernel<<<(Nh / 64) * 4, 256, 0, stream>>>(
      t_hi, t_lo, w1t_hi, w1t_lo, b1, nullptr, h1_hi, h1_lo, 1, 1);
  mfma_gemm_kernel<<<(Nh / 64) * 4, 256, 0, stream>>>(
      h1_hi, h1_lo, w2t_hi, w2t_lo, b2, h2, nullptr, nullptr, 1, 0);

  // ---- final: out = (h2 @ W3 + b3) + res ----
  final_kernel<<<Nh / 4, 256, 0, stream>>>(h2, W3, b3, res, out, Nh);
}

// Round 17
// 119.512 us; speedup vs baseline: 1.9150x; 1.0692x over previous
//
#include <hip/hip_runtime.h>
#include <math.h>

#define BIGF 3.0e38f

typedef short  s16x8 __attribute__((ext_vector_type(8)));
typedef float  f32x4 __attribute__((ext_vector_type(4)));

// bf16 helpers (manual RNE)
__device__ __forceinline__ unsigned short f2bf(float x) {
  unsigned int b = __float_as_uint(x);
  unsigned int r = b + 0x7FFFu + ((b >> 16) & 1u);
  return (unsigned short)(r >> 16);
}
__device__ __forceinline__ float bf2f(unsigned short h) {
  return __uint_as_float(((unsigned int)h) << 16);
}

// ===========================================================================
// Spatial-hash KNN (K=3), 16 lanes per query, row-range shell scan,
// cell-sorted query order, 1-deep scan prefetch.
// Selection replicates the np reference's fp32 expansion distance:
//   sx  = (x*x + y*y) + z*z            (sequential, individually rounded)
//   dot = (p0 + p1) + p2, p_k = q_k*s_k
//   d2  = (sy + sx) - 2*dot
// under fp contract(off) (scan_shell-local pragma) — verified rounds 3-6.
// DO NOT TOUCH. Tie-break: lexicographic (d, idx); every candidate visited
// exactly once. build_t is inlined post-merge (all 16 lanes hold the merged
// result after the butterfly) with DEFAULT contract — same as rounds 12-16.
// ===========================================================================

__device__ __forceinline__ int cell_clamp(float v, int G) {
  int c = (int)(v * (float)G);
  return min(G - 1, max(0, c));
}

__device__ __forceinline__ void ins3(float d, int id,
                                     float& d0, float& d1, float& d2,
                                     int& i0, int& i1, int& i2) {
  bool l0 = (d < d0) || (d == d0 && id < i0);
  bool l1 = (d < d1) || (d == d1 && id < i1);
  bool l2 = (d < d2) || (d == d2 && id < i2);
  float nd0 = l0 ? d  : d0;  int ni0 = l0 ? id : i0;
  float nd1 = l0 ? d0 : (l1 ? d  : d1);
  int   ni1 = l0 ? i0 : (l1 ? id : i1);
  float nd2 = l1 ? d1 : (l2 ? d  : d2);
  int   ni2 = l1 ? i1 : (l2 ? id : i2);
  d0 = nd0; d1 = nd1; d2 = nd2; i0 = ni0; i1 = ni1; i2 = ni2;
}

// scan one Chebyshev shell R of grid G; per-lane local top-3 accumulate.
__device__ __forceinline__ void scan_shell(
    int R, int sl, int G, int cx, int cy, int cz,
    const int* __restrict__ offs, const float4* __restrict__ spts,
    const int* __restrict__ sidx,
    float qx, float qy, float qz, float sy,
    float& d0, float& d1, float& d2v, int& i0, int& i1, int& i2)
{
  #pragma clang fp contract(off)
  #define SCANP()                                                             \
    { int j = js;                                                             \
      if (j < je) {                                                           \
        float4 sc = spts[j]; int idc = sidx[j];                               \
        for (++j; ; ++j) {                                                    \
          bool more = (j < je);                                               \
          float4 sn; int idn;                                                 \
          if (more) { sn = spts[j]; idn = sidx[j]; }                          \
          float p0 = qx * sc.x, p1 = qy * sc.y, p2 = qz * sc.z;               \
          float dt = (p0 + p1) + p2;                                          \
          float S  = sy + sc.w;                                               \
          float dd = S - 2.0f * dt;                                           \
          ins3(dd, idc, d0, d1, d2v, i0, i1, i2);                             \
          if (!more) break;                                                   \
          sc = sn; idc = idn;                                                 \
        }                                                                     \
      } }

  if (R == 1) {
    if (sl < 9) {
      int dy = sl % 3 - 1, dz = sl / 3 - 1;
      int yy = cy + dy, zz = cz + dz;
      if (yy >= 0 && yy < G && zz >= 0 && zz < G) {
        int xs = max(cx - 1, 0), xe = min(cx + 1, G - 1);
        int base = (zz * G + yy) * G;
        int js = offs[base + xs], je = offs[base + xe + 1];
        SCANP()
      }
    }
  } else {
    const int twoR1 = 2 * R + 1, inner = 2 * R - 1;
    const int nfz = 2 * twoR1;
    const int nfull = nfz + 2 * inner;
    const int half = inner * inner;
    const int nitems = nfull + 2 * half;
    for (int m = sl; m < nitems; m += 16) {
      int dy, dz, js, je;
      if (m < nfull) {
        if (m < nfz) { dz = (m < twoR1) ? -R : R; dy = (m % twoR1) - R; }
        else { int u = m - nfz; dy = (u < inner) ? -R : R; dz = (u % inner) - (R - 1); }
        int yy = cy + dy, zz = cz + dz;
        if (yy < 0 || yy >= G || zz < 0 || zz >= G) continue;
        int xs = max(cx - R, 0), xe = min(cx + R, G - 1);
        int base = (zz * G + yy) * G;
        js = offs[base + xs]; je = offs[base + xe + 1];
      } else {
        int u = m - nfull;
        int xc = (u < half) ? (cx - R) : (cx + R);
        int r2 = (u < half) ? u : u - half;
        dy = r2 % inner - (R - 1); dz = r2 / inner - (R - 1);
        int yy = cy + dy, zz = cz + dz;
        if (xc < 0 || xc >= G || yy < 0 || yy >= G || zz < 0 || zz >= G) continue;
        int c = (zz * G + yy) * G + xc;
        js = offs[c]; je = offs[c + 1];
      }
      SCANP()
    }
  }
  #undef SCANP
}

#define MERGE16(E0, E1, E2, J0, J1, J2)                                       \
  { _Pragma("unroll")                                                         \
    for (int msk = 1; msk < 16; msk <<= 1) {                                  \
      float o0 = __shfl_xor(E0, msk), o1 = __shfl_xor(E1, msk), o2 = __shfl_xor(E2, msk); \
      int   p0 = __shfl_xor(J0, msk), p1 = __shfl_xor(J1, msk), p2 = __shfl_xor(J2, msk); \
      ins3(o0, p0, E0, E1, E2, J0, J1, J2);                                   \
      ins3(o1, p1, E0, E1, E2, J0, J1, J2);                                   \
      ins3(o2, p2, E0, E1, E2, J0, J1, J2);                                   \
    } }

// ---- dual-grid KNN + inlined build_t ---------------------------------------
// Grid A (G1, h_pos2 sources): result consumed IN-REGISTER by build_t.
// Grid B (G2, l_pos1 sources): (wC, idxC) written for the later res-gather.
__device__ void knn_bt_body(
    int bid,
    const float4* __restrict__ qspts, const int* __restrict__ qsidx, int Nq,
    int GA, const int* __restrict__ offsA, const float4* __restrict__ sptsA, const int* __restrict__ sidxA,
    int GB, const int* __restrict__ offsB, const float4* __restrict__ sptsB, const int* __restrict__ sidxB,
    float* __restrict__ wC_out, int* __restrict__ iC_out,
    const float* __restrict__ emb1, const float* __restrict__ emb2,
    unsigned short* __restrict__ t_hi, unsigned short* __restrict__ t_lo)
{
  const int sl = threadIdx.x & 15;
  const int qs = bid * 16 + (threadIdx.x >> 4);
  if (qs >= Nq) return;

  float4 qv = qspts[qs];
  const float qx = qv.x, qy = qv.y, qz = qv.z;
  const float sy = qv.w;
  const int qorig = qsidx[qs];
  const float csA = 1.0f / (float)GA, csB = 1.0f / (float)GB;
  const int cxA = cell_clamp(qx, GA), cyA = cell_clamp(qy, GA), czA = cell_clamp(qz, GA);
  const int cxB = cell_clamp(qx, GB), cyB = cell_clamp(qy, GB), czB = cell_clamp(qz, GB);

  float a0 = BIGF, a1 = BIGF, a2 = BIGF;  int ia0 = -1, ia1 = -1, ia2 = -1;
  float b0 = BIGF, b1 = BIGF, b2 = BIGF;  int ib0 = -1, ib1 = -1, ib2 = -1;
  float eA0 = BIGF, eA1 = BIGF, eA2 = BIGF; int jA0 = -1, jA1 = -1, jA2 = -1;
  float eB0 = BIGF, eB1 = BIGF, eB2 = BIGF; int jB0 = -1, jB1 = -1, jB2 = -1;
  bool doneA = false, doneB = false;

  const int Gmax = max(GA, GB);
  for (int R = 1; R <= Gmax; ++R) {
    if (!doneA && R <= GA)
      scan_shell(R, sl, GA, cxA, cyA, czA, offsA, sptsA, sidxA,
                 qx, qy, qz, sy, a0, a1, a2, ia0, ia1, ia2);
    if (!doneB && R <= GB)
      scan_shell(R, sl, GB, cxB, cyB, czB, offsB, sptsB, sidxB,
                 qx, qy, qz, sy, b0, b1, b2, ib0, ib1, ib2);
    if (!doneA && R <= GA) {
      eA0 = a0; eA1 = a1; eA2 = a2; jA0 = ia0; jA1 = ia1; jA2 = ia2;
      MERGE16(eA0, eA1, eA2, jA0, jA1, jA2)
      float bnd = (float)R * csA;
      doneA = (eA2 <= bnd * bnd - 1e-6f) || (R >= GA);
    }
    if (!doneB && R <= GB) {
      eB0 = b0; eB1 = b1; eB2 = b2; jB0 = ib0; jB1 = ib1; jB2 = ib2;
      MERGE16(eB0, eB1, eB2, jB0, jB1, jB2)
      float bnd = (float)R * csB;
      doneB = (eB2 <= bnd * bnd - 1e-6f) || (R >= GB);
    }
    if (__all(doneA && doneB)) break;
  }

  // grid-B result -> memory (consumed by res_gather after knn1's diff exists)
  if (sl == 0) {
    float w0 = 1.0f / fmaxf(eB0, 1e-16f);
    float w1 = 1.0f / fmaxf(eB1, 1e-16f);
    float w2 = 1.0f / fmaxf(eB2, 1e-16f);
    float inv = 1.0f / (w0 + w1 + w2);
    wC_out[(size_t)qorig * 3 + 0] = w0 * inv;
    wC_out[(size_t)qorig * 3 + 1] = w1 * inv;
    wC_out[(size_t)qorig * 3 + 2] = w2 * inv;
    iC_out[(size_t)qorig * 3 + 0] = jB0;
    iC_out[(size_t)qorig * 3 + 1] = jB1;
    iC_out[(size_t)qorig * 3 + 2] = jB2;
  }

  // ---- inlined build_t: every lane holds the merged grid-A result ----
  // t[qorig,:] = emb1[qorig,:] - (w0*emb2[jA0,:] + w1*emb2[jA1,:] + w2*emb2[jA2,:])
  // default contract (same codegen as rounds 12-16's build_t_body).
  {
    float w0 = 1.0f / fmaxf(eA0, 1e-16f);
    float w1 = 1.0f / fmaxf(eA1, 1e-16f);
    float w2 = 1.0f / fmaxf(eA2, 1e-16f);
    float inv = 1.0f / (w0 + w1 + w2);
    w0 *= inv; w1 *= inv; w2 *= inv;
    const float4* e1 = (const float4*)emb1;
    const float4* e2 = (const float4*)emb2;
    #pragma unroll
    for (int k = 0; k < 4; ++k) {
      int c4 = sl + 16 * k;                      // coalesced across the group
      float4 a  = e1[(size_t)qorig * 64 + c4];
      float4 f0 = e2[(size_t)jA0 * 64 + c4];
      float4 f1 = e2[(size_t)jA1 * 64 + c4];
      float4 f2 = e2[(size_t)jA2 * 64 + c4];
      float4 r;
      r.x = a.x - (w0 * f0.x + w1 * f1.x + w2 * f2.x);
      r.y = a.y - (w0 * f0.y + w1 * f1.y + w2 * f2.y);
      r.z = a.z - (w0 * f0.z + w1 * f1.z + w2 * f2.z);
      r.w = a.w - (w0 * f0.w + w1 * f1.w + w2 * f2.w);
      ushort4 h, l;
      h.x = f2bf(r.x); l.x = f2bf(r.x - bf2f(h.x));
      h.y = f2bf(r.y); l.y = f2bf(r.y - bf2f(h.y));
      h.z = f2bf(r.z); l.z = f2bf(r.z - bf2f(h.z));
      h.w = f2bf(r.w); l.w = f2bf(r.w - bf2f(h.w));
      size_t o = (size_t)qorig * 256 + (size_t)c4 * 4;
      *(ushort4*)&t_hi[o] = h;
      *(ushort4*)&t_lo[o] = l;
    }
  }
}

// ---- single-grid KNN body (knn1: out3 = base3 - interp) --------------------
__device__ void knn_single_body(
    int bid,
    const float4* __restrict__ qspts, const int* __restrict__ qsidx, int Nq, int G,
    const int* __restrict__ offs, const float4* __restrict__ spts, const int* __restrict__ sidx,
    const float* __restrict__ base3, const float* __restrict__ feat3,
    float* __restrict__ out3)
{
  #pragma clang fp contract(off)
  const int sl = threadIdx.x & 15;
  const int qs = bid * 16 + (threadIdx.x >> 4);
  if (qs >= Nq) return;

  float4 qv = qspts[qs];
  const float qx = qv.x, qy = qv.y, qz = qv.z;
  const float sy = qv.w;
  const int qorig = qsidx[qs];
  const float cs = 1.0f / (float)G;
  const int cx = cell_clamp(qx, G), cy = cell_clamp(qy, G), cz = cell_clamp(qz, G);

  float d0 = BIGF, d1 = BIGF, d2v = BIGF;
  int i0 = -1, i1 = -1, i2 = -1;
  float e0 = BIGF, e1 = BIGF, e2 = BIGF;
  int j0 = -1, j1 = -1, j2 = -1;
  bool done = false;

  for (int R = 1; R <= G; ++R) {
    if (!done) {
      scan_shell(R, sl, G, cx, cy, cz, offs, spts, sidx,
                 qx, qy, qz, sy, d0, d1, d2v, i0, i1, i2);
      e0 = d0; e1 = d1; e2 = d2v; j0 = i0; j1 = i1; j2 = i2;
      MERGE16(e0, e1, e2, j0, j1, j2)
      float bnd = (float)R * cs;
      done = (e2 <= bnd * bnd - 1e-6f) || (R >= G);
    }
    if (__all(done)) break;
  }

  if (sl == 0) {
    float w0 = 1.0f / fmaxf(e0, 1e-16f);
    float w1 = 1.0f / fmaxf(e1, 1e-16f);
    float w2 = 1.0f / fmaxf(e2, 1e-16f);
    float inv = 1.0f / (w0 + w1 + w2);
    w0 *= inv; w1 *= inv; w2 *= inv;
    #pragma unroll
    for (int f = 0; f < 3; ++f) {
      float v = w0 * feat3[(size_t)j0 * 3 + f]
              + w1 * feat3[(size_t)j1 * 3 + f]
              + w2 * feat3[(size_t)j2 * 3 + f];
      out3[(size_t)qorig * 3 + f] = base3[(size_t)qorig * 3 + f] - v;
    }
  }
}

// res[q,:] = sum_k wC[q,k] * diff[idxC[q,k],:]
__device__ void res_gather_body(
    int bid, const float* __restrict__ wC, const int* __restrict__ idxC,
    const float* __restrict__ diff, float* __restrict__ res, int Nq)
{
  int q = bid * 256 + threadIdx.x;
  if (q >= Nq) return;
  float w0 = wC[(size_t)q * 3 + 0], w1 = wC[(size_t)q * 3 + 1], w2 = wC[(size_t)q * 3 + 2];
  int i0 = idxC[(size_t)q * 3 + 0], i1 = idxC[(size_t)q * 3 + 1], i2 = idxC[(size_t)q * 3 + 2];
  #pragma unroll
  for (int f = 0; f < 3; ++f) {
    res[(size_t)q * 3 + f] = w0 * diff[(size_t)i0 * 3 + f]
                           + w1 * diff[(size_t)i1 * 3 + f]
                           + w2 * diff[(size_t)i2 * 3 + f];
  }
}

// ---- fused KNN+bt dispatch: dual-grid+build_t || knn1 ----------------------
// 1280 blocks = 256 groups x {4 dual+bt, 1 knn1}
__global__ __launch_bounds__(256) void knn_bt_kernel(
    const float4* qspts, const int* qsidx, int Nh,
    int G1, const int* offs1, const float4* spts1, const int* sidx1,
    int G2, const int* offs3, const float4* spts3, const int* sidx3,
    float* wC, int* idxC,
    const float* emb1, const float* emb2,
    unsigned short* t_hi, unsigned short* t_lo,
    int Nl, const int* offs2, const float4* spts2, const int* sidx2,
    const float* l_y1, const float* l_y2, float* diff)
{
  int g = blockIdx.x / 5, r = blockIdx.x % 5;
  if (r < 4)
    knn_bt_body(g * 4 + r, qspts, qsidx, Nh,
                G1, offs1, spts1, sidx1,
                G2, offs3, spts3, sidx3, wC, idxC,
                emb1, emb2, t_hi, t_lo);
  else
    knn_single_body(g, spts3, sidx3, Nl, G2, offs2, spts2, sidx2,
                    l_y1, l_y2, diff);
}

// ---- grid build ------------------------------------------------------------
__global__ __launch_bounds__(256) void zero_kernel(int* __restrict__ p, int n) {
  int i = blockIdx.x * 256 + threadIdx.x;
  if (i < n) p[i] = 0;
}

// count (blocks 0..159) + weight splits (blocks 160..671)
__global__ __launch_bounds__(256) void count_split_kernel(
    const float* __restrict__ p1, int n1, int g1, int* __restrict__ c1,
    const float* __restrict__ p2, int n2, int g2, int* __restrict__ c2,
    const float* __restrict__ p3, int n3, int g3, int* __restrict__ c3,
    const float* __restrict__ p4, int n4, int g4, int* __restrict__ c4,
    const float* __restrict__ W1, unsigned short* __restrict__ h1T, unsigned short* __restrict__ l1T,
    const float* __restrict__ W2, unsigned short* __restrict__ h2T, unsigned short* __restrict__ l2T)
{
  int b = blockIdx.x;
  if (b >= 160) {
    int sb = b - 160;
    const float* W = (sb < 256) ? W1 : W2;
    unsigned short* hiT = (sb < 256) ? h1T : h2T;
    unsigned short* loT = (sb < 256) ? l1T : l2T;
    int id = (sb & 255) * 256 + threadIdx.x;
    int k = id >> 8, n = id & 255;
    float x = W[id];
    unsigned short h = f2bf(x);
    unsigned short l = f2bf(x - bf2f(h));
    hiT[n * 256 + k] = h;
    loT[n * 256 + k] = l;
    return;
  }
  const float* p; int n, G; int* cnt; int i;
  if (b < 64)       { p = p1; n = n1; G = g1; cnt = c1; i = b * 256 + threadIdx.x; }
  else if (b < 80)  { p = p2; n = n2; G = g2; cnt = c2; i = (b - 64) * 256 + threadIdx.x; }
  else if (b < 96)  { p = p3; n = n3; G = g3; cnt = c3; i = (b - 80) * 256 + threadIdx.x; }
  else              { p = p4; n = n4; G = g4; cnt = c4; i = (b - 96) * 256 + threadIdx.x; }
  if (i >= n) return;
  int cx = cell_clamp(p[3 * i],     G);
  int cy = cell_clamp(p[3 * i + 1], G);
  int cz = cell_clamp(p[3 * i + 2], G);
  atomicAdd(&cnt[(cz * G + cy) * G + cx], 1);
}

__global__ __launch_bounds__(256) void prefix4_kernel(
    const int* __restrict__ c1, int* __restrict__ o1, int* __restrict__ u1, int m1,
    const int* __restrict__ c2, int* __restrict__ o2, int* __restrict__ u2, int m2,
    const int* __restrict__ c3, int* __restrict__ o3, int* __restrict__ u3, int m3,
    const int* __restrict__ c4, int* __restrict__ o4, int* __restrict__ u4, int m4)
{
  const int* cnt; int* offs; int* cur; int M;
  if (blockIdx.x == 0)      { cnt = c1; offs = o1; cur = u1; M = m1; }
  else if (blockIdx.x == 1) { cnt = c2; offs = o2; cur = u2; M = m2; }
  else if (blockIdx.x == 2) { cnt = c3; offs = o3; cur = u3; M = m3; }
  else                      { cnt = c4; offs = o4; cur = u4; M = m4; }
  __shared__ int ps[256];
  const int tid = threadIdx.x;
  const int per = (M + 255) >> 8;
  const int base = tid * per;
  int s = 0;
  for (int j = 0; j < per; ++j) if (base + j < M) s += cnt[base + j];
  ps[tid] = s;
  __syncthreads();
  for (int off = 1; off < 256; off <<= 1) {
    int v = (tid >= off) ? ps[tid - off] : 0;
    __syncthreads();
    ps[tid] += v;
    __syncthreads();
  }
  int run = (tid > 0) ? ps[tid - 1] : 0;
  for (int j = 0; j < per; ++j) {
    if (base + j < M) {
      offs[base + j] = run; cur[base + j] = run;
      run += cnt[base + j];
    }
  }
  if (tid == 255) offs[M] = run;
}

__global__ __launch_bounds__(256) void scatter4_kernel(
    const float* __restrict__ p1, int n1, int g1, int* __restrict__ u1, float4* __restrict__ s1, int* __restrict__ x1,
    const float* __restrict__ p2, int n2, int g2, int* __restrict__ u2, float4* __restrict__ s2, int* __restrict__ x2,
    const float* __restrict__ p3, int n3, int g3, int* __restrict__ u3, float4* __restrict__ s3, int* __restrict__ x3,
    const float* __restrict__ p4, int n4, int g4, int* __restrict__ u4, float4* __restrict__ s4, int* __restrict__ x4)
{
  #pragma clang fp contract(off)
  int b = blockIdx.x;
  const float* p; int n, G; int* cur; float4* spts; int* sidx; int i;
  if (b < 64)       { p = p1; n = n1; G = g1; cur = u1; spts = s1; sidx = x1; i = b * 256 + threadIdx.x; }
  else if (b < 80)  { p = p2; n = n2; G = g2; cur = u2; spts = s2; sidx = x2; i = (b - 64) * 256 + threadIdx.x; }
  else if (b < 96)  { p = p3; n = n3; G = g3; cur = u3; spts = s3; sidx = x3; i = (b - 80) * 256 + threadIdx.x; }
  else              { p = p4; n = n4; G = g4; cur = u4; spts = s4; sidx = x4; i = (b - 96) * 256 + threadIdx.x; }
  if (i >= n) return;
  float x = p[3 * i], y = p[3 * i + 1], z = p[3 * i + 2];
  int cx = cell_clamp(x, G), cy = cell_clamp(y, G), cz = cell_clamp(z, G);
  int c = (cz * G + cy) * G + cx;
  int pos = atomicAdd(&cur[c], 1);
  float sx = (x * x + y * y) + z * z;   // sequential, no contraction
  spts[pos] = make_float4(x, y, z, sx);
  sidx[pos] = i;
}

// ---------------------------------------------------------------------------
// bf16x3-split MFMA GEMM (verified round 12 — absmax 0.0625).
// Blocks [0, ngemm) do GEMM; blocks [ngemm, ngemm+nres) do res_gather.
// ---------------------------------------------------------------------------
__global__ __launch_bounds__(256) void mfma_gemm_kernel(
    const unsigned short* __restrict__ A_hi, const unsigned short* __restrict__ A_lo,
    const unsigned short* __restrict__ BT_hi, const unsigned short* __restrict__ BT_lo,
    const float* __restrict__ bias,
    float* __restrict__ outf,
    unsigned short* __restrict__ out_hi, unsigned short* __restrict__ out_lo,
    int relu, int split_out, int ngemm,
    const float* __restrict__ wC, const int* __restrict__ idxC,
    const float* __restrict__ diff, float* __restrict__ resout, int NqG)
{
  __shared__ unsigned short Bs_hi[64][132];
  __shared__ unsigned short Bs_lo[64][132];
  const int t = threadIdx.x;
  const int d = blockIdx.x;
  if (d >= ngemm) {
    res_gather_body(d - ngemm, wC, idxC, diff, resout, NqG);
    return;
  }
  const int xcd = d & 7, slot = d >> 3;
  const int lin = xcd * (ngemm >> 3) + slot;
  const int row0 = (lin >> 2) * 64;
  const int col0 = (lin & 3) * 64;

  const int l = t & 63, w = t >> 6;
  const int lr = l & 15;
  const int lk = (l >> 4) << 3;
  const unsigned short* arh = A_hi + (size_t)(row0 + w * 16 + lr) * 256;
  const unsigned short* arl = A_lo + (size_t)(row0 + w * 16 + lr) * 256;

  const int sc = t >> 2;
  const int sk = (t & 3) << 5;

  f32x4 acc0 = {0.f,0.f,0.f,0.f}, acc1 = {0.f,0.f,0.f,0.f};
  f32x4 acc2 = {0.f,0.f,0.f,0.f}, acc3 = {0.f,0.f,0.f,0.f};

  #define KSTEP(CT, ACC)                                                      \
    { s16x8 bh = *(const s16x8*)&Bs_hi[CT * 16 + lr][kc + lk];                \
      s16x8 bl = *(const s16x8*)&Bs_lo[CT * 16 + lr][kc + lk];                \
      ACC = __builtin_amdgcn_mfma_f32_16x16x32_bf16(ah, bh, ACC, 0, 0, 0);    \
      ACC = __builtin_amdgcn_mfma_f32_16x16x32_bf16(al, bh, ACC, 0, 0, 0);    \
      ACC = __builtin_amdgcn_mfma_f32_16x16x32_bf16(ah, bl, ACC, 0, 0, 0); }

  for (int half = 0; half < 2; ++half) {
    if (half) __syncthreads();
    {
      const int4* sh = (const int4*)&BT_hi[(size_t)(col0 + sc) * 256 + half * 128 + sk];
      const int4* slo = (const int4*)&BT_lo[(size_t)(col0 + sc) * 256 + half * 128 + sk];
      int4* dh = (int4*)&Bs_hi[sc][sk];
      int4* dl = (int4*)&Bs_lo[sc][sk];
      #pragma unroll
      for (int i = 0; i < 4; ++i) { dh[i] = sh[i]; dl[i] = slo[i]; }
    }
    __syncthreads();
    const int kbase = half * 128;
    #pragma unroll
    for (int kc = 0; kc < 128; kc += 32) {
      s16x8 ah = *(const s16x8*)&arh[kbase + kc + lk];
      s16x8 al = *(const s16x8*)&arl[kbase + kc + lk];
      KSTEP(0, acc0)
      KSTEP(1, acc1)
      KSTEP(2, acc2)
      KSTEP(3, acc3)
    }
  }
  #undef KSTEP

  const int orow = row0 + w * 16 + ((l >> 4) << 2);
  #define EPILOG(CT, ACC)                                                     \
    { int col = col0 + CT * 16 + lr;                                          \
      float bb = bias[col];                                                   \
      _Pragma("unroll")                                                       \
      for (int r = 0; r < 4; ++r) {                                           \
        float v = ACC[r] + bb;                                                \
        if (relu) v = fmaxf(v, 0.0f);                                         \
        size_t o = (size_t)(orow + r) * 256 + col;                            \
        if (split_out) {                                                      \
          unsigned short hh = f2bf(v);                                        \
          out_hi[o] = hh; out_lo[o] = f2bf(v - bf2f(hh));                     \
        } else {                                                              \
          outf[o] = v;                                                        \
        }                                                                     \
      } }
  EPILOG(0, acc0)
  EPILOG(1, acc1)
  EPILOG(2, acc2)
  EPILOG(3, acc3)
  #undef EPILOG
}

// ---------------------------------------------------------------------------
// out[r, :] = h2[r, :] @ W3[256,3] + b3 + res[r, :]   (wave per row)
// ---------------------------------------------------------------------------
__global__ __launch_bounds__(256) void final_kernel(
    const float* __restrict__ h2, const float* __restrict__ W3,
    const float* __restrict__ b3, const float* __restrict__ res,
    float* __restrict__ out, int M)
{
  __shared__ float sW3[768];
  const int tid = threadIdx.x;
  for (int i = tid; i < 768; i += 256) sW3[i] = W3[i];
  __syncthreads();

  const int wave = tid >> 6, lane = tid & 63;
  const int r = blockIdx.x * 4 + wave;
  if (r >= M) return;

  float4 h = ((const float4*)h2)[(size_t)r * 64 + lane];
  const int c = lane * 4;
  float a0 = h.x * sW3[(c + 0) * 3 + 0] + h.y * sW3[(c + 1) * 3 + 0]
           + h.z * sW3[(c + 2) * 3 + 0] + h.w * sW3[(c + 3) * 3 + 0];
  float a1 = h.x * sW3[(c + 0) * 3 + 1] + h.y * sW3[(c + 1) * 3 + 1]
           + h.z * sW3[(c + 2) * 3 + 1] + h.w * sW3[(c + 3) * 3 + 1];
  float a2 = h.x * sW3[(c + 0) * 3 + 2] + h.y * sW3[(c + 1) * 3 + 2]
           + h.z * sW3[(c + 2) * 3 + 2] + h.w * sW3[(c + 3) * 3 + 2];

  #pragma unroll
  for (int off = 32; off; off >>= 1) {
    a0 += __shfl_xor(a0, off);
    a1 += __shfl_xor(a1, off);
    a2 += __shfl_xor(a2, off);
  }
  if (lane == 0) {
    out[(size_t)r * 3 + 0] = a0 + b3[0] + res[(size_t)r * 3 + 0];
    out[(size_t)r * 3 + 1] = a1 + b3[1] + res[(size_t)r * 3 + 1];
    out[(size_t)r * 3 + 2] = a2 + b3[2] + res[(size_t)r * 3 + 2];
  }
}

// ---------------------------------------------------------------------------
extern "C" void kernel_launch(void* const* d_in, const int* in_sizes, int n_in,
                              void* d_out, int out_size, void* d_ws, size_t ws_size,
                              hipStream_t stream) {
  (void)in_sizes; (void)n_in; (void)out_size; (void)ws_size;
  const float* emb1   = (const float*)d_in[0];
  const float* l_y1   = (const float*)d_in[1];
  const float* l_pos1 = (const float*)d_in[2];
  const float* h_pos1 = (const float*)d_in[3];
  const float* emb2   = (const float*)d_in[4];
  const float* l_y2   = (const float*)d_in[5];
  const float* l_pos2 = (const float*)d_in[6];
  const float* h_pos2 = (const float*)d_in[7];
  const float* W1     = (const float*)d_in[8];
  const float* b1     = (const float*)d_in[9];
  const float* W2     = (const float*)d_in[10];
  const float* b2     = (const float*)d_in[11];
  const float* W3     = (const float*)d_in[12];
  const float* b3     = (const float*)d_in[13];
  float* out = (float*)d_out;

  const int Nh = 16384, Nl = 4096, H = 256;
  const int G1 = 16, G2 = 10;
  const int M1 = G1 * G1 * G1, M2 = G2 * G2 * G2;

  // ---- workspace carve-up (sequential bump allocator, 256B aligned) ----
  char* wsp = (char*)d_ws;
  size_t off = 0;
  auto alloc = [&](size_t bytes) -> void* {
    void* p = wsp + off;
    off += (bytes + 255) & ~(size_t)255;
    return p;
  };
  int*            idxC   = (int*)           alloc((size_t)Nh * 3 * 4);
  float*          wC     = (float*)         alloc((size_t)Nh * 3 * 4);
  unsigned short* t_hi   = (unsigned short*)alloc((size_t)Nh * H * 2);
  unsigned short* t_lo   = (unsigned short*)alloc((size_t)Nh * H * 2);
  unsigned short* h1_hi  = (unsigned short*)alloc((size_t)Nh * H * 2);
  unsigned short* h1_lo  = (unsigned short*)alloc((size_t)Nh * H * 2);
  float*          h2     = (float*)t_hi;    // alias over t_hi+t_lo (t dead)
  unsigned short* w1t_hi = (unsigned short*)alloc((size_t)H * H * 2);
  unsigned short* w1t_lo = (unsigned short*)alloc((size_t)H * H * 2);
  unsigned short* w2t_hi = (unsigned short*)alloc((size_t)H * H * 2);
  unsigned short* w2t_lo = (unsigned short*)alloc((size_t)H * H * 2);
  float*          diff   = (float*)         alloc((size_t)Nl * 3 * 4);
  float*          res    = (float*)         alloc((size_t)Nh * 3 * 4);
  int*            cnts   = (int*)           alloc((size_t)(M1 + M2 + M2 + M1) * 4);
  int* cnt1 = cnts, *cnt2 = cnts + M1, *cnt3 = cnts + M1 + M2, *cnt4 = cnts + M1 + 2 * M2;
  int*            offs1  = (int*)           alloc((size_t)(M1 + 1) * 4);
  int*            cur1   = (int*)           alloc((size_t)M1 * 4);
  int*            offs2  = (int*)           alloc((size_t)(M2 + 1) * 4);
  int*            cur2   = (int*)           alloc((size_t)M2 * 4);
  int*            offs3  = (int*)           alloc((size_t)(M2 + 1) * 4);
  int*            cur3   = (int*)           alloc((size_t)M2 * 4);
  int*            offs4  = (int*)           alloc((size_t)(M1 + 1) * 4);
  int*            cur4   = (int*)           alloc((size_t)M1 * 4);
  float4*         spts1  = (float4*)        alloc((size_t)Nh * 16);
  int*            sidx1  = (int*)           alloc((size_t)Nh * 4);
  float4*         spts2  = (float4*)        alloc((size_t)Nl * 16);
  int*            sidx2  = (int*)           alloc((size_t)Nl * 4);
  float4*         spts3  = (float4*)        alloc((size_t)Nl * 16);
  int*            sidx3  = (int*)           alloc((size_t)Nl * 4);
  float4*         qspts  = (float4*)        alloc((size_t)Nh * 16);   // sorted h_pos1
  int*            qsidx  = (int*)           alloc((size_t)Nh * 4);

  // ---- build grids (3 source + 1 query sort) + weight splits ----
  const int ncnt = M1 + M2 + M2 + M1;
  zero_kernel<<<(ncnt + 255) / 256, 256, 0, stream>>>(cnts, ncnt);
  count_split_kernel<<<672, 256, 0, stream>>>(
      h_pos2, Nh, G1, cnt1,  l_pos2, Nl, G2, cnt2,
      l_pos1, Nl, G2, cnt3,  h_pos1, Nh, G1, cnt4,
      W1, w1t_hi, w1t_lo, W2, w2t_hi, w2t_lo);
  prefix4_kernel<<<4, 256, 0, stream>>>(
      cnt1, offs1, cur1, M1,  cnt2, offs2, cur2, M2,
      cnt3, offs3, cur3, M2,  cnt4, offs4, cur4, M1);
  scatter4_kernel<<<160, 256, 0, stream>>>(
      h_pos2, Nh, G1, cur1, spts1, sidx1,
      l_pos2, Nl, G2, cur2, spts2, sidx2,
      l_pos1, Nl, G2, cur3, spts3, sidx3,
      h_pos1, Nh, G1, cur4, qspts, qsidx);

  // ---- KNN (dual-grid + inlined build_t) || knn1 ----
  knn_bt_kernel<<<1280, 256, 0, stream>>>(
      qspts, qsidx, Nh,
      G1, offs1, spts1, sidx1,
      G2, offs3, spts3, sidx3, wC, idxC,
      emb1, emb2, t_hi, t_lo,
      Nl, offs2, spts2, sidx2, l_y1, l_y2, diff);

  // ---- gemm1 (+ res_gather riding along) ----
  mfma_gemm_kernel<<<1024 + 64, 256, 0, stream>>>(
      t_hi, t_lo, w1t_hi, w1t_lo, b1, nullptr, h1_hi, h1_lo, 1, 1, 1024,
      wC, idxC, diff, res, Nh);
  // ---- gemm2 ----
  mfma_gemm_kernel<<<1024, 256, 0, stream>>>(
      h1_hi, h1_lo, w2t_hi, w2t_lo, b2, h2, nullptr, nullptr, 1, 0, 1024,
      nullptr, nullptr, nullptr, nullptr, 0);

  // ---- final: out = (h2 @ W3 + b3) + res ----
  final_kernel<<<Nh / 4, 256, 0, stream>>>(h2, W3, b3, res, out, Nh);
}

// Round 18
// 109.048 us; speedup vs baseline: 2.0987x; 1.0960x over previous
//
#include <hip/hip_runtime.h>
#include <math.h>

#define BIGF 3.0e38f

typedef short  s16x8 __attribute__((ext_vector_type(8)));
typedef float  f32x4 __attribute__((ext_vector_type(4)));

// bf16 helpers (manual RNE)
__device__ __forceinline__ unsigned short f2bf(float x) {
  unsigned int b = __float_as_uint(x);
  unsigned int r = b + 0x7FFFu + ((b >> 16) & 1u);
  return (unsigned short)(r >> 16);
}
__device__ __forceinline__ float bf2f(unsigned short h) {
  return __uint_as_float(((unsigned int)h) << 16);
}

// ===========================================================================
// Spatial-hash KNN (K=3), 16 lanes per query, row-range shell scan,
// cell-sorted query order, 4-deep batched point loads.
// Selection replicates the np reference's fp32 expansion distance:
//   sx  = (x*x + y*y) + z*z            (sequential, individually rounded)
//   dot = (p0 + p1) + p2, p_k = q_k*s_k
//   d2  = (sy + sx) - 2*dot
// under fp contract(off) (scan_shell-local pragma) — verified rounds 3-6.
// DO NOT TOUCH. Tie-break: lexicographic (d, idx) — makes the top-3
// independent of scan order, so the 4-wide batch is result-identical.
// Every candidate visited exactly once.
// ===========================================================================

__device__ __forceinline__ int cell_clamp(float v, int G) {
  int c = (int)(v * (float)G);
  return min(G - 1, max(0, c));
}

__device__ __forceinline__ void ins3(float d, int id,
                                     float& d0, float& d1, float& d2,
                                     int& i0, int& i1, int& i2) {
  bool l0 = (d < d0) || (d == d0 && id < i0);
  bool l1 = (d < d1) || (d == d1 && id < i1);
  bool l2 = (d < d2) || (d == d2 && id < i2);
  float nd0 = l0 ? d  : d0;  int ni0 = l0 ? id : i0;
  float nd1 = l0 ? d0 : (l1 ? d  : d1);
  int   ni1 = l0 ? i0 : (l1 ? id : i1);
  float nd2 = l1 ? d1 : (l2 ? d  : d2);
  int   ni2 = l1 ? i1 : (l2 ? id : i2);
  d0 = nd0; d1 = nd1; d2 = nd2; i0 = ni0; i1 = ni1; i2 = ni2;
}

// scan one Chebyshev shell R of grid G; per-lane local top-3 accumulate.
// 4-deep load batching (order-independent thanks to lex tie-break).
__device__ __forceinline__ void scan_shell(
    int R, int sl, int G, int cx, int cy, int cz,
    const int* __restrict__ offs, const float4* __restrict__ spts,
    const int* __restrict__ sidx,
    float qx, float qy, float qz, float sy,
    float& d0, float& d1, float& d2v, int& i0, int& i1, int& i2)
{
  #pragma clang fp contract(off)
  #define DIST_INS(SV, IDV)                                                   \
    { float p0 = qx * SV.x, p1 = qy * SV.y, p2 = qz * SV.z;                   \
      float dt = (p0 + p1) + p2;                                              \
      float S  = sy + SV.w;                                                   \
      float dd = S - 2.0f * dt;                                               \
      ins3(dd, IDV, d0, d1, d2v, i0, i1, i2); }

  #define SCANP()                                                             \
    { int j = js;                                                             \
      for (; j + 4 <= je; j += 4) {                                           \
        float4 s0 = spts[j],     s1 = spts[j + 1];                            \
        float4 s2 = spts[j + 2], s3 = spts[j + 3];                            \
        int id0 = sidx[j],     id1 = sidx[j + 1];                             \
        int id2 = sidx[j + 2], id3 = sidx[j + 3];                             \
        DIST_INS(s0, id0) DIST_INS(s1, id1)                                   \
        DIST_INS(s2, id2) DIST_INS(s3, id3)                                   \
      }                                                                       \
      for (; j < je; ++j) {                                                   \
        float4 s = spts[j]; int id = sidx[j];                                 \
        DIST_INS(s, id)                                                       \
      } }

  if (R == 1) {
    if (sl < 9) {
      int dy = sl % 3 - 1, dz = sl / 3 - 1;
      int yy = cy + dy, zz = cz + dz;
      if (yy >= 0 && yy < G && zz >= 0 && zz < G) {
        int xs = max(cx - 1, 0), xe = min(cx + 1, G - 1);
        int base = (zz * G + yy) * G;
        int js = offs[base + xs], je = offs[base + xe + 1];
        SCANP()
      }
    }
  } else {
    const int twoR1 = 2 * R + 1, inner = 2 * R - 1;
    const int nfz = 2 * twoR1;
    const int nfull = nfz + 2 * inner;
    const int half = inner * inner;
    const int nitems = nfull + 2 * half;
    for (int m = sl; m < nitems; m += 16) {
      int dy, dz, js, je;
      if (m < nfull) {
        if (m < nfz) { dz = (m < twoR1) ? -R : R; dy = (m % twoR1) - R; }
        else { int u = m - nfz; dy = (u < inner) ? -R : R; dz = (u % inner) - (R - 1); }
        int yy = cy + dy, zz = cz + dz;
        if (yy < 0 || yy >= G || zz < 0 || zz >= G) continue;
        int xs = max(cx - R, 0), xe = min(cx + R, G - 1);
        int base = (zz * G + yy) * G;
        js = offs[base + xs]; je = offs[base + xe + 1];
      } else {
        int u = m - nfull;
        int xc = (u < half) ? (cx - R) : (cx + R);
        int r2 = (u < half) ? u : u - half;
        dy = r2 % inner - (R - 1); dz = r2 / inner - (R - 1);
        int yy = cy + dy, zz = cz + dz;
        if (xc < 0 || xc >= G || yy < 0 || yy >= G || zz < 0 || zz >= G) continue;
        int c = (zz * G + yy) * G + xc;
        js = offs[c]; je = offs[c + 1];
      }
      SCANP()
    }
  }
  #undef SCANP
  #undef DIST_INS
}

#define MERGE16(E0, E1, E2, J0, J1, J2)                                       \
  { _Pragma("unroll")                                                         \
    for (int msk = 1; msk < 16; msk <<= 1) {                                  \
      float o0 = __shfl_xor(E0, msk), o1 = __shfl_xor(E1, msk), o2 = __shfl_xor(E2, msk); \
      int   p0 = __shfl_xor(J0, msk), p1 = __shfl_xor(J1, msk), p2 = __shfl_xor(J2, msk); \
      ins3(o0, p0, E0, E1, E2, J0, J1, J2);                                   \
      ins3(o1, p1, E0, E1, E2, J0, J1, J2);                                   \
      ins3(o2, p2, E0, E1, E2, J0, J1, J2);                                   \
    } }

// ---- generic single-grid search: leaves merged top-3 in (e*, j*) ----------
__device__ __forceinline__ void knn_search(
    int sl, float qx, float qy, float qz, float sy, int G,
    const int* __restrict__ offs, const float4* __restrict__ spts,
    const int* __restrict__ sidx,
    float& e0, float& e1, float& e2, int& j0, int& j1, int& j2)
{
  const float cs = 1.0f / (float)G;
  const int cx = cell_clamp(qx, G), cy = cell_clamp(qy, G), cz = cell_clamp(qz, G);
  float d0 = BIGF, d1 = BIGF, d2v = BIGF;
  int i0 = -1, i1 = -1, i2 = -1;
  bool done = false;
  for (int R = 1; R <= G; ++R) {
    if (!done) {
      scan_shell(R, sl, G, cx, cy, cz, offs, spts, sidx,
                 qx, qy, qz, sy, d0, d1, d2v, i0, i1, i2);
      e0 = d0; e1 = d1; e2 = d2v; j0 = i0; j1 = i1; j2 = i2;
      MERGE16(e0, e1, e2, j0, j1, j2)
      float bnd = (float)R * cs;
      done = (e2 <= bnd * bnd - 1e-6f) || (R >= G);
    }
    if (__all(done)) break;
  }
}

// ---- knn0 + inlined build_t (grid G1 over h_pos2 sources) ------------------
__device__ void knn0_bt_body(
    int bid,
    const float4* __restrict__ qspts, const int* __restrict__ qsidx, int Nq,
    int G, const int* __restrict__ offs, const float4* __restrict__ spts, const int* __restrict__ sidx,
    const float* __restrict__ emb1, const float* __restrict__ emb2,
    unsigned short* __restrict__ t_hi, unsigned short* __restrict__ t_lo)
{
  const int sl = threadIdx.x & 15;
  const int qs = bid * 16 + (threadIdx.x >> 4);
  if (qs >= Nq) return;
  float4 qv = qspts[qs];
  const int qorig = qsidx[qs];

  float e0, e1, e2; int j0, j1, j2;
  knn_search(sl, qv.x, qv.y, qv.z, qv.w, G, offs, spts, sidx,
             e0, e1, e2, j0, j1, j2);

  // inlined build_t: every lane holds the merged result post-butterfly.
  // default contract (same codegen as rounds 12-17's build_t).
  float w0 = 1.0f / fmaxf(e0, 1e-16f);
  float w1 = 1.0f / fmaxf(e1, 1e-16f);
  float w2 = 1.0f / fmaxf(e2, 1e-16f);
  float inv = 1.0f / (w0 + w1 + w2);
  w0 *= inv; w1 *= inv; w2 *= inv;
  const float4* e1p = (const float4*)emb1;
  const float4* e2p = (const float4*)emb2;
  #pragma unroll
  for (int k = 0; k < 4; ++k) {
    int c4 = sl + 16 * k;                      // coalesced across the group
    float4 a  = e1p[(size_t)qorig * 64 + c4];
    float4 f0 = e2p[(size_t)j0 * 64 + c4];
    float4 f1 = e2p[(size_t)j1 * 64 + c4];
    float4 f2 = e2p[(size_t)j2 * 64 + c4];
    float4 r;
    r.x = a.x - (w0 * f0.x + w1 * f1.x + w2 * f2.x);
    r.y = a.y - (w0 * f0.y + w1 * f1.y + w2 * f2.y);
    r.z = a.z - (w0 * f0.z + w1 * f1.z + w2 * f2.z);
    r.w = a.w - (w0 * f0.w + w1 * f1.w + w2 * f2.w);
    ushort4 h, l;
    h.x = f2bf(r.x); l.x = f2bf(r.x - bf2f(h.x));
    h.y = f2bf(r.y); l.y = f2bf(r.y - bf2f(h.y));
    h.z = f2bf(r.z); l.z = f2bf(r.z - bf2f(h.z));
    h.w = f2bf(r.w); l.w = f2bf(r.w - bf2f(h.w));
    size_t o = (size_t)qorig * 256 + (size_t)c4 * 4;
    *(ushort4*)&t_hi[o] = h;
    *(ushort4*)&t_lo[o] = l;
  }
}

// ---- knn2: search grid G2 (l_pos1 sources), write (wC, idxC) ---------------
__device__ void knn2_body(
    int bid,
    const float4* __restrict__ qspts, const int* __restrict__ qsidx, int Nq,
    int G, const int* __restrict__ offs, const float4* __restrict__ spts, const int* __restrict__ sidx,
    float* __restrict__ wC_out, int* __restrict__ iC_out)
{
  const int sl = threadIdx.x & 15;
  const int qs = bid * 16 + (threadIdx.x >> 4);
  if (qs >= Nq) return;
  float4 qv = qspts[qs];
  const int qorig = qsidx[qs];

  float e0, e1, e2; int j0, j1, j2;
  knn_search(sl, qv.x, qv.y, qv.z, qv.w, G, offs, spts, sidx,
             e0, e1, e2, j0, j1, j2);

  if (sl == 0) {
    float w0 = 1.0f / fmaxf(e0, 1e-16f);
    float w1 = 1.0f / fmaxf(e1, 1e-16f);
    float w2 = 1.0f / fmaxf(e2, 1e-16f);
    float inv = 1.0f / (w0 + w1 + w2);
    wC_out[(size_t)qorig * 3 + 0] = w0 * inv;
    wC_out[(size_t)qorig * 3 + 1] = w1 * inv;
    wC_out[(size_t)qorig * 3 + 2] = w2 * inv;
    iC_out[(size_t)qorig * 3 + 0] = j0;
    iC_out[(size_t)qorig * 3 + 1] = j1;
    iC_out[(size_t)qorig * 3 + 2] = j2;
  }
}

// ---- knn1: search grid (l_pos2 sources), out3 = base3 - interp(feat3) ------
__device__ void knn1_body(
    int bid,
    const float4* __restrict__ qspts, const int* __restrict__ qsidx, int Nq, int G,
    const int* __restrict__ offs, const float4* __restrict__ spts, const int* __restrict__ sidx,
    const float* __restrict__ base3, const float* __restrict__ feat3,
    float* __restrict__ out3)
{
  const int sl = threadIdx.x & 15;
  const int qs = bid * 16 + (threadIdx.x >> 4);
  if (qs >= Nq) return;
  float4 qv = qspts[qs];
  const int qorig = qsidx[qs];

  float e0, e1, e2; int j0, j1, j2;
  knn_search(sl, qv.x, qv.y, qv.z, qv.w, G, offs, spts, sidx,
             e0, e1, e2, j0, j1, j2);

  if (sl == 0) {
    float w0 = 1.0f / fmaxf(e0, 1e-16f);
    float w1 = 1.0f / fmaxf(e1, 1e-16f);
    float w2 = 1.0f / fmaxf(e2, 1e-16f);
    float inv = 1.0f / (w0 + w1 + w2);
    w0 *= inv; w1 *= inv; w2 *= inv;
    #pragma unroll
    for (int f = 0; f < 3; ++f) {
      float v = w0 * feat3[(size_t)j0 * 3 + f]
              + w1 * feat3[(size_t)j1 * 3 + f]
              + w2 * feat3[(size_t)j2 * 3 + f];
      out3[(size_t)qorig * 3 + f] = base3[(size_t)qorig * 3 + f] - v;
    }
  }
}

// res[q,:] = sum_k wC[q,k] * diff[idxC[q,k],:]
__device__ void res_gather_body(
    int bid, const float* __restrict__ wC, const int* __restrict__ idxC,
    const float* __restrict__ diff, float* __restrict__ res, int Nq)
{
  int q = bid * 256 + threadIdx.x;
  if (q >= Nq) return;
  float w0 = wC[(size_t)q * 3 + 0], w1 = wC[(size_t)q * 3 + 1], w2 = wC[(size_t)q * 3 + 2];
  int i0 = idxC[(size_t)q * 3 + 0], i1 = idxC[(size_t)q * 3 + 1], i2 = idxC[(size_t)q * 3 + 2];
  #pragma unroll
  for (int f = 0; f < 3; ++f) {
    res[(size_t)q * 3 + f] = w0 * diff[(size_t)i0 * 3 + f]
                           + w1 * diff[(size_t)i1 * 3 + f]
                           + w2 * diff[(size_t)i2 * 3 + f];
  }
}

// ---- fused KNN dispatch: knn0+bt || knn2 || knn1 (all independent) ---------
// 2304 blocks = 256 groups x {4 knn0+bt, 4 knn2, 1 knn1}
__global__ __launch_bounds__(256) void knn_all_kernel(
    const float4* qspts, const int* qsidx, int Nh,
    int G1, const int* offs1, const float4* spts1, const int* sidx1,
    const float* emb1, const float* emb2,
    unsigned short* t_hi, unsigned short* t_lo,
    int G2, const int* offs3, const float4* spts3, const int* sidx3,
    float* wC, int* idxC,
    int Nl, const int* offs2, const float4* spts2, const int* sidx2,
    const float* l_y1, const float* l_y2, float* diff)
{
  int g = blockIdx.x / 9, r = blockIdx.x % 9;
  if (r < 4)
    knn0_bt_body(g * 4 + r, qspts, qsidx, Nh, G1, offs1, spts1, sidx1,
                 emb1, emb2, t_hi, t_lo);
  else if (r < 8)
    knn2_body(g * 4 + (r - 4), qspts, qsidx, Nh, G2, offs3, spts3, sidx3,
              wC, idxC);
  else
    knn1_body(g, spts3, sidx3, Nl, G2, offs2, spts2, sidx2,
              l_y1, l_y2, diff);
}

// ---- grid build ------------------------------------------------------------
__global__ __launch_bounds__(256) void zero_kernel(int* __restrict__ p, int n) {
  int i = blockIdx.x * 256 + threadIdx.x;
  if (i < n) p[i] = 0;
}

// count (blocks 0..159) + weight splits (blocks 160..671)
__global__ __launch_bounds__(256) void count_split_kernel(
    const float* __restrict__ p1, int n1, int g1, int* __restrict__ c1,
    const float* __restrict__ p2, int n2, int g2, int* __restrict__ c2,
    const float* __restrict__ p3, int n3, int g3, int* __restrict__ c3,
    const float* __restrict__ p4, int n4, int g4, int* __restrict__ c4,
    const float* __restrict__ W1, unsigned short* __restrict__ h1T, unsigned short* __restrict__ l1T,
    const float* __restrict__ W2, unsigned short* __restrict__ h2T, unsigned short* __restrict__ l2T)
{
  int b = blockIdx.x;
  if (b >= 160) {
    int sb = b - 160;
    const float* W = (sb < 256) ? W1 : W2;
    unsigned short* hiT = (sb < 256) ? h1T : h2T;
    unsigned short* loT = (sb < 256) ? l1T : l2T;
    int id = (sb & 255) * 256 + threadIdx.x;
    int k = id >> 8, n = id & 255;
    float x = W[id];
    unsigned short h = f2bf(x);
    unsigned short l = f2bf(x - bf2f(h));
    hiT[n * 256 + k] = h;
    loT[n * 256 + k] = l;
    return;
  }
  const float* p; int n, G; int* cnt; int i;
  if (b < 64)       { p = p1; n = n1; G = g1; cnt = c1; i = b * 256 + threadIdx.x; }
  else if (b < 80)  { p = p2; n = n2; G = g2; cnt = c2; i = (b - 64) * 256 + threadIdx.x; }
  else if (b < 96)  { p = p3; n = n3; G = g3; cnt = c3; i = (b - 80) * 256 + threadIdx.x; }
  else              { p = p4; n = n4; G = g4; cnt = c4; i = (b - 96) * 256 + threadIdx.x; }
  if (i >= n) return;
  int cx = cell_clamp(p[3 * i],     G);
  int cy = cell_clamp(p[3 * i + 1], G);
  int cz = cell_clamp(p[3 * i + 2], G);
  atomicAdd(&cnt[(cz * G + cy) * G + cx], 1);
}

__global__ __launch_bounds__(256) void prefix4_kernel(
    const int* __restrict__ c1, int* __restrict__ o1, int* __restrict__ u1, int m1,
    const int* __restrict__ c2, int* __restrict__ o2, int* __restrict__ u2, int m2,
    const int* __restrict__ c3, int* __restrict__ o3, int* __restrict__ u3, int m3,
    const int* __restrict__ c4, int* __restrict__ o4, int* __restrict__ u4, int m4)
{
  const int* cnt; int* offs; int* cur; int M;
  if (blockIdx.x == 0)      { cnt = c1; offs = o1; cur = u1; M = m1; }
  else if (blockIdx.x == 1) { cnt = c2; offs = o2; cur = u2; M = m2; }
  else if (blockIdx.x == 2) { cnt = c3; offs = o3; cur = u3; M = m3; }
  else                      { cnt = c4; offs = o4; cur = u4; M = m4; }
  __shared__ int ps[256];
  const int tid = threadIdx.x;
  const int per = (M + 255) >> 8;
  const int base = tid * per;
  int s = 0;
  for (int j = 0; j < per; ++j) if (base + j < M) s += cnt[base + j];
  ps[tid] = s;
  __syncthreads();
  for (int off = 1; off < 256; off <<= 1) {
    int v = (tid >= off) ? ps[tid - off] : 0;
    __syncthreads();
    ps[tid] += v;
    __syncthreads();
  }
  int run = (tid > 0) ? ps[tid - 1] : 0;
  for (int j = 0; j < per; ++j) {
    if (base + j < M) {
      offs[base + j] = run; cur[base + j] = run;
      run += cnt[base + j];
    }
  }
  if (tid == 255) offs[M] = run;
}

__global__ __launch_bounds__(256) void scatter4_kernel(
    const float* __restrict__ p1, int n1, int g1, int* __restrict__ u1, float4* __restrict__ s1, int* __restrict__ x1,
    const float* __restrict__ p2, int n2, int g2, int* __restrict__ u2, float4* __restrict__ s2, int* __restrict__ x2,
    const float* __restrict__ p3, int n3, int g3, int* __restrict__ u3, float4* __restrict__ s3, int* __restrict__ x3,
    const float* __restrict__ p4, int n4, int g4, int* __restrict__ u4, float4* __restrict__ s4, int* __restrict__ x4)
{
  #pragma clang fp contract(off)
  int b = blockIdx.x;
  const float* p; int n, G; int* cur; float4* spts; int* sidx; int i;
  if (b < 64)       { p = p1; n = n1; G = g1; cur = u1; spts = s1; sidx = x1; i = b * 256 + threadIdx.x; }
  else if (b < 80)  { p = p2; n = n2; G = g2; cur = u2; spts = s2; sidx = x2; i = (b - 64) * 256 + threadIdx.x; }
  else if (b < 96)  { p = p3; n = n3; G = g3; cur = u3; spts = s3; sidx = x3; i = (b - 80) * 256 + threadIdx.x; }
  else              { p = p4; n = n4; G = g4; cur = u4; spts = s4; sidx = x4; i = (b - 96) * 256 + threadIdx.x; }
  if (i >= n) return;
  float x = p[3 * i], y = p[3 * i + 1], z = p[3 * i + 2];
  int cx = cell_clamp(x, G), cy = cell_clamp(y, G), cz = cell_clamp(z, G);
  int c = (cz * G + cy) * G + cx;
  int pos = atomicAdd(&cur[c], 1);
  float sx = (x * x + y * y) + z * z;   // sequential, no contraction
  spts[pos] = make_float4(x, y, z, sx);
  sidx[pos] = i;
}

// ---------------------------------------------------------------------------
// bf16x3-split MFMA GEMM (verified round 12 — absmax 0.0625).
// Blocks [0, ngemm) do GEMM; blocks [ngemm, ...) do res_gather.
// ---------------------------------------------------------------------------
__global__ __launch_bounds__(256) void mfma_gemm_kernel(
    const unsigned short* __restrict__ A_hi, const unsigned short* __restrict__ A_lo,
    const unsigned short* __restrict__ BT_hi, const unsigned short* __restrict__ BT_lo,
    const float* __restrict__ bias,
    float* __restrict__ outf,
    unsigned short* __restrict__ out_hi, unsigned short* __restrict__ out_lo,
    int relu, int split_out, int ngemm,
    const float* __restrict__ wC, const int* __restrict__ idxC,
    const float* __restrict__ diff, float* __restrict__ resout, int NqG)
{
  __shared__ unsigned short Bs_hi[64][132];
  __shared__ unsigned short Bs_lo[64][132];
  const int t = threadIdx.x;
  const int d = blockIdx.x;
  if (d >= ngemm) {
    res_gather_body(d - ngemm, wC, idxC, diff, resout, NqG);
    return;
  }
  const int xcd = d & 7, slot = d >> 3;
  const int lin = xcd * (ngemm >> 3) + slot;
  const int row0 = (lin >> 2) * 64;
  const int col0 = (lin & 3) * 64;

  const int l = t & 63, w = t >> 6;
  const int lr = l & 15;
  const int lk = (l >> 4) << 3;
  const unsigned short* arh = A_hi + (size_t)(row0 + w * 16 + lr) * 256;
  const unsigned short* arl = A_lo + (size_t)(row0 + w * 16 + lr) * 256;

  const int sc = t >> 2;
  const int sk = (t & 3) << 5;

  f32x4 acc0 = {0.f,0.f,0.f,0.f}, acc1 = {0.f,0.f,0.f,0.f};
  f32x4 acc2 = {0.f,0.f,0.f,0.f}, acc3 = {0.f,0.f,0.f,0.f};

  #define KSTEP(CT, ACC)                                                      \
    { s16x8 bh = *(const s16x8*)&Bs_hi[CT * 16 + lr][kc + lk];                \
      s16x8 bl = *(const s16x8*)&Bs_lo[CT * 16 + lr][kc + lk];                \
      ACC = __builtin_amdgcn_mfma_f32_16x16x32_bf16(ah, bh, ACC, 0, 0, 0);    \
      ACC = __builtin_amdgcn_mfma_f32_16x16x32_bf16(al, bh, ACC, 0, 0, 0);    \
      ACC = __builtin_amdgcn_mfma_f32_16x16x32_bf16(ah, bl, ACC, 0, 0, 0); }

  for (int half = 0; half < 2; ++half) {
    if (half) __syncthreads();
    {
      const int4* sh = (const int4*)&BT_hi[(size_t)(col0 + sc) * 256 + half * 128 + sk];
      const int4* slo = (const int4*)&BT_lo[(size_t)(col0 + sc) * 256 + half * 128 + sk];
      int4* dh = (int4*)&Bs_hi[sc][sk];
      int4* dl = (int4*)&Bs_lo[sc][sk];
      #pragma unroll
      for (int i = 0; i < 4; ++i) { dh[i] = sh[i]; dl[i] = slo[i]; }
    }
    __syncthreads();
    const int kbase = half * 128;
    #pragma unroll
    for (int kc = 0; kc < 128; kc += 32) {
      s16x8 ah = *(const s16x8*)&arh[kbase + kc + lk];
      s16x8 al = *(const s16x8*)&arl[kbase + kc + lk];
      KSTEP(0, acc0)
      KSTEP(1, acc1)
      KSTEP(2, acc2)
      KSTEP(3, acc3)
    }
  }
  #undef KSTEP

  const int orow = row0 + w * 16 + ((l >> 4) << 2);
  #define EPILOG(CT, ACC)                                                     \
    { int col = col0 + CT * 16 + lr;                                          \
      float bb = bias[col];                                                   \
      _Pragma("unroll")                                                       \
      for (int r = 0; r < 4; ++r) {                                           \
        float v = ACC[r] + bb;                                                \
        if (relu) v = fmaxf(v, 0.0f);                                         \
        size_t o = (size_t)(orow + r) * 256 + col;                            \
        if (split_out) {                                                      \
          unsigned short hh = f2bf(v);                                        \
          out_hi[o] = hh; out_lo[o] = f2bf(v - bf2f(hh));                     \
        } else {                                                              \
          outf[o] = v;                                                        \
        }                                                                     \
      } }
  EPILOG(0, acc0)
  EPILOG(1, acc1)
  EPILOG(2, acc2)
  EPILOG(3, acc3)
  #undef EPILOG
}

// ---------------------------------------------------------------------------
// out[r, :] = h2[r, :] @ W3[256,3] + b3 + res[r, :]   (wave per row)
// ---------------------------------------------------------------------------
__global__ __launch_bounds__(256) void final_kernel(
    const float* __restrict__ h2, const float* __restrict__ W3,
    const float* __restrict__ b3, const float* __restrict__ res,
    float* __restrict__ out, int M)
{
  __shared__ float sW3[768];
  const int tid = threadIdx.x;
  for (int i = tid; i < 768; i += 256) sW3[i] = W3[i];
  __syncthreads();

  const int wave = tid >> 6, lane = tid & 63;
  const int r = blockIdx.x * 4 + wave;
  if (r >= M) return;

  float4 h = ((const float4*)h2)[(size_t)r * 64 + lane];
  const int c = lane * 4;
  float a0 = h.x * sW3[(c + 0) * 3 + 0] + h.y * sW3[(c + 1) * 3 + 0]
           + h.z * sW3[(c + 2) * 3 + 0] + h.w * sW3[(c + 3) * 3 + 0];
  float a1 = h.x * sW3[(c + 0) * 3 + 1] + h.y * sW3[(c + 1) * 3 + 1]
           + h.z * sW3[(c + 2) * 3 + 1] + h.w * sW3[(c + 3) * 3 + 1];
  float a2 = h.x * sW3[(c + 0) * 3 + 2] + h.y * sW3[(c + 1) * 3 + 2]
           + h.z * sW3[(c + 2) * 3 + 2] + h.w * sW3[(c + 3) * 3 + 2];

  #pragma unroll
  for (int off = 32; off; off >>= 1) {
    a0 += __shfl_xor(a0, off);
    a1 += __shfl_xor(a1, off);
    a2 += __shfl_xor(a2, off);
  }
  if (lane == 0) {
    out[(size_t)r * 3 + 0] = a0 + b3[0] + res[(size_t)r * 3 + 0];
    out[(size_t)r * 3 + 1] = a1 + b3[1] + res[(size_t)r * 3 + 1];
    out[(size_t)r * 3 + 2] = a2 + b3[2] + res[(size_t)r * 3 + 2];
  }
}

// ---------------------------------------------------------------------------
extern "C" void kernel_launch(void* const* d_in, const int* in_sizes, int n_in,
                              void* d_out, int out_size, void* d_ws, size_t ws_size,
                              hipStream_t stream) {
  (void)in_sizes; (void)n_in; (void)out_size; (void)ws_size;
  const float* emb1   = (const float*)d_in[0];
  const float* l_y1   = (const float*)d_in[1];
  const float* l_pos1 = (const float*)d_in[2];
  const float* h_pos1 = (const float*)d_in[3];
  const float* emb2   = (const float*)d_in[4];
  const float* l_y2   = (const float*)d_in[5];
  const float* l_pos2 = (const float*)d_in[6];
  const float* h_pos2 = (const float*)d_in[7];
  const float* W1     = (const float*)d_in[8];
  const float* b1     = (const float*)d_in[9];
  const float* W2     = (const float*)d_in[10];
  const float* b2     = (const float*)d_in[11];
  const float* W3     = (const float*)d_in[12];
  const float* b3     = (const float*)d_in[13];
  float* out = (float*)d_out;

  const int Nh = 16384, Nl = 4096, H = 256;
  const int G1 = 16, G2 = 10;
  const int M1 = G1 * G1 * G1, M2 = G2 * G2 * G2;

  // ---- workspace carve-up (sequential bump allocator, 256B aligned) ----
  char* wsp = (char*)d_ws;
  size_t off = 0;
  auto alloc = [&](size_t bytes) -> void* {
    void* p = wsp + off;
    off += (bytes + 255) & ~(size_t)255;
    return p;
  };
  int*            idxC   = (int*)           alloc((size_t)Nh * 3 * 4);
  float*          wC     = (float*)         alloc((size_t)Nh * 3 * 4);
  unsigned short* t_hi   = (unsigned short*)alloc((size_t)Nh * H * 2);
  unsigned short* t_lo   = (unsigned short*)alloc((size_t)Nh * H * 2);
  unsigned short* h1_hi  = (unsigned short*)alloc((size_t)Nh * H * 2);
  unsigned short* h1_lo  = (unsigned short*)alloc((size_t)Nh * H * 2);
  float*          h2     = (float*)t_hi;    // alias over t_hi+t_lo (t dead)
  unsigned short* w1t_hi = (unsigned short*)alloc((size_t)H * H * 2);
  unsigned short* w1t_lo = (unsigned short*)alloc((size_t)H * H * 2);
  unsigned short* w2t_hi = (unsigned short*)alloc((size_t)H * H * 2);
  unsigned short* w2t_lo = (unsigned short*)alloc((size_t)H * H * 2);
  float*          diff   = (float*)         alloc((size_t)Nl * 3 * 4);
  float*          res    = (float*)         alloc((size_t)Nh * 3 * 4);
  int*            cnts   = (int*)           alloc((size_t)(M1 + M2 + M2 + M1) * 4);
  int* cnt1 = cnts, *cnt2 = cnts + M1, *cnt3 = cnts + M1 + M2, *cnt4 = cnts + M1 + 2 * M2;
  int*            offs1  = (int*)           alloc((size_t)(M1 + 1) * 4);
  int*            cur1   = (int*)           alloc((size_t)M1 * 4);
  int*            offs2  = (int*)           alloc((size_t)(M2 + 1) * 4);
  int*            cur2   = (int*)           alloc((size_t)M2 * 4);
  int*            offs3  = (int*)           alloc((size_t)(M2 + 1) * 4);
  int*            cur3   = (int*)           alloc((size_t)M2 * 4);
  int*            offs4  = (int*)           alloc((size_t)(M1 + 1) * 4);
  int*            cur4   = (int*)           alloc((size_t)M1 * 4);
  float4*         spts1  = (float4*)        alloc((size_t)Nh * 16);
  int*            sidx1  = (int*)           alloc((size_t)Nh * 4);
  float4*         spts2  = (float4*)        alloc((size_t)Nl * 16);
  int*            sidx2  = (int*)           alloc((size_t)Nl * 4);
  float4*         spts3  = (float4*)        alloc((size_t)Nl * 16);
  int*            sidx3  = (int*)           alloc((size_t)Nl * 4);
  float4*         qspts  = (float4*)        alloc((size_t)Nh * 16);   // sorted h_pos1
  int*            qsidx  = (int*)           alloc((size_t)Nh * 4);

  // ---- build grids (3 source + 1 query sort) + weight splits ----
  const int ncnt = M1 + M2 + M2 + M1;
  zero_kernel<<<(ncnt + 255) / 256, 256, 0, stream>>>(cnts, ncnt);
  count_split_kernel<<<672, 256, 0, stream>>>(
      h_pos2, Nh, G1, cnt1,  l_pos2, Nl, G2, cnt2,
      l_pos1, Nl, G2, cnt3,  h_pos1, Nh, G1, cnt4,
      W1, w1t_hi, w1t_lo, W2, w2t_hi, w2t_lo);
  prefix4_kernel<<<4, 256, 0, stream>>>(
      cnt1, offs1, cur1, M1,  cnt2, offs2, cur2, M2,
      cnt3, offs3, cur3, M2,  cnt4, offs4, cur4, M1);
  scatter4_kernel<<<160, 256, 0, stream>>>(
      h_pos2, Nh, G1, cur1, spts1, sidx1,
      l_pos2, Nl, G2, cur2, spts2, sidx2,
      l_pos1, Nl, G2, cur3, spts3, sidx3,
      h_pos1, Nh, G1, cur4, qspts, qsidx);

  // ---- all KNN work in one dispatch: knn0+bt || knn2 || knn1 ----
  knn_all_kernel<<<2304, 256, 0, stream>>>(
      qspts, qsidx, Nh,
      G1, offs1, spts1, sidx1, emb1, emb2, t_hi, t_lo,
      G2, offs3, spts3, sidx3, wC, idxC,
      Nl, offs2, spts2, sidx2, l_y1, l_y2, diff);

  // ---- gemm1 (+ res_gather riding along) ----
  mfma_gemm_kernel<<<1024 + 64, 256, 0, stream>>>(
      t_hi, t_lo, w1t_hi, w1t_lo, b1, nullptr, h1_hi, h1_lo, 1, 1, 1024,
      wC, idxC, diff, res, Nh);
  // ---- gemm2 ----
  mfma_gemm_kernel<<<1024, 256, 0, stream>>>(
      h1_hi, h1_lo, w2t_hi, w2t_lo, b2, h2, nullptr, nullptr, 1, 0, 1024,
      nullptr, nullptr, nullptr, nullptr, 0);

  // ---- final: out = (h2 @ W3 + b3) + res ----
  final_kernel<<<Nh / 4, 256, 0, stream>>>(h2, W3, b3, res, out, Nh);
}

// Round 19
// 108.799 us; speedup vs baseline: 2.1035x; 1.0023x over previous
//
#include <hip/hip_runtime.h>
#include <math.h>

#define BIGF 3.0e38f

typedef short  s16x8 __attribute__((ext_vector_type(8)));
typedef float  f32x4 __attribute__((ext_vector_type(4)));

// bf16 helpers (manual RNE)
__device__ __forceinline__ unsigned short f2bf(float x) {
  unsigned int b = __float_as_uint(x);
  unsigned int r = b + 0x7FFFu + ((b >> 16) & 1u);
  return (unsigned short)(r >> 16);
}
__device__ __forceinline__ float bf2f(unsigned short h) {
  return __uint_as_float(((unsigned int)h) << 16);
}

// ===========================================================================
// Spatial-hash KNN (K=3), 16 lanes per query, row-range shell scan,
// cell-sorted query order, 4-deep batched point loads, 128-thread blocks
// (finer scheduling quanta -> better CU wave-slot packing).
// Selection replicates the np reference's fp32 expansion distance:
//   sx  = (x*x + y*y) + z*z            (sequential, individually rounded)
//   dot = (p0 + p1) + p2, p_k = q_k*s_k
//   d2  = (sy + sx) - 2*dot
// under fp contract(off) (scan_shell-local pragma) — verified rounds 3-6.
// DO NOT TOUCH. Tie-break: lexicographic (d, idx) — scan-order independent.
// Every candidate visited exactly once.
// ===========================================================================

__device__ __forceinline__ int cell_clamp(float v, int G) {
  int c = (int)(v * (float)G);
  return min(G - 1, max(0, c));
}

__device__ __forceinline__ void ins3(float d, int id,
                                     float& d0, float& d1, float& d2,
                                     int& i0, int& i1, int& i2) {
  bool l0 = (d < d0) || (d == d0 && id < i0);
  bool l1 = (d < d1) || (d == d1 && id < i1);
  bool l2 = (d < d2) || (d == d2 && id < i2);
  float nd0 = l0 ? d  : d0;  int ni0 = l0 ? id : i0;
  float nd1 = l0 ? d0 : (l1 ? d  : d1);
  int   ni1 = l0 ? i0 : (l1 ? id : i1);
  float nd2 = l1 ? d1 : (l2 ? d  : d2);
  int   ni2 = l1 ? i1 : (l2 ? id : i2);
  d0 = nd0; d1 = nd1; d2 = nd2; i0 = ni0; i1 = ni1; i2 = ni2;
}

// scan one Chebyshev shell R of grid G; per-lane local top-3 accumulate.
// 4-deep load batching (order-independent thanks to lex tie-break).
__device__ __forceinline__ void scan_shell(
    int R, int sl, int G, int cx, int cy, int cz,
    const int* __restrict__ offs, const float4* __restrict__ spts,
    const int* __restrict__ sidx,
    float qx, float qy, float qz, float sy,
    float& d0, float& d1, float& d2v, int& i0, int& i1, int& i2)
{
  #pragma clang fp contract(off)
  #define DIST_INS(SV, IDV)                                                   \
    { float p0 = qx * SV.x, p1 = qy * SV.y, p2 = qz * SV.z;                   \
      float dt = (p0 + p1) + p2;                                              \
      float S  = sy + SV.w;                                                   \
      float dd = S - 2.0f * dt;                                               \
      ins3(dd, IDV, d0, d1, d2v, i0, i1, i2); }

  #define SCANP()                                                             \
    { int j = js;                                                             \
      for (; j + 4 <= je; j += 4) {                                           \
        float4 s0 = spts[j],     s1 = spts[j + 1];                            \
        float4 s2 = spts[j + 2], s3 = spts[j + 3];                            \
        int id0 = sidx[j],     id1 = sidx[j + 1];                             \
        int id2 = sidx[j + 2], id3 = sidx[j + 3];                             \
        DIST_INS(s0, id0) DIST_INS(s1, id1)                                   \
        DIST_INS(s2, id2) DIST_INS(s3, id3)                                   \
      }                                                                       \
      for (; j < je; ++j) {                                                   \
        float4 s = spts[j]; int id = sidx[j];                                 \
        DIST_INS(s, id)                                                       \
      } }

  if (R == 1) {
    if (sl < 9) {
      int dy = sl % 3 - 1, dz = sl / 3 - 1;
      int yy = cy + dy, zz = cz + dz;
      if (yy >= 0 && yy < G && zz >= 0 && zz < G) {
        int xs = max(cx - 1, 0), xe = min(cx + 1, G - 1);
        int base = (zz * G + yy) * G;
        int js = offs[base + xs], je = offs[base + xe + 1];
        SCANP()
      }
    }
  } else {
    const int twoR1 = 2 * R + 1, inner = 2 * R - 1;
    const int nfz = 2 * twoR1;
    const int nfull = nfz + 2 * inner;
    const int half = inner * inner;
    const int nitems = nfull + 2 * half;
    for (int m = sl; m < nitems; m += 16) {
      int dy, dz, js, je;
      if (m < nfull) {
        if (m < nfz) { dz = (m < twoR1) ? -R : R; dy = (m % twoR1) - R; }
        else { int u = m - nfz; dy = (u < inner) ? -R : R; dz = (u % inner) - (R - 1); }
        int yy = cy + dy, zz = cz + dz;
        if (yy < 0 || yy >= G || zz < 0 || zz >= G) continue;
        int xs = max(cx - R, 0), xe = min(cx + R, G - 1);
        int base = (zz * G + yy) * G;
        js = offs[base + xs]; je = offs[base + xe + 1];
      } else {
        int u = m - nfull;
        int xc = (u < half) ? (cx - R) : (cx + R);
        int r2 = (u < half) ? u : u - half;
        dy = r2 % inner - (R - 1); dz = r2 / inner - (R - 1);
        int yy = cy + dy, zz = cz + dz;
        if (xc < 0 || xc >= G || yy < 0 || yy >= G || zz < 0 || zz >= G) continue;
        int c = (zz * G + yy) * G + xc;
        js = offs[c]; je = offs[c + 1];
      }
      SCANP()
    }
  }
  #undef SCANP
  #undef DIST_INS
}

#define MERGE16(E0, E1, E2, J0, J1, J2)                                       \
  { _Pragma("unroll")                                                         \
    for (int msk = 1; msk < 16; msk <<= 1) {                                  \
      float o0 = __shfl_xor(E0, msk), o1 = __shfl_xor(E1, msk), o2 = __shfl_xor(E2, msk); \
      int   p0 = __shfl_xor(J0, msk), p1 = __shfl_xor(J1, msk), p2 = __shfl_xor(J2, msk); \
      ins3(o0, p0, E0, E1, E2, J0, J1, J2);                                   \
      ins3(o1, p1, E0, E1, E2, J0, J1, J2);                                   \
      ins3(o2, p2, E0, E1, E2, J0, J1, J2);                                   \
    } }

// ---- generic single-grid search: leaves merged top-3 in (e*, j*) ----------
__device__ __forceinline__ void knn_search(
    int sl, float qx, float qy, float qz, float sy, int G,
    const int* __restrict__ offs, const float4* __restrict__ spts,
    const int* __restrict__ sidx,
    float& e0, float& e1, float& e2, int& j0, int& j1, int& j2)
{
  const float cs = 1.0f / (float)G;
  const int cx = cell_clamp(qx, G), cy = cell_clamp(qy, G), cz = cell_clamp(qz, G);
  float d0 = BIGF, d1 = BIGF, d2v = BIGF;
  int i0 = -1, i1 = -1, i2 = -1;
  bool done = false;
  for (int R = 1; R <= G; ++R) {
    if (!done) {
      scan_shell(R, sl, G, cx, cy, cz, offs, spts, sidx,
                 qx, qy, qz, sy, d0, d1, d2v, i0, i1, i2);
      e0 = d0; e1 = d1; e2 = d2v; j0 = i0; j1 = i1; j2 = i2;
      MERGE16(e0, e1, e2, j0, j1, j2)
      float bnd = (float)R * cs;
      done = (e2 <= bnd * bnd - 1e-6f) || (R >= G);
    }
    if (__all(done)) break;
  }
}

// ---- knn0 + inlined build_t (grid G1 over h_pos2 sources); 8 queries/block -
__device__ void knn0_bt_body(
    int bid,
    const float4* __restrict__ qspts, const int* __restrict__ qsidx, int Nq,
    int G, const int* __restrict__ offs, const float4* __restrict__ spts, const int* __restrict__ sidx,
    const float* __restrict__ emb1, const float* __restrict__ emb2,
    unsigned short* __restrict__ t_hi, unsigned short* __restrict__ t_lo)
{
  const int sl = threadIdx.x & 15;
  const int qs = bid * 8 + (threadIdx.x >> 4);
  if (qs >= Nq) return;
  float4 qv = qspts[qs];
  const int qorig = qsidx[qs];

  float e0, e1, e2; int j0, j1, j2;
  knn_search(sl, qv.x, qv.y, qv.z, qv.w, G, offs, spts, sidx,
             e0, e1, e2, j0, j1, j2);

  // inlined build_t: every lane holds the merged result post-butterfly.
  // default contract (same codegen as rounds 12-18's build_t).
  float w0 = 1.0f / fmaxf(e0, 1e-16f);
  float w1 = 1.0f / fmaxf(e1, 1e-16f);
  float w2 = 1.0f / fmaxf(e2, 1e-16f);
  float inv = 1.0f / (w0 + w1 + w2);
  w0 *= inv; w1 *= inv; w2 *= inv;
  const float4* e1p = (const float4*)emb1;
  const float4* e2p = (const float4*)emb2;
  #pragma unroll
  for (int k = 0; k < 4; ++k) {
    int c4 = sl + 16 * k;                      // coalesced across the group
    float4 a  = e1p[(size_t)qorig * 64 + c4];
    float4 f0 = e2p[(size_t)j0 * 64 + c4];
    float4 f1 = e2p[(size_t)j1 * 64 + c4];
    float4 f2 = e2p[(size_t)j2 * 64 + c4];
    float4 r;
    r.x = a.x - (w0 * f0.x + w1 * f1.x + w2 * f2.x);
    r.y = a.y - (w0 * f0.y + w1 * f1.y + w2 * f2.y);
    r.z = a.z - (w0 * f0.z + w1 * f1.z + w2 * f2.z);
    r.w = a.w - (w0 * f0.w + w1 * f1.w + w2 * f2.w);
    ushort4 h, l;
    h.x = f2bf(r.x); l.x = f2bf(r.x - bf2f(h.x));
    h.y = f2bf(r.y); l.y = f2bf(r.y - bf2f(h.y));
    h.z = f2bf(r.z); l.z = f2bf(r.z - bf2f(h.z));
    h.w = f2bf(r.w); l.w = f2bf(r.w - bf2f(h.w));
    size_t o = (size_t)qorig * 256 + (size_t)c4 * 4;
    *(ushort4*)&t_hi[o] = h;
    *(ushort4*)&t_lo[o] = l;
  }
}

// ---- knn2: search grid G2 (l_pos1 sources), write (wC, idxC) ---------------
__device__ void knn2_body(
    int bid,
    const float4* __restrict__ qspts, const int* __restrict__ qsidx, int Nq,
    int G, const int* __restrict__ offs, const float4* __restrict__ spts, const int* __restrict__ sidx,
    float* __restrict__ wC_out, int* __restrict__ iC_out)
{
  const int sl = threadIdx.x & 15;
  const int qs = bid * 8 + (threadIdx.x >> 4);
  if (qs >= Nq) return;
  float4 qv = qspts[qs];
  const int qorig = qsidx[qs];

  float e0, e1, e2; int j0, j1, j2;
  knn_search(sl, qv.x, qv.y, qv.z, qv.w, G, offs, spts, sidx,
             e0, e1, e2, j0, j1, j2);

  if (sl == 0) {
    float w0 = 1.0f / fmaxf(e0, 1e-16f);
    float w1 = 1.0f / fmaxf(e1, 1e-16f);
    float w2 = 1.0f / fmaxf(e2, 1e-16f);
    float inv = 1.0f / (w0 + w1 + w2);
    wC_out[(size_t)qorig * 3 + 0] = w0 * inv;
    wC_out[(size_t)qorig * 3 + 1] = w1 * inv;
    wC_out[(size_t)qorig * 3 + 2] = w2 * inv;
    iC_out[(size_t)qorig * 3 + 0] = j0;
    iC_out[(size_t)qorig * 3 + 1] = j1;
    iC_out[(size_t)qorig * 3 + 2] = j2;
  }
}

// ---- knn1: search grid (l_pos2 sources), out3 = base3 - interp(feat3) ------
__device__ void knn1_body(
    int bid,
    const float4* __restrict__ qspts, const int* __restrict__ qsidx, int Nq, int G,
    const int* __restrict__ offs, const float4* __restrict__ spts, const int* __restrict__ sidx,
    const float* __restrict__ base3, const float* __restrict__ feat3,
    float* __restrict__ out3)
{
  const int sl = threadIdx.x & 15;
  const int qs = bid * 8 + (threadIdx.x >> 4);
  if (qs >= Nq) return;
  float4 qv = qspts[qs];
  const int qorig = qsidx[qs];

  float e0, e1, e2; int j0, j1, j2;
  knn_search(sl, qv.x, qv.y, qv.z, qv.w, G, offs, spts, sidx,
             e0, e1, e2, j0, j1, j2);

  if (sl == 0) {
    float w0 = 1.0f / fmaxf(e0, 1e-16f);
    float w1 = 1.0f / fmaxf(e1, 1e-16f);
    float w2 = 1.0f / fmaxf(e2, 1e-16f);
    float inv = 1.0f / (w0 + w1 + w2);
    w0 *= inv; w1 *= inv; w2 *= inv;
    #pragma unroll
    for (int f = 0; f < 3; ++f) {
      float v = w0 * feat3[(size_t)j0 * 3 + f]
              + w1 * feat3[(size_t)j1 * 3 + f]
              + w2 * feat3[(size_t)j2 * 3 + f];
      out3[(size_t)qorig * 3 + f] = base3[(size_t)qorig * 3 + f] - v;
    }
  }
}

// res[q,:] = sum_k wC[q,k] * diff[idxC[q,k],:]
__device__ void res_gather_body(
    int bid, const float* __restrict__ wC, const int* __restrict__ idxC,
    const float* __restrict__ diff, float* __restrict__ res, int Nq)
{
  int q = bid * 256 + threadIdx.x;
  if (q >= Nq) return;
  float w0 = wC[(size_t)q * 3 + 0], w1 = wC[(size_t)q * 3 + 1], w2 = wC[(size_t)q * 3 + 2];
  int i0 = idxC[(size_t)q * 3 + 0], i1 = idxC[(size_t)q * 3 + 1], i2 = idxC[(size_t)q * 3 + 2];
  #pragma unroll
  for (int f = 0; f < 3; ++f) {
    res[(size_t)q * 3 + f] = w0 * diff[(size_t)i0 * 3 + f]
                           + w1 * diff[(size_t)i1 * 3 + f]
                           + w2 * diff[(size_t)i2 * 3 + f];
  }
}

// ---- fused KNN dispatch, 128-thread blocks (8 queries each) -----------------
// 4608 blocks = 512 groups x {4 knn0+bt, 4 knn2, 1 knn1}
__global__ __launch_bounds__(128) void knn_all_kernel(
    const float4* qspts, const int* qsidx, int Nh,
    int G1, const int* offs1, const float4* spts1, const int* sidx1,
    const float* emb1, const float* emb2,
    unsigned short* t_hi, unsigned short* t_lo,
    int G2, const int* offs3, const float4* spts3, const int* sidx3,
    float* wC, int* idxC,
    int Nl, const int* offs2, const float4* spts2, const int* sidx2,
    const float* l_y1, const float* l_y2, float* diff)
{
  int g = blockIdx.x / 9, r = blockIdx.x % 9;
  if (r < 4)
    knn0_bt_body(g * 4 + r, qspts, qsidx, Nh, G1, offs1, spts1, sidx1,
                 emb1, emb2, t_hi, t_lo);
  else if (r < 8)
    knn2_body(g * 4 + (r - 4), qspts, qsidx, Nh, G2, offs3, spts3, sidx3,
              wC, idxC);
  else
    knn1_body(g, spts3, sidx3, Nl, G2, offs2, spts2, sidx2,
              l_y1, l_y2, diff);
}

// ---- grid build ------------------------------------------------------------
__global__ __launch_bounds__(256) void zero_kernel(int* __restrict__ p, int n) {
  int i = blockIdx.x * 256 + threadIdx.x;
  if (i < n) p[i] = 0;
}

// count (blocks 0..159) + weight splits (blocks 160..671)
__global__ __launch_bounds__(256) void count_split_kernel(
    const float* __restrict__ p1, int n1, int g1, int* __restrict__ c1,
    const float* __restrict__ p2, int n2, int g2, int* __restrict__ c2,
    const float* __restrict__ p3, int n3, int g3, int* __restrict__ c3,
    const float* __restrict__ p4, int n4, int g4, int* __restrict__ c4,
    const float* __restrict__ W1, unsigned short* __restrict__ h1T, unsigned short* __restrict__ l1T,
    const float* __restrict__ W2, unsigned short* __restrict__ h2T, unsigned short* __restrict__ l2T)
{
  int b = blockIdx.x;
  if (b >= 160) {
    int sb = b - 160;
    const float* W = (sb < 256) ? W1 : W2;
    unsigned short* hiT = (sb < 256) ? h1T : h2T;
    unsigned short* loT = (sb < 256) ? l1T : l2T;
    int id = (sb & 255) * 256 + threadIdx.x;
    int k = id >> 8, n = id & 255;
    float x = W[id];
    unsigned short h = f2bf(x);
    unsigned short l = f2bf(x - bf2f(h));
    hiT[n * 256 + k] = h;
    loT[n * 256 + k] = l;
    return;
  }
  const float* p; int n, G; int* cnt; int i;
  if (b < 64)       { p = p1; n = n1; G = g1; cnt = c1; i = b * 256 + threadIdx.x; }
  else if (b < 80)  { p = p2; n = n2; G = g2; cnt = c2; i = (b - 64) * 256 + threadIdx.x; }
  else if (b < 96)  { p = p3; n = n3; G = g3; cnt = c3; i = (b - 80) * 256 + threadIdx.x; }
  else              { p = p4; n = n4; G = g4; cnt = c4; i = (b - 96) * 256 + threadIdx.x; }
  if (i >= n) return;
  int cx = cell_clamp(p[3 * i],     G);
  int cy = cell_clamp(p[3 * i + 1], G);
  int cz = cell_clamp(p[3 * i + 2], G);
  atomicAdd(&cnt[(cz * G + cy) * G + cx], 1);
}

__global__ __launch_bounds__(256) void prefix4_kernel(
    const int* __restrict__ c1, int* __restrict__ o1, int* __restrict__ u1, int m1,
    const int* __restrict__ c2, int* __restrict__ o2, int* __restrict__ u2, int m2,
    const int* __restrict__ c3, int* __restrict__ o3, int* __restrict__ u3, int m3,
    const int* __restrict__ c4, int* __restrict__ o4, int* __restrict__ u4, int m4)
{
  const int* cnt; int* offs; int* cur; int M;
  if (blockIdx.x == 0)      { cnt = c1; offs = o1; cur = u1; M = m1; }
  else if (blockIdx.x == 1) { cnt = c2; offs = o2; cur = u2; M = m2; }
  else if (blockIdx.x == 2) { cnt = c3; offs = o3; cur = u3; M = m3; }
  else                      { cnt = c4; offs = o4; cur = u4; M = m4; }
  __shared__ int ps[256];
  const int tid = threadIdx.x;
  const int per = (M + 255) >> 8;
  const int base = tid * per;
  int s = 0;
  for (int j = 0; j < per; ++j) if (base + j < M) s += cnt[base + j];
  ps[tid] = s;
  __syncthreads();
  for (int off = 1; off < 256; off <<= 1) {
    int v = (tid >= off) ? ps[tid - off] : 0;
    __syncthreads();
    ps[tid] += v;
    __syncthreads();
  }
  int run = (tid > 0) ? ps[tid - 1] : 0;
  for (int j = 0; j < per; ++j) {
    if (base + j < M) {
      offs[base + j] = run; cur[base + j] = run;
      run += cnt[base + j];
    }
  }
  if (tid == 255) offs[M] = run;
}

__global__ __launch_bounds__(256) void scatter4_kernel(
    const float* __restrict__ p1, int n1, int g1, int* __restrict__ u1, float4* __restrict__ s1, int* __restrict__ x1,
    const float* __restrict__ p2, int n2, int g2, int* __restrict__ u2, float4* __restrict__ s2, int* __restrict__ x2,
    const float* __restrict__ p3, int n3, int g3, int* __restrict__ u3, float4* __restrict__ s3, int* __restrict__ x3,
    const float* __restrict__ p4, int n4, int g4, int* __restrict__ u4, float4* __restrict__ s4, int* __restrict__ x4)
{
  #pragma clang fp contract(off)
  int b = blockIdx.x;
  const float* p; int n, G; int* cur; float4* spts; int* sidx; int i;
  if (b < 64)       { p = p1; n = n1; G = g1; cur = u1; spts = s1; sidx = x1; i = b * 256 + threadIdx.x; }
  else if (b < 80)  { p = p2; n = n2; G = g2; cur = u2; spts = s2; sidx = x2; i = (b - 64) * 256 + threadIdx.x; }
  else if (b < 96)  { p = p3; n = n3; G = g3; cur = u3; spts = s3; sidx = x3; i = (b - 80) * 256 + threadIdx.x; }
  else              { p = p4; n = n4; G = g4; cur = u4; spts = s4; sidx = x4; i = (b - 96) * 256 + threadIdx.x; }
  if (i >= n) return;
  float x = p[3 * i], y = p[3 * i + 1], z = p[3 * i + 2];
  int cx = cell_clamp(x, G), cy = cell_clamp(y, G), cz = cell_clamp(z, G);
  int c = (cz * G + cy) * G + cx;
  int pos = atomicAdd(&cur[c], 1);
  float sx = (x * x + y * y) + z * z;   // sequential, no contraction
  spts[pos] = make_float4(x, y, z, sx);
  sidx[pos] = i;
}

// ---------------------------------------------------------------------------
// bf16x3-split MFMA GEMM (verified round 12 — absmax 0.0625).
// Blocks [0, ngemm) do GEMM; blocks [ngemm, ...) do res_gather.
// ---------------------------------------------------------------------------
__global__ __launch_bounds__(256) void mfma_gemm_kernel(
    const unsigned short* __restrict__ A_hi, const unsigned short* __restrict__ A_lo,
    const unsigned short* __restrict__ BT_hi, const unsigned short* __restrict__ BT_lo,
    const float* __restrict__ bias,
    float* __restrict__ outf,
    unsigned short* __restrict__ out_hi, unsigned short* __restrict__ out_lo,
    int relu, int split_out, int ngemm,
    const float* __restrict__ wC, const int* __restrict__ idxC,
    const float* __restrict__ diff, float* __restrict__ resout, int NqG)
{
  __shared__ unsigned short Bs_hi[64][132];
  __shared__ unsigned short Bs_lo[64][132];
  const int t = threadIdx.x;
  const int d = blockIdx.x;
  if (d >= ngemm) {
    res_gather_body(d - ngemm, wC, idxC, diff, resout, NqG);
    return;
  }
  const int xcd = d & 7, slot = d >> 3;
  const int lin = xcd * (ngemm >> 3) + slot;
  const int row0 = (lin >> 2) * 64;
  const int col0 = (lin & 3) * 64;

  const int l = t & 63, w = t >> 6;
  const int lr = l & 15;
  const int lk = (l >> 4) << 3;
  const unsigned short* arh = A_hi + (size_t)(row0 + w * 16 + lr) * 256;
  const unsigned short* arl = A_lo + (size_t)(row0 + w * 16 + lr) * 256;

  const int sc = t >> 2;
  const int sk = (t & 3) << 5;

  f32x4 acc0 = {0.f,0.f,0.f,0.f}, acc1 = {0.f,0.f,0.f,0.f};
  f32x4 acc2 = {0.f,0.f,0.f,0.f}, acc3 = {0.f,0.f,0.f,0.f};

  #define KSTEP(CT, ACC)                                                      \
    { s16x8 bh = *(const s16x8*)&Bs_hi[CT * 16 + lr][kc + lk];                \
      s16x8 bl = *(const s16x8*)&Bs_lo[CT * 16 + lr][kc + lk];                \
      ACC = __builtin_amdgcn_mfma_f32_16x16x32_bf16(ah, bh, ACC, 0, 0, 0);    \
      ACC = __builtin_amdgcn_mfma_f32_16x16x32_bf16(al, bh, ACC, 0, 0, 0);    \
      ACC = __builtin_amdgcn_mfma_f32_16x16x32_bf16(ah, bl, ACC, 0, 0, 0); }

  for (int half = 0; half < 2; ++half) {
    if (half) __syncthreads();
    {
      const int4* sh = (const int4*)&BT_hi[(size_t)(col0 + sc) * 256 + half * 128 + sk];
      const int4* slo = (const int4*)&BT_lo[(size_t)(col0 + sc) * 256 + half * 128 + sk];
      int4* dh = (int4*)&Bs_hi[sc][sk];
      int4* dl = (int4*)&Bs_lo[sc][sk];
      #pragma unroll
      for (int i = 0; i < 4; ++i) { dh[i] = sh[i]; dl[i] = slo[i]; }
    }
    __syncthreads();
    const int kbase = half * 128;
    #pragma unroll
    for (int kc = 0; kc < 128; kc += 32) {
      s16x8 ah = *(const s16x8*)&arh[kbase + kc + lk];
      s16x8 al = *(const s16x8*)&arl[kbase + kc + lk];
      KSTEP(0, acc0)
      KSTEP(1, acc1)
      KSTEP(2, acc2)
      KSTEP(3, acc3)
    }
  }
  #undef KSTEP

  const int orow = row0 + w * 16 + ((l >> 4) << 2);
  #define EPILOG(CT, ACC)                                                     \
    { int col = col0 + CT * 16 + lr;                                          \
      float bb = bias[col];                                                   \
      _Pragma("unroll")                                                       \
      for (int r = 0; r < 4; ++r) {                                           \
        float v = ACC[r] + bb;                                                \
        if (relu) v = fmaxf(v, 0.0f);                                         \
        size_t o = (size_t)(orow + r) * 256 + col;                            \
        if (split_out) {                                                      \
          unsigned short hh = f2bf(v);                                        \
          out_hi[o] = hh; out_lo[o] = f2bf(v - bf2f(hh));                     \
        } else {                                                              \
          outf[o] = v;                                                        \
        }                                                                     \
      } }
  EPILOG(0, acc0)
  EPILOG(1, acc1)
  EPILOG(2, acc2)
  EPILOG(3, acc3)
  #undef EPILOG
}

// ---------------------------------------------------------------------------
// out[r, :] = h2[r, :] @ W3[256,3] + b3 + res[r, :]   (wave per row)
// ---------------------------------------------------------------------------
__global__ __launch_bounds__(256) void final_kernel(
    const float* __restrict__ h2, const float* __restrict__ W3,
    const float* __restrict__ b3, const float* __restrict__ res,
    float* __restrict__ out, int M)
{
  __shared__ float sW3[768];
  const int tid = threadIdx.x;
  for (int i = tid; i < 768; i += 256) sW3[i] = W3[i];
  __syncthreads();

  const int wave = tid >> 6, lane = tid & 63;
  const int r = blockIdx.x * 4 + wave;
  if (r >= M) return;

  float4 h = ((const float4*)h2)[(size_t)r * 64 + lane];
  const int c = lane * 4;
  float a0 = h.x * sW3[(c + 0) * 3 + 0] + h.y * sW3[(c + 1) * 3 + 0]
           + h.z * sW3[(c + 2) * 3 + 0] + h.w * sW3[(c + 3) * 3 + 0];
  float a1 = h.x * sW3[(c + 0) * 3 + 1] + h.y * sW3[(c + 1) * 3 + 1]
           + h.z * sW3[(c + 2) * 3 + 1] + h.w * sW3[(c + 3) * 3 + 1];
  float a2 = h.x * sW3[(c + 0) * 3 + 2] + h.y * sW3[(c + 1) * 3 + 2]
           + h.z * sW3[(c + 2) * 3 + 2] + h.w * sW3[(c + 3) * 3 + 2];

  #pragma unroll
  for (int off = 32; off; off >>= 1) {
    a0 += __shfl_xor(a0, off);
    a1 += __shfl_xor(a1, off);
    a2 += __shfl_xor(a2, off);
  }
  if (lane == 0) {
    out[(size_t)r * 3 + 0] = a0 + b3[0] + res[(size_t)r * 3 + 0];
    out[(size_t)r * 3 + 1] = a1 + b3[1] + res[(size_t)r * 3 + 1];
    out[(size_t)r * 3 + 2] = a2 + b3[2] + res[(size_t)r * 3 + 2];
  }
}

// ---------------------------------------------------------------------------
extern "C" void kernel_launch(void* const* d_in, const int* in_sizes, int n_in,
                              void* d_out, int out_size, void* d_ws, size_t ws_size,
                              hipStream_t stream) {
  (void)in_sizes; (void)n_in; (void)out_size; (void)ws_size;
  const float* emb1   = (const float*)d_in[0];
  const float* l_y1   = (const float*)d_in[1];
  const float* l_pos1 = (const float*)d_in[2];
  const float* h_pos1 = (const float*)d_in[3];
  const float* emb2   = (const float*)d_in[4];
  const float* l_y2   = (const float*)d_in[5];
  const float* l_pos2 = (const float*)d_in[6];
  const float* h_pos2 = (const float*)d_in[7];
  const float* W1     = (const float*)d_in[8];
  const float* b1     = (const float*)d_in[9];
  const float* W2     = (const float*)d_in[10];
  const float* b2     = (const float*)d_in[11];
  const float* W3     = (const float*)d_in[12];
  const float* b3     = (const float*)d_in[13];
  float* out = (float*)d_out;

  const int Nh = 16384, Nl = 4096, H = 256;
  const int G1 = 16, G2 = 10;
  const int M1 = G1 * G1 * G1, M2 = G2 * G2 * G2;

  // ---- workspace carve-up (sequential bump allocator, 256B aligned) ----
  char* wsp = (char*)d_ws;
  size_t off = 0;
  auto alloc = [&](size_t bytes) -> void* {
    void* p = wsp + off;
    off += (bytes + 255) & ~(size_t)255;
    return p;
  };
  int*            idxC   = (int*)           alloc((size_t)Nh * 3 * 4);
  float*          wC     = (float*)         alloc((size_t)Nh * 3 * 4);
  unsigned short* t_hi   = (unsigned short*)alloc((size_t)Nh * H * 2);
  unsigned short* t_lo   = (unsigned short*)alloc((size_t)Nh * H * 2);
  unsigned short* h1_hi  = (unsigned short*)alloc((size_t)Nh * H * 2);
  unsigned short* h1_lo  = (unsigned short*)alloc((size_t)Nh * H * 2);
  float*          h2     = (float*)t_hi;    // alias over t_hi+t_lo (t dead)
  unsigned short* w1t_hi = (unsigned short*)alloc((size_t)H * H * 2);
  unsigned short* w1t_lo = (unsigned short*)alloc((size_t)H * H * 2);
  unsigned short* w2t_hi = (unsigned short*)alloc((size_t)H * H * 2);
  unsigned short* w2t_lo = (unsigned short*)alloc((size_t)H * H * 2);
  float*          diff   = (float*)         alloc((size_t)Nl * 3 * 4);
  float*          res    = (float*)         alloc((size_t)Nh * 3 * 4);
  int*            cnts   = (int*)           alloc((size_t)(M1 + M2 + M2 + M1) * 4);
  int* cnt1 = cnts, *cnt2 = cnts + M1, *cnt3 = cnts + M1 + M2, *cnt4 = cnts + M1 + 2 * M2;
  int*            offs1  = (int*)           alloc((size_t)(M1 + 1) * 4);
  int*            cur1   = (int*)           alloc((size_t)M1 * 4);
  int*            offs2  = (int*)           alloc((size_t)(M2 + 1) * 4);
  int*            cur2   = (int*)           alloc((size_t)M2 * 4);
  int*            offs3  = (int*)           alloc((size_t)(M2 + 1) * 4);
  int*            cur3   = (int*)           alloc((size_t)M2 * 4);
  int*            offs4  = (int*)           alloc((size_t)(M1 + 1) * 4);
  int*            cur4   = (int*)           alloc((size_t)M1 * 4);
  float4*         spts1  = (float4*)        alloc((size_t)Nh * 16);
  int*            sidx1  = (int*)           alloc((size_t)Nh * 4);
  float4*         spts2  = (float4*)        alloc((size_t)Nl * 16);
  int*            sidx2  = (int*)           alloc((size_t)Nl * 4);
  float4*         spts3  = (float4*)        alloc((size_t)Nl * 16);
  int*            sidx3  = (int*)           alloc((size_t)Nl * 4);
  float4*         qspts  = (float4*)        alloc((size_t)Nh * 16);   // sorted h_pos1
  int*            qsidx  = (int*)           alloc((size_t)Nh * 4);

  // ---- build grids (3 source + 1 query sort) + weight splits ----
  const int ncnt = M1 + M2 + M2 + M1;
  zero_kernel<<<(ncnt + 255) / 256, 256, 0, stream>>>(cnts, ncnt);
  count_split_kernel<<<672, 256, 0, stream>>>(
      h_pos2, Nh, G1, cnt1,  l_pos2, Nl, G2, cnt2,
      l_pos1, Nl, G2, cnt3,  h_pos1, Nh, G1, cnt4,
      W1, w1t_hi, w1t_lo, W2, w2t_hi, w2t_lo);
  prefix4_kernel<<<4, 256, 0, stream>>>(
      cnt1, offs1, cur1, M1,  cnt2, offs2, cur2, M2,
      cnt3, offs3, cur3, M2,  cnt4, offs4, cur4, M1);
  scatter4_kernel<<<160, 256, 0, stream>>>(
      h_pos2, Nh, G1, cur1, spts1, sidx1,
      l_pos2, Nl, G2, cur2, spts2, sidx2,
      l_pos1, Nl, G2, cur3, spts3, sidx3,
      h_pos1, Nh, G1, cur4, qspts, qsidx);

  // ---- all KNN work in one dispatch (128-thread blocks) ----
  knn_all_kernel<<<4608, 128, 0, stream>>>(
      qspts, qsidx, Nh,
      G1, offs1, spts1, sidx1, emb1, emb2, t_hi, t_lo,
      G2, offs3, spts3, sidx3, wC, idxC,
      Nl, offs2, spts2, sidx2, l_y1, l_y2, diff);

  // ---- gemm1 (+ res_gather riding along) ----
  mfma_gemm_kernel<<<1024 + 64, 256, 0, stream>>>(
      t_hi, t_lo, w1t_hi, w1t_lo, b1, nullptr, h1_hi, h1_lo, 1, 1, 1024,
      wC, idxC, diff, res, Nh);
  // ---- gemm2 ----
  mfma_gemm_kernel<<<1024, 256, 0, stream>>>(
      h1_hi, h1_lo, w2t_hi, w2t_lo, b2, h2, nullptr, nullptr, 1, 0, 1024,
      nullptr, nullptr, nullptr, nullptr, 0);

  // ---- final: out = (h2 @ W3 + b3) + res ----
  final_kernel<<<Nh / 4, 256, 0, stream>>>(h2, W3, b3, res, out, Nh);
}